// Round 9
// baseline (499.992 us; speedup 1.0000x reference)
//
#include <hip/hip_runtime.h>
#include <cstdint>
#include <cstddef>
#include <math.h>

#define N_NODES 100000
#define N_EDGES 1600000
#define DIM 128
#define DOUT 40
#define BN_EPS 1e-5f

// bucketed CSR build
#define NB 250          // buckets
#define NPB 400         // nodes per bucket (250*400 = 100000 exactly)
#define BCAP 8192       // bucket capacity (mean 6400 -> huge headroom)

typedef __attribute__((ext_vector_type(8))) short bf16x8;
typedef __attribute__((ext_vector_type(4))) float f32x4;

__device__ __forceinline__ float bf2f(uint u16shifted) {
    union { uint i; float f; } c; c.i = u16shifted; return c.f;
}
__device__ __forceinline__ ushort f2bf(float f) {
    union { float f; uint i; } c; c.f = f;
    uint i = c.i;
    uint lsb = (i >> 16) & 1u;
    i += 0x7FFFu + lsb;
    return (ushort)(i >> 16);
}
// apply BN+ReLU to a packed pair of bf16 given per-col scale/shift, repack
__device__ __forceinline__ uint bnpack(uint u, float s0, float h0, float s1, float h1) {
    float lo = fmaxf(bf2f(u << 16) * s0 + h0, 0.f);
    float hi = fmaxf(bf2f(u & 0xFFFF0000u) * s1 + h1, 0.f);
    return (uint)f2bf(lo) | ((uint)f2bf(hi) << 16);
}

// SLAB layout: feature buffers stored as [8 slabs][N_NODES][16 cols] bf16.
// element (node, col) -> ((col>>4)*N_NODES + node)*16 + (col&15)

// ---------------- convert x (row-major fp32) -> bf16 slabs ----------------
__global__ __launch_bounds__(256) void k_cvt_slab(const float* __restrict__ in,
                                                  ushort* __restrict__ out) {
    int idx = blockIdx.x * 256 + threadIdx.x;  // grid exact: N*16 / 256
    int n = idx >> 4, c8 = idx & 15;
    int col0 = c8 * 8;
    float4 v0 = *reinterpret_cast<const float4*>(in + (size_t)n * 128 + col0);
    float4 v1 = *reinterpret_cast<const float4*>(in + (size_t)n * 128 + col0 + 4);
    uint4 o;
    o.x = (uint)f2bf(v0.x) | ((uint)f2bf(v0.y) << 16);
    o.y = (uint)f2bf(v0.z) | ((uint)f2bf(v0.w) << 16);
    o.z = (uint)f2bf(v1.x) | ((uint)f2bf(v1.y) << 16);
    o.w = (uint)f2bf(v1.z) | ((uint)f2bf(v1.w) << 16);
    int slab = c8 >> 1, half = c8 & 1;
    *reinterpret_cast<uint4*>(out + ((size_t)slab * N_NODES + n) * 16 + half * 8) = o;
}

// ---------------- build Wcat[n][k] = k<128 ? W[k][n] : R[k-128][n], bf16, zero-pad n>=NW ----
__global__ void k_wcat(const float* __restrict__ W, const float* __restrict__ R,
                       ushort* __restrict__ out, int NW) {
    int idx = blockIdx.x * 256 + threadIdx.x;  // grid = Nout blocks
    int n = idx >> 8, k = idx & 255;
    float v = 0.f;
    if (n < NW) v = (k < 128) ? W[k * NW + n] : R[(k - 128) * NW + n];
    out[idx] = f2bf(v);
}

// ---------------- CSR pass A: partition edges into dst-buckets ----------------
__global__ __launch_bounds__(256) void k_bucket(const int* __restrict__ ei,
                                                uint* __restrict__ bucketbuf,
                                                int* __restrict__ gcnt) {
    __shared__ int hist[NB];
    __shared__ int base_[NB];
    int tid = threadIdx.x;
    for (int i = tid; i < NB; i += 256) hist[i] = 0;
    __syncthreads();
    const int EPB = N_EDGES / 256;  // 6250
    int e0 = blockIdx.x * EPB, e1 = e0 + EPB;
    for (int e = e0 + tid; e < e1; e += 256) {
        int d = ei[N_EDGES + e];
        atomicAdd(&hist[d / NPB], 1);
    }
    __syncthreads();
    for (int i = tid; i < NB; i += 256) base_[i] = atomicAdd(&gcnt[i], hist[i]);
    __syncthreads();
    for (int i = tid; i < NB; i += 256) hist[i] = 0;
    __syncthreads();
    for (int e = e0 + tid; e < e1; e += 256) {
        int d = ei[N_EDGES + e];
        int s = ei[e];
        int b = d / NPB;
        int pos = base_[b] + atomicAdd(&hist[b], 1);
        if (pos < BCAP)
            bucketbuf[(size_t)b * BCAP + pos] = ((uint)(d - b * NPB) << 17) | (uint)s;
    }
}

__global__ void k_bscan(const int* __restrict__ gcnt, int* __restrict__ bbase) {
    if (threadIdx.x == 0) {
        int run = 0;
        for (int b = 0; b < NB; b++) { bbase[b] = run; run += gcnt[b]; }
        bbase[NB] = run;
    }
}

// ---------------- CSR pass B: per-bucket CSR entirely in LDS, stream out ----------------
__global__ __launch_bounds__(256) void k_csr_build(const int* __restrict__ ei,
                                                   const uint* __restrict__ bucketbuf,
                                                   const int* __restrict__ gcnt,
                                                   const int* __restrict__ bbase,
                                                   int* __restrict__ rowstart,
                                                   int* __restrict__ csr) {
    __shared__ int cnts[NPB + 1];
    __shared__ int lcur[NPB];
    __shared__ int csr_l[BCAP];
    int b = blockIdx.x, tid = threadIdx.x;
    int cnt = gcnt[b];
    int base = bbase[b];
    int lo = b * NPB;
    bool fits = (cnt <= BCAP);
    for (int i = tid; i < NPB; i += 256) cnts[i] = 0;
    __syncthreads();
    if (fits) {
        for (int i = tid; i < cnt; i += 256)
            atomicAdd(&cnts[bucketbuf[(size_t)b * BCAP + i] >> 17], 1);
    } else {  // overflow fallback (statistically never): full edge sweep
        for (int e = tid; e < N_EDGES; e += 256) {
            int d = ei[N_EDGES + e];
            if (d >= lo && d < lo + NPB) atomicAdd(&cnts[d - lo], 1);
        }
    }
    __syncthreads();
    if (tid == 0) {
        int run = 0;
        for (int i = 0; i < NPB; i++) { int c = cnts[i]; cnts[i] = run; run += c; }
        cnts[NPB] = run;
    }
    __syncthreads();
    for (int i = tid; i < NPB; i += 256) rowstart[lo + i] = base + cnts[i];
    if (b == NB - 1 && tid == 0) rowstart[N_NODES] = base + cnts[NPB];
    for (int i = tid; i < NPB; i += 256) lcur[i] = 0;
    __syncthreads();
    if (fits) {
        for (int i = tid; i < cnt; i += 256) {
            uint p = bucketbuf[(size_t)b * BCAP + i];
            int dl = p >> 17;
            int pos = cnts[dl] + atomicAdd(&lcur[dl], 1);
            csr_l[pos] = (int)(p & 0x1FFFFu);
        }
        __syncthreads();
        for (int i = tid; i < cnt; i += 256) csr[base + i] = csr_l[i];
    } else {
        for (int e = tid; e < N_EDGES; e += 256) {
            int d = ei[N_EDGES + e];
            if (d >= lo && d < lo + NPB) {
                int dl = d - lo;
                int pos = cnts[dl] + atomicAdd(&lcur[dl], 1);
                csr[base + pos] = ei[e];
            }
        }
    }
}

// ---------------- mean aggregation over SLABS, XCD-column-sliced ----------------
// slice g = blockIdx&7 handles slab g (16 cols, 3.2 MB -> L2-resident per XCD).
// wave = 4 nodes; per node 8 edge-slots x 2 halves; lane loads uint4 (8 bf16).
__global__ __launch_bounds__(256) void k_agg_slab(const ushort* __restrict__ cur,
                                                  const int* __restrict__ rowstart,
                                                  const int* __restrict__ csr,
                                                  ushort* __restrict__ out,
                                                  const float* __restrict__ scale,
                                                  const float* __restrict__ shift,
                                                  int hasbn) {
    int g = blockIdx.x & 7;
    int tid = threadIdx.x;
    int lane = tid & 63;
    int nsub = lane >> 4;          // node within wave (0..3)
    int r = lane & 15;
    int slot = r >> 1;             // edge slot (0..7)
    int half = r & 1;              // which 8-col half of the 16-col slab
    int node = (blockIdx.x >> 3) * 16 + (tid >> 6) * 4 + nsub;  // exact: 6250*16=100000

    const ushort* slab = cur + (size_t)g * N_NODES * 16;
    float sc0 = 1.f, sc1 = 1.f, sc2 = 1.f, sc3 = 1.f, sc4 = 1.f, sc5 = 1.f, sc6 = 1.f, sc7 = 1.f;
    float sh0 = 0.f, sh1 = 0.f, sh2 = 0.f, sh3 = 0.f, sh4 = 0.f, sh5 = 0.f, sh6 = 0.f, sh7 = 0.f;
    if (hasbn) {
        int c0 = g * 16 + half * 8;
        sc0 = scale[c0 + 0]; sc1 = scale[c0 + 1]; sc2 = scale[c0 + 2]; sc3 = scale[c0 + 3];
        sc4 = scale[c0 + 4]; sc5 = scale[c0 + 5]; sc6 = scale[c0 + 6]; sc7 = scale[c0 + 7];
        sh0 = shift[c0 + 0]; sh1 = shift[c0 + 1]; sh2 = shift[c0 + 2]; sh3 = shift[c0 + 3];
        sh4 = shift[c0 + 4]; sh5 = shift[c0 + 5]; sh6 = shift[c0 + 6]; sh7 = shift[c0 + 7];
    }
    int beg = rowstart[node];
    int end = rowstart[node + 1];
    float a0 = 0.f, a1 = 0.f, a2 = 0.f, a3 = 0.f, a4 = 0.f, a5 = 0.f, a6 = 0.f, a7 = 0.f;
    for (int e = beg + slot; e < end; e += 8) {
        int s = csr[e];
        uint4 u = *reinterpret_cast<const uint4*>(slab + (size_t)s * 16 + half * 8);
        float v0 = bf2f(u.x << 16), v1 = bf2f(u.x & 0xFFFF0000u);
        float v2 = bf2f(u.y << 16), v3 = bf2f(u.y & 0xFFFF0000u);
        float v4 = bf2f(u.z << 16), v5 = bf2f(u.z & 0xFFFF0000u);
        float v6 = bf2f(u.w << 16), v7 = bf2f(u.w & 0xFFFF0000u);
        if (hasbn) {
            v0 = fmaxf(v0 * sc0 + sh0, 0.f); v1 = fmaxf(v1 * sc1 + sh1, 0.f);
            v2 = fmaxf(v2 * sc2 + sh2, 0.f); v3 = fmaxf(v3 * sc3 + sh3, 0.f);
            v4 = fmaxf(v4 * sc4 + sh4, 0.f); v5 = fmaxf(v5 * sc5 + sh5, 0.f);
            v6 = fmaxf(v6 * sc6 + sh6, 0.f); v7 = fmaxf(v7 * sc7 + sh7, 0.f);
        }
        a0 += v0; a1 += v1; a2 += v2; a3 += v3;
        a4 += v4; a5 += v5; a6 += v6; a7 += v7;
    }
    // reduce across the 8 slots (lane bits 1..3)
#pragma unroll
    for (int off = 2; off <= 8; off <<= 1) {
        a0 += __shfl_xor(a0, off, 64); a1 += __shfl_xor(a1, off, 64);
        a2 += __shfl_xor(a2, off, 64); a3 += __shfl_xor(a3, off, 64);
        a4 += __shfl_xor(a4, off, 64); a5 += __shfl_xor(a5, off, 64);
        a6 += __shfl_xor(a6, off, 64); a7 += __shfl_xor(a7, off, 64);
    }
    if (slot == 0) {
        int deg = end - beg;
        float inv = 1.0f / (float)(deg > 1 ? deg : 1);
        uint4 o;
        o.x = (uint)f2bf(a0 * inv) | ((uint)f2bf(a1 * inv) << 16);
        o.y = (uint)f2bf(a2 * inv) | ((uint)f2bf(a3 * inv) << 16);
        o.z = (uint)f2bf(a4 * inv) | ((uint)f2bf(a5 * inv) << 16);
        o.w = (uint)f2bf(a6 * inv) | ((uint)f2bf(a7 * inv) << 16);
        *reinterpret_cast<uint4*>(out + ((size_t)g * N_NODES + node) * 16 + half * 8) = o;
    }
}

// ---------------- MFMA GEMM (LDS-staged): out = mean@W + bnrelu(cur)@R + b, fused stats ----
// A operands (Am/Ac) and out are in SLAB layout; Wcat row-major [128][256].
__global__ __launch_bounds__(256) void k_gemm_mfma(const ushort* __restrict__ Am,
                                                   const ushort* __restrict__ Ac,
                                                   const ushort* __restrict__ Wcat,
                                                   const float* __restrict__ bias,
                                                   const float* __restrict__ scale,
                                                   const float* __restrict__ shift,
                                                   int hasbn,
                                                   ushort* __restrict__ out,
                                                   float* __restrict__ csum,
                                                   float* __restrict__ csumsq,
                                                   int dostats) {
    __shared__ ushort As[128 * 40];  // 128 rows x 32 k, padded stride 40
    __shared__ ushort Bs[128 * 40];  // 128 cols x 32 k
    __shared__ float scS[128], shS[128];
    __shared__ float lsum[128], lsumsq[128];
    int tid = threadIdx.x;
    int wid = tid >> 6, lane = tid & 63;
    int wr = wid >> 1, wc = wid & 1;
    int l15 = lane & 15, lhi = lane >> 4;
    int row0 = blockIdx.x * 128;

    if (hasbn && tid < 128) { scS[tid] = scale[tid]; shS[tid] = shift[tid]; }
    if (dostats && tid < 128) { lsum[tid] = 0.f; lsumsq[tid] = 0.f; }

    f32x4 acc[4][4];
#pragma unroll
    for (int m = 0; m < 4; m++)
#pragma unroll
        for (int n = 0; n < 4; n++) acc[m][n] = (f32x4){0.f, 0.f, 0.f, 0.f};

    for (int ks = 0; ks < 8; ++ks) {
        int kg = ks * 32;
        bool self = (kg >= 128);
        const ushort* Asrc = self ? Ac : Am;
        int ka = kg & 127;
        bool doBN = self && hasbn;
        __syncthreads();
#pragma unroll
        for (int h = 0; h < 2; ++h) {
            int c = tid + h * 256;
            int row = c >> 2, q = c & 3;
            int gr = row0 + row;
            int co = ka + q * 8;                       // column offset 0..127, %8==0
            uint4 v = {0, 0, 0, 0};
            if (gr < N_NODES)
                v = *reinterpret_cast<const uint4*>(
                        Asrc + ((size_t)(co >> 4) * N_NODES + gr) * 16 + (co & 15));
            if (doBN) {
                v.x = bnpack(v.x, scS[co + 0], shS[co + 0], scS[co + 1], shS[co + 1]);
                v.y = bnpack(v.y, scS[co + 2], shS[co + 2], scS[co + 3], shS[co + 3]);
                v.z = bnpack(v.z, scS[co + 4], shS[co + 4], scS[co + 5], shS[co + 5]);
                v.w = bnpack(v.w, scS[co + 6], shS[co + 6], scS[co + 7], shS[co + 7]);
            }
            *reinterpret_cast<uint4*>(&As[row * 40 + q * 8]) = v;
        }
#pragma unroll
        for (int h = 0; h < 2; ++h) {
            int c = tid + h * 256;
            int n = c >> 2, q = c & 3;
            *reinterpret_cast<uint4*>(&Bs[n * 40 + q * 8]) =
                *reinterpret_cast<const uint4*>(Wcat + n * 256 + kg + q * 8);
        }
        __syncthreads();
        bf16x8 a[4], b[4];
#pragma unroll
        for (int m = 0; m < 4; m++)
            a[m] = *reinterpret_cast<bf16x8*>(&As[(wr * 64 + m * 16 + l15) * 40 + lhi * 8]);
#pragma unroll
        for (int n = 0; n < 4; n++)
            b[n] = *reinterpret_cast<bf16x8*>(&Bs[(wc * 64 + n * 16 + l15) * 40 + lhi * 8]);
#pragma unroll
        for (int m = 0; m < 4; m++)
#pragma unroll
            for (int n = 0; n < 4; n++)
                acc[m][n] = __builtin_amdgcn_mfma_f32_16x16x32_bf16(a[m], b[n], acc[m][n], 0, 0, 0);
    }
    // epilogue: + bias, bf16 store to slab layout, per-column stats partials
    float ps[4] = {0.f, 0.f, 0.f, 0.f}, ps2[4] = {0.f, 0.f, 0.f, 0.f};
#pragma unroll
    for (int m = 0; m < 4; m++) {
        int rbase = row0 + wr * 64 + m * 16 + lhi * 4;
#pragma unroll
        for (int n = 0; n < 4; n++) {
            int col = wc * 64 + n * 16 + l15;
            float bv = bias[col];
            size_t sbase = ((size_t)(col >> 4) * N_NODES) * 16 + (col & 15);
#pragma unroll
            for (int j = 0; j < 4; j++) {
                int gr = rbase + j;
                if (gr < N_NODES) {
                    float v = acc[m][n][j] + bv;
                    out[sbase + (size_t)gr * 16] = f2bf(v);
                    ps[n] += v;
                    ps2[n] += v * v;
                }
            }
        }
    }
    if (dostats) {
#pragma unroll
        for (int n = 0; n < 4; n++) {
            ps[n] += __shfl_xor(ps[n], 16, 64);
            ps2[n] += __shfl_xor(ps2[n], 16, 64);
            ps[n] += __shfl_xor(ps[n], 32, 64);
            ps2[n] += __shfl_xor(ps2[n], 32, 64);
        }
        if (lhi == 0) {
#pragma unroll
            for (int n = 0; n < 4; n++) {
                int col = wc * 64 + n * 16 + l15;
                atomicAdd(&lsum[col], ps[n]);
                atomicAdd(&lsumsq[col], ps2[n]);
            }
        }
        __syncthreads();
        if (tid < 128) {
            atomicAdd(&csum[tid], lsum[tid]);
            atomicAdd(&csumsq[tid], lsumsq[tid]);
        }
    }
}

// ---------------- layer-3 MFMA GEMM (LDS-staged, slab A) + bias + log_softmax fused --------
__global__ __launch_bounds__(256) void k_gemm40_mfma(const ushort* __restrict__ Am,
                                                     const ushort* __restrict__ Ac,
                                                     const ushort* __restrict__ Wcat, // [48][256]
                                                     const float* __restrict__ bias,  // [40]
                                                     const float* __restrict__ scale,
                                                     const float* __restrict__ shift,
                                                     float* __restrict__ out) {
    __shared__ ushort As[128 * 40];
    __shared__ ushort Bs[48 * 40];
    __shared__ float scS[128], shS[128];
    int tid = threadIdx.x;
    int w = tid >> 6, lane = tid & 63;
    int l15 = lane & 15, lhi = lane >> 4;
    int row0 = blockIdx.x * 128;

    if (tid < 128) { scS[tid] = scale[tid]; shS[tid] = shift[tid]; }

    f32x4 acc[2][3];
#pragma unroll
    for (int m = 0; m < 2; m++)
#pragma unroll
        for (int n = 0; n < 3; n++) acc[m][n] = (f32x4){0.f, 0.f, 0.f, 0.f};

    for (int ks = 0; ks < 8; ++ks) {
        int kg = ks * 32;
        bool self = (kg >= 128);
        const ushort* Asrc = self ? Ac : Am;
        int ka = kg & 127;
        __syncthreads();
#pragma unroll
        for (int h = 0; h < 2; ++h) {
            int c = tid + h * 256;
            int row = c >> 2, q = c & 3;
            int gr = row0 + row;
            int co = ka + q * 8;
            uint4 v = {0, 0, 0, 0};
            if (gr < N_NODES)
                v = *reinterpret_cast<const uint4*>(
                        Asrc + ((size_t)(co >> 4) * N_NODES + gr) * 16 + (co & 15));
            if (self) {
                v.x = bnpack(v.x, scS[co + 0], shS[co + 0], scS[co + 1], shS[co + 1]);
                v.y = bnpack(v.y, scS[co + 2], shS[co + 2], scS[co + 3], shS[co + 3]);
                v.z = bnpack(v.z, scS[co + 4], shS[co + 4], scS[co + 5], shS[co + 5]);
                v.w = bnpack(v.w, scS[co + 6], shS[co + 6], scS[co + 7], shS[co + 7]);
            }
            *reinterpret_cast<uint4*>(&As[row * 40 + q * 8]) = v;
        }
        if (tid < 192) {
            int n = tid >> 2, q = tid & 3;
            *reinterpret_cast<uint4*>(&Bs[n * 40 + q * 8]) =
                *reinterpret_cast<const uint4*>(Wcat + n * 256 + kg + q * 8);
        }
        __syncthreads();
        bf16x8 a[2], b[3];
#pragma unroll
        for (int m = 0; m < 2; m++)
            a[m] = *reinterpret_cast<bf16x8*>(&As[(w * 32 + m * 16 + l15) * 40 + lhi * 8]);
#pragma unroll
        for (int n = 0; n < 3; n++)
            b[n] = *reinterpret_cast<bf16x8*>(&Bs[(n * 16 + l15) * 40 + lhi * 8]);
#pragma unroll
        for (int m = 0; m < 2; m++)
#pragma unroll
            for (int n = 0; n < 3; n++)
                acc[m][n] = __builtin_amdgcn_mfma_f32_16x16x32_bf16(a[m], b[n], acc[m][n], 0, 0, 0);
    }
    // epilogue: bias + log_softmax per row
    float b0 = bias[l15];
    float b1 = bias[16 + l15];
    float b2 = (l15 < 8) ? bias[32 + l15] : 0.f;
#pragma unroll
    for (int m = 0; m < 2; m++) {
#pragma unroll
        for (int j = 0; j < 4; j++) {
            int grow = row0 + w * 32 + m * 16 + lhi * 4 + j;
            float v0 = acc[m][0][j] + b0;
            float v1 = acc[m][1][j] + b1;
            float v2 = (l15 < 8) ? (acc[m][2][j] + b2) : -INFINITY;
            float mx = fmaxf(fmaxf(v0, v1), v2);
#pragma unroll
            for (int off = 1; off < 16; off <<= 1) mx = fmaxf(mx, __shfl_xor(mx, off, 64));
            float s = expf(v0 - mx) + expf(v1 - mx) + ((l15 < 8) ? expf(v2 - mx) : 0.f);
#pragma unroll
            for (int off = 1; off < 16; off <<= 1) s += __shfl_xor(s, off, 64);
            float lg = mx + logf(s);
            if (grow < N_NODES) {
                out[(size_t)grow * DOUT + l15] = v0 - lg;
                out[(size_t)grow * DOUT + 16 + l15] = v1 - lg;
                if (l15 < 8) out[(size_t)grow * DOUT + 32 + l15] = v2 - lg;
            }
        }
    }
}

__global__ void k_bnfin(const float* __restrict__ sum, const float* __restrict__ sumsq,
                        const float* __restrict__ g, const float* __restrict__ be,
                        float* __restrict__ scale, float* __restrict__ shift) {
    int c = threadIdx.x;
    if (c < DIM) {
        float mu = sum[c] * (1.0f / N_NODES);
        float var = sumsq[c] * (1.0f / N_NODES) - mu * mu;
        float sc = g[c] * rsqrtf(var + BN_EPS);
        scale[c] = sc;
        shift[c] = be[c] - mu * sc;
    }
}

// ---------------- launch ----------------
extern "C" void kernel_launch(void* const* d_in, const int* in_sizes, int n_in,
                              void* d_out, int out_size, void* d_ws, size_t ws_size,
                              hipStream_t stream) {
    const float* x = (const float*)d_in[0];
    const int* ei = (const int*)d_in[1];
    const float* w1 = (const float*)d_in[2];
    const float* r1 = (const float*)d_in[3];
    const float* b1 = (const float*)d_in[4];
    const float* g1 = (const float*)d_in[5];
    const float* be1 = (const float*)d_in[6];
    const float* w2 = (const float*)d_in[7];
    const float* r2 = (const float*)d_in[8];
    const float* b2 = (const float*)d_in[9];
    const float* g2 = (const float*)d_in[10];
    const float* be2 = (const float*)d_in[11];
    const float* w3 = (const float*)d_in[12];
    const float* r3 = (const float*)d_in[13];
    const float* b3 = (const float*)d_in[14];
    float* out = (float*)d_out;

    const size_t NF = (size_t)N_NODES * DIM;  // 12.8M
    ushort* Xb = (ushort*)d_ws;
    ushort* Ab = Xb + NF;
    ushort* Bb = Ab + NF;
    ushort* Wc1 = Bb + NF;             // 128*256
    ushort* Wc2 = Wc1 + 128 * 256;
    ushort* Wc3 = Wc2 + 128 * 256;     // 48*256
    uint* bucketbuf = (uint*)(Wc3 + 48 * 256);   // NB*BCAP = 2.048M uints
    int* gcnt = (int*)(bucketbuf + (size_t)NB * BCAP);  // NB
    int* bbase = gcnt + NB;                       // NB+1
    int* rowstart = bbase + NB + 1;               // N+1
    int* csr = rowstart + (N_NODES + 1);          // E
    float* colsum = (float*)(csr + N_EDGES);      // 128
    float* colsumsq = colsum + 128;
    float* scaleS = colsumsq + 128;
    float* shiftS = scaleS + 128;
    size_t needed = (size_t)((char*)(shiftS + 128) - (char*)d_ws);
    if (ws_size < needed) return;

    const int CVT_BLOCKS = N_NODES * 16 / 256;        // 6250
    const int AGG_BLOCKS = (N_NODES / 16) * 8;        // 50000
    const int GEMM_BLOCKS = (N_NODES + 127) / 128;    // 782

    // conversions
    k_cvt_slab<<<CVT_BLOCKS, 256, 0, stream>>>(x, Xb);
    k_wcat<<<128, 256, 0, stream>>>(w1, r1, Wc1, 128);
    k_wcat<<<128, 256, 0, stream>>>(w2, r2, Wc2, 128);
    k_wcat<<<48, 256, 0, stream>>>(w3, r3, Wc3, DOUT);

    // CSR build (bucketed, 2-pass)
    hipMemsetAsync(gcnt, 0, sizeof(int) * NB, stream);
    k_bucket<<<256, 256, 0, stream>>>(ei, bucketbuf, gcnt);
    k_bscan<<<1, 64, 0, stream>>>(gcnt, bbase);
    k_csr_build<<<NB, 256, 0, stream>>>(ei, bucketbuf, gcnt, bbase, rowstart, csr);

    // ---- layer 1 ----  (h1 = gemm output, PRE-BN, in slab layout; stats fused)
    k_agg_slab<<<AGG_BLOCKS, 256, 0, stream>>>(Xb, rowstart, csr, Ab, nullptr, nullptr, 0);
    hipMemsetAsync(colsum, 0, sizeof(float) * 256, stream);
    k_gemm_mfma<<<GEMM_BLOCKS, 256, 0, stream>>>(Ab, Xb, Wc1, b1, nullptr, nullptr, 0, Ab,
                                                 colsum, colsumsq, 1);
    k_bnfin<<<1, 128, 0, stream>>>(colsum, colsumsq, g1, be1, scaleS, shiftS);  // BN1

    // ---- layer 2 ----  (consumers apply BN1+ReLU on the fly; stats fused)
    k_agg_slab<<<AGG_BLOCKS, 256, 0, stream>>>(Ab, rowstart, csr, Bb, scaleS, shiftS, 1);
    hipMemsetAsync(colsum, 0, sizeof(float) * 256, stream);
    k_gemm_mfma<<<GEMM_BLOCKS, 256, 0, stream>>>(Bb, Ab, Wc2, b2, scaleS, shiftS, 1, Bb,
                                                 colsum, colsumsq, 1);
    k_bnfin<<<1, 128, 0, stream>>>(colsum, colsumsq, g2, be2, scaleS, shiftS);  // BN2

    // ---- layer 3 ----  (consumers apply BN2+ReLU; bias + log_softmax fused)
    k_agg_slab<<<AGG_BLOCKS, 256, 0, stream>>>(Bb, rowstart, csr, Ab, scaleS, shiftS, 1);
    k_gemm40_mfma<<<GEMM_BLOCKS, 256, 0, stream>>>(Ab, Bb, Wc3, b3, scaleS, shiftS, out);
}

// Round 10
// 452.954 us; speedup vs baseline: 1.1038x; 1.1038x over previous
//
#include <hip/hip_runtime.h>
#include <cstdint>
#include <cstddef>
#include <math.h>

#define N_NODES 100000
#define N_EDGES 1600000
#define DIM 128
#define DOUT 40
#define BN_EPS 1e-5f

// bucketed CSR build
#define NB 250          // buckets
#define NPB 400         // nodes per bucket (250*400 = 100000 exactly)
#define BCAP 8192       // bucket capacity (mean 6400 -> huge headroom)

typedef __attribute__((ext_vector_type(8))) short bf16x8;
typedef __attribute__((ext_vector_type(4))) float f32x4;

__device__ __forceinline__ float bf2f(uint u16shifted) {
    union { uint i; float f; } c; c.i = u16shifted; return c.f;
}
__device__ __forceinline__ ushort f2bf(float f) {
    union { float f; uint i; } c; c.f = f;
    uint i = c.i;
    uint lsb = (i >> 16) & 1u;
    i += 0x7FFFu + lsb;
    return (ushort)(i >> 16);
}
// apply BN+ReLU to a packed pair of bf16 given per-col scale/shift, repack
__device__ __forceinline__ uint bnpack(uint u, float s0, float h0, float s1, float h1) {
    float lo = fmaxf(bf2f(u << 16) * s0 + h0, 0.f);
    float hi = fmaxf(bf2f(u & 0xFFFF0000u) * s1 + h1, 0.f);
    return (uint)f2bf(lo) | ((uint)f2bf(hi) << 16);
}

// ---------------- convert x -> bf16 ----------------
__global__ __launch_bounds__(256) void k_cvt(const float* __restrict__ in,
                                             ushort* __restrict__ out, int n4) {
    int i = blockIdx.x * blockDim.x + threadIdx.x;
    int stride = gridDim.x * blockDim.x;
    for (; i < n4; i += stride) {
        float4 v = reinterpret_cast<const float4*>(in)[i];
        ushort4 o;
        o.x = f2bf(v.x); o.y = f2bf(v.y); o.z = f2bf(v.z); o.w = f2bf(v.w);
        reinterpret_cast<ushort4*>(out)[i] = o;
    }
}

// ---------------- build Wcat[n][k] = k<128 ? W[k][n] : R[k-128][n], bf16, zero-pad n>=NW ----
__global__ void k_wcat(const float* __restrict__ W, const float* __restrict__ R,
                       ushort* __restrict__ out, int NW) {
    int idx = blockIdx.x * 256 + threadIdx.x;  // grid = Nout blocks
    int n = idx >> 8, k = idx & 255;
    float v = 0.f;
    if (n < NW) v = (k < 128) ? W[k * NW + n] : R[(k - 128) * NW + n];
    out[idx] = f2bf(v);
}

// ---------------- CSR pass A: partition edges into dst-buckets ----------------
__global__ __launch_bounds__(256) void k_bucket(const int* __restrict__ ei,
                                                uint* __restrict__ bucketbuf,
                                                int* __restrict__ gcnt) {
    __shared__ int hist[NB];
    __shared__ int base_[NB];
    int tid = threadIdx.x;
    for (int i = tid; i < NB; i += 256) hist[i] = 0;
    __syncthreads();
    const int EPB = N_EDGES / 256;  // 6250
    int e0 = blockIdx.x * EPB, e1 = e0 + EPB;
    for (int e = e0 + tid; e < e1; e += 256) {
        int d = ei[N_EDGES + e];
        atomicAdd(&hist[d / NPB], 1);
    }
    __syncthreads();
    for (int i = tid; i < NB; i += 256) base_[i] = atomicAdd(&gcnt[i], hist[i]);
    __syncthreads();
    for (int i = tid; i < NB; i += 256) hist[i] = 0;
    __syncthreads();
    for (int e = e0 + tid; e < e1; e += 256) {
        int d = ei[N_EDGES + e];
        int s = ei[e];
        int b = d / NPB;
        int pos = base_[b] + atomicAdd(&hist[b], 1);
        if (pos < BCAP)
            bucketbuf[(size_t)b * BCAP + pos] = ((uint)(d - b * NPB) << 17) | (uint)s;
    }
}

__global__ void k_bscan(const int* __restrict__ gcnt, int* __restrict__ bbase) {
    if (threadIdx.x == 0) {
        int run = 0;
        for (int b = 0; b < NB; b++) { bbase[b] = run; run += gcnt[b]; }
        bbase[NB] = run;
    }
}

// ---------------- CSR pass B: per-bucket CSR entirely in LDS, stream out ----------------
__global__ __launch_bounds__(256) void k_csr_build(const int* __restrict__ ei,
                                                   const uint* __restrict__ bucketbuf,
                                                   const int* __restrict__ gcnt,
                                                   const int* __restrict__ bbase,
                                                   int* __restrict__ rowstart,
                                                   int* __restrict__ csr) {
    __shared__ int cnts[NPB + 1];
    __shared__ int lcur[NPB];
    __shared__ int csr_l[BCAP];
    int b = blockIdx.x, tid = threadIdx.x;
    int cnt = gcnt[b];
    int base = bbase[b];
    int lo = b * NPB;
    bool fits = (cnt <= BCAP);
    for (int i = tid; i < NPB; i += 256) cnts[i] = 0;
    __syncthreads();
    if (fits) {
        for (int i = tid; i < cnt; i += 256)
            atomicAdd(&cnts[bucketbuf[(size_t)b * BCAP + i] >> 17], 1);
    } else {  // overflow fallback (statistically never): full edge sweep
        for (int e = tid; e < N_EDGES; e += 256) {
            int d = ei[N_EDGES + e];
            if (d >= lo && d < lo + NPB) atomicAdd(&cnts[d - lo], 1);
        }
    }
    __syncthreads();
    if (tid == 0) {
        int run = 0;
        for (int i = 0; i < NPB; i++) { int c = cnts[i]; cnts[i] = run; run += c; }
        cnts[NPB] = run;
    }
    __syncthreads();
    for (int i = tid; i < NPB; i += 256) rowstart[lo + i] = base + cnts[i];
    if (b == NB - 1 && tid == 0) rowstart[N_NODES] = base + cnts[NPB];
    for (int i = tid; i < NPB; i += 256) lcur[i] = 0;
    __syncthreads();
    if (fits) {
        for (int i = tid; i < cnt; i += 256) {
            uint p = bucketbuf[(size_t)b * BCAP + i];
            int dl = p >> 17;
            int pos = cnts[dl] + atomicAdd(&lcur[dl], 1);
            csr_l[pos] = (int)(p & 0x1FFFFu);
        }
        __syncthreads();
        for (int i = tid; i < cnt; i += 256) csr[base + i] = csr_l[i];
    } else {
        for (int e = tid; e < N_EDGES; e += 256) {
            int d = ei[N_EDGES + e];
            if (d >= lo && d < lo + NPB) {
                int dl = d - lo;
                int pos = cnts[dl] + atomicAdd(&lcur[dl], 1);
                csr[base + pos] = ei[e];
            }
        }
    }
}

// ---------------- mean aggregation, bf16, 4 edges in flight, optional fused BN+ReLU --------
// one wave per node; lane = slot(0..3) x colgroup(0..15); each lane loads uint4 = 8 bf16 cols
__global__ __launch_bounds__(256) void k_agg_bf(const ushort* __restrict__ cur,
                                                const int* __restrict__ rowstart,
                                                const int* __restrict__ csr,
                                                ushort* __restrict__ out,
                                                const float* __restrict__ scale,
                                                const float* __restrict__ shift,
                                                int hasbn) {
    int wid = (blockIdx.x * blockDim.x + threadIdx.x) >> 6;
    int lane = threadIdx.x & 63;
    if (wid >= N_NODES) return;
    int beg = rowstart[wid];
    int end = rowstart[wid + 1];
    int slot = lane >> 4;   // which edge within a group of 4
    int cg = lane & 15;     // column group: cols cg*8 .. cg*8+7
    float sc0 = 1.f, sc1 = 1.f, sc2 = 1.f, sc3 = 1.f, sc4 = 1.f, sc5 = 1.f, sc6 = 1.f, sc7 = 1.f;
    float sh0 = 0.f, sh1 = 0.f, sh2 = 0.f, sh3 = 0.f, sh4 = 0.f, sh5 = 0.f, sh6 = 0.f, sh7 = 0.f;
    if (hasbn) {
        int c0 = cg * 8;
        sc0 = scale[c0 + 0]; sc1 = scale[c0 + 1]; sc2 = scale[c0 + 2]; sc3 = scale[c0 + 3];
        sc4 = scale[c0 + 4]; sc5 = scale[c0 + 5]; sc6 = scale[c0 + 6]; sc7 = scale[c0 + 7];
        sh0 = shift[c0 + 0]; sh1 = shift[c0 + 1]; sh2 = shift[c0 + 2]; sh3 = shift[c0 + 3];
        sh4 = shift[c0 + 4]; sh5 = shift[c0 + 5]; sh6 = shift[c0 + 6]; sh7 = shift[c0 + 7];
    }
    const uint4* base = reinterpret_cast<const uint4*>(cur);  // row = 16 x uint4
    float a0 = 0.f, a1 = 0.f, a2 = 0.f, a3 = 0.f, a4 = 0.f, a5 = 0.f, a6 = 0.f, a7 = 0.f;
#pragma unroll 2
    for (int e = beg + slot; e < end; e += 4) {
        int s = csr[e];
        uint4 u = base[(size_t)s * 16 + cg];
        float v0 = bf2f(u.x << 16), v1 = bf2f(u.x & 0xFFFF0000u);
        float v2 = bf2f(u.y << 16), v3 = bf2f(u.y & 0xFFFF0000u);
        float v4 = bf2f(u.z << 16), v5 = bf2f(u.z & 0xFFFF0000u);
        float v6 = bf2f(u.w << 16), v7 = bf2f(u.w & 0xFFFF0000u);
        if (hasbn) {
            v0 = fmaxf(v0 * sc0 + sh0, 0.f); v1 = fmaxf(v1 * sc1 + sh1, 0.f);
            v2 = fmaxf(v2 * sc2 + sh2, 0.f); v3 = fmaxf(v3 * sc3 + sh3, 0.f);
            v4 = fmaxf(v4 * sc4 + sh4, 0.f); v5 = fmaxf(v5 * sc5 + sh5, 0.f);
            v6 = fmaxf(v6 * sc6 + sh6, 0.f); v7 = fmaxf(v7 * sc7 + sh7, 0.f);
        }
        a0 += v0; a1 += v1; a2 += v2; a3 += v3;
        a4 += v4; a5 += v5; a6 += v6; a7 += v7;
    }
    // combine the 4 slots: lanes l, l^16, l^32
#pragma unroll
    for (int off = 16; off < 64; off <<= 1) {
        a0 += __shfl_xor(a0, off, 64); a1 += __shfl_xor(a1, off, 64);
        a2 += __shfl_xor(a2, off, 64); a3 += __shfl_xor(a3, off, 64);
        a4 += __shfl_xor(a4, off, 64); a5 += __shfl_xor(a5, off, 64);
        a6 += __shfl_xor(a6, off, 64); a7 += __shfl_xor(a7, off, 64);
    }
    if (slot == 0) {
        int deg = end - beg;
        float inv = 1.0f / (float)(deg > 1 ? deg : 1);
        uint4 o;
        o.x = (uint)f2bf(a0 * inv) | ((uint)f2bf(a1 * inv) << 16);
        o.y = (uint)f2bf(a2 * inv) | ((uint)f2bf(a3 * inv) << 16);
        o.z = (uint)f2bf(a4 * inv) | ((uint)f2bf(a5 * inv) << 16);
        o.w = (uint)f2bf(a6 * inv) | ((uint)f2bf(a7 * inv) << 16);
        reinterpret_cast<uint4*>(out)[(size_t)wid * 16 + cg] = o;
    }
}

// ---------------- MFMA GEMM (LDS-staged): out = mean@W + bnrelu(cur)@R + b, fused stats ----
// 128x128 tile, 256 threads = 4 waves as 2x2, each wave 64x64 (4x4 frags of 16x16x32)
// in-place safe for out==mean; Ac tile gets optional BN+ReLU applied at staging
__global__ __launch_bounds__(256) void k_gemm_mfma(const ushort* __restrict__ Am,
                                                   const ushort* __restrict__ Ac,
                                                   const ushort* __restrict__ Wcat, // [128][256]
                                                   const float* __restrict__ bias,
                                                   const float* __restrict__ scale,
                                                   const float* __restrict__ shift,
                                                   int hasbn,
                                                   ushort* __restrict__ out,
                                                   float* __restrict__ csum,
                                                   float* __restrict__ csumsq,
                                                   int dostats) {
    __shared__ ushort As[128 * 40];  // 128 rows x 32 k, padded stride 40 (80 B)
    __shared__ ushort Bs[128 * 40];  // 128 cols x 32 k
    __shared__ float scS[128], shS[128];
    __shared__ float lsum[128], lsumsq[128];
    int tid = threadIdx.x;
    int wid = tid >> 6, lane = tid & 63;
    int wr = wid >> 1, wc = wid & 1;
    int l15 = lane & 15, lhi = lane >> 4;
    int row0 = blockIdx.x * 128;

    if (hasbn && tid < 128) { scS[tid] = scale[tid]; shS[tid] = shift[tid]; }
    if (dostats && tid < 128) { lsum[tid] = 0.f; lsumsq[tid] = 0.f; }

    f32x4 acc[4][4];
#pragma unroll
    for (int m = 0; m < 4; m++)
#pragma unroll
        for (int n = 0; n < 4; n++) acc[m][n] = (f32x4){0.f, 0.f, 0.f, 0.f};

    for (int ks = 0; ks < 8; ++ks) {
        int kg = ks * 32;
        bool self = (kg >= 128);
        const ushort* Asrc = self ? Ac : Am;
        int ka = kg & 127;
        bool doBN = self && hasbn;
        __syncthreads();
#pragma unroll
        for (int h = 0; h < 2; ++h) {
            int c = tid + h * 256;
            int row = c >> 2, q = c & 3;
            int gr = row0 + row;
            uint4 v = {0, 0, 0, 0};
            if (gr < N_NODES)
                v = *reinterpret_cast<const uint4*>(Asrc + (size_t)gr * 128 + ka + q * 8);
            if (doBN) {
                int cc = ka + q * 8;
                v.x = bnpack(v.x, scS[cc + 0], shS[cc + 0], scS[cc + 1], shS[cc + 1]);
                v.y = bnpack(v.y, scS[cc + 2], shS[cc + 2], scS[cc + 3], shS[cc + 3]);
                v.z = bnpack(v.z, scS[cc + 4], shS[cc + 4], scS[cc + 5], shS[cc + 5]);
                v.w = bnpack(v.w, scS[cc + 6], shS[cc + 6], scS[cc + 7], shS[cc + 7]);
            }
            *reinterpret_cast<uint4*>(&As[row * 40 + q * 8]) = v;
        }
#pragma unroll
        for (int h = 0; h < 2; ++h) {
            int c = tid + h * 256;
            int n = c >> 2, q = c & 3;
            *reinterpret_cast<uint4*>(&Bs[n * 40 + q * 8]) =
                *reinterpret_cast<const uint4*>(Wcat + n * 256 + kg + q * 8);
        }
        __syncthreads();
        bf16x8 a[4], b[4];
#pragma unroll
        for (int m = 0; m < 4; m++)
            a[m] = *reinterpret_cast<bf16x8*>(&As[(wr * 64 + m * 16 + l15) * 40 + lhi * 8]);
#pragma unroll
        for (int n = 0; n < 4; n++)
            b[n] = *reinterpret_cast<bf16x8*>(&Bs[(wc * 64 + n * 16 + l15) * 40 + lhi * 8]);
#pragma unroll
        for (int m = 0; m < 4; m++)
#pragma unroll
            for (int n = 0; n < 4; n++)
                acc[m][n] = __builtin_amdgcn_mfma_f32_16x16x32_bf16(a[m], b[n], acc[m][n], 0, 0, 0);
    }
    // epilogue: + bias, bf16 store, per-column stats partials
    float ps[4] = {0.f, 0.f, 0.f, 0.f}, ps2[4] = {0.f, 0.f, 0.f, 0.f};
#pragma unroll
    for (int m = 0; m < 4; m++) {
        int rbase = row0 + wr * 64 + m * 16 + lhi * 4;
#pragma unroll
        for (int n = 0; n < 4; n++) {
            int col = wc * 64 + n * 16 + l15;
            float bv = bias[col];
#pragma unroll
            for (int j = 0; j < 4; j++) {
                int gr = rbase + j;
                if (gr < N_NODES) {
                    float v = acc[m][n][j] + bv;
                    out[(size_t)gr * 128 + col] = f2bf(v);
                    ps[n] += v;
                    ps2[n] += v * v;
                }
            }
        }
    }
    if (dostats) {
#pragma unroll
        for (int n = 0; n < 4; n++) {
            ps[n] += __shfl_xor(ps[n], 16, 64);
            ps2[n] += __shfl_xor(ps2[n], 16, 64);
            ps[n] += __shfl_xor(ps[n], 32, 64);
            ps2[n] += __shfl_xor(ps2[n], 32, 64);
        }
        if (lhi == 0) {
#pragma unroll
            for (int n = 0; n < 4; n++) {
                int col = wc * 64 + n * 16 + l15;
                atomicAdd(&lsum[col], ps[n]);
                atomicAdd(&lsumsq[col], ps2[n]);
            }
        }
        __syncthreads();
        if (tid < 128) {
            atomicAdd(&csum[tid], lsum[tid]);
            atomicAdd(&csumsq[tid], lsumsq[tid]);
        }
    }
}

// ---------------- layer-3 MFMA GEMM (LDS-staged) + bias + log_softmax fused ----------------
__global__ __launch_bounds__(256) void k_gemm40_mfma(const ushort* __restrict__ Am,
                                                     const ushort* __restrict__ Ac,
                                                     const ushort* __restrict__ Wcat, // [48][256]
                                                     const float* __restrict__ bias,  // [40]
                                                     const float* __restrict__ scale,
                                                     const float* __restrict__ shift,
                                                     float* __restrict__ out) {
    __shared__ ushort As[128 * 40];
    __shared__ ushort Bs[48 * 40];
    __shared__ float scS[128], shS[128];
    int tid = threadIdx.x;
    int w = tid >> 6, lane = tid & 63;
    int l15 = lane & 15, lhi = lane >> 4;
    int row0 = blockIdx.x * 128;

    if (tid < 128) { scS[tid] = scale[tid]; shS[tid] = shift[tid]; }

    f32x4 acc[2][3];
#pragma unroll
    for (int m = 0; m < 2; m++)
#pragma unroll
        for (int n = 0; n < 3; n++) acc[m][n] = (f32x4){0.f, 0.f, 0.f, 0.f};

    for (int ks = 0; ks < 8; ++ks) {
        int kg = ks * 32;
        bool self = (kg >= 128);
        const ushort* Asrc = self ? Ac : Am;
        int ka = kg & 127;
        __syncthreads();
#pragma unroll
        for (int h = 0; h < 2; ++h) {
            int c = tid + h * 256;
            int row = c >> 2, q = c & 3;
            int gr = row0 + row;
            uint4 v = {0, 0, 0, 0};
            if (gr < N_NODES)
                v = *reinterpret_cast<const uint4*>(Asrc + (size_t)gr * 128 + ka + q * 8);
            if (self) {
                int cc = ka + q * 8;
                v.x = bnpack(v.x, scS[cc + 0], shS[cc + 0], scS[cc + 1], shS[cc + 1]);
                v.y = bnpack(v.y, scS[cc + 2], shS[cc + 2], scS[cc + 3], shS[cc + 3]);
                v.z = bnpack(v.z, scS[cc + 4], shS[cc + 4], scS[cc + 5], shS[cc + 5]);
                v.w = bnpack(v.w, scS[cc + 6], shS[cc + 6], scS[cc + 7], shS[cc + 7]);
            }
            *reinterpret_cast<uint4*>(&As[row * 40 + q * 8]) = v;
        }
        if (tid < 192) {
            int n = tid >> 2, q = tid & 3;
            *reinterpret_cast<uint4*>(&Bs[n * 40 + q * 8]) =
                *reinterpret_cast<const uint4*>(Wcat + n * 256 + kg + q * 8);
        }
        __syncthreads();
        bf16x8 a[2], b[3];
#pragma unroll
        for (int m = 0; m < 2; m++)
            a[m] = *reinterpret_cast<bf16x8*>(&As[(w * 32 + m * 16 + l15) * 40 + lhi * 8]);
#pragma unroll
        for (int n = 0; n < 3; n++)
            b[n] = *reinterpret_cast<bf16x8*>(&Bs[(n * 16 + l15) * 40 + lhi * 8]);
#pragma unroll
        for (int m = 0; m < 2; m++)
#pragma unroll
            for (int n = 0; n < 3; n++)
                acc[m][n] = __builtin_amdgcn_mfma_f32_16x16x32_bf16(a[m], b[n], acc[m][n], 0, 0, 0);
    }
    // epilogue: bias + log_softmax per row (row lives in a 16-lane group)
    float b0 = bias[l15];
    float b1 = bias[16 + l15];
    float b2 = (l15 < 8) ? bias[32 + l15] : 0.f;
#pragma unroll
    for (int m = 0; m < 2; m++) {
#pragma unroll
        for (int j = 0; j < 4; j++) {
            int grow = row0 + w * 32 + m * 16 + lhi * 4 + j;
            float v0 = acc[m][0][j] + b0;
            float v1 = acc[m][1][j] + b1;
            float v2 = (l15 < 8) ? (acc[m][2][j] + b2) : -INFINITY;
            float mx = fmaxf(fmaxf(v0, v1), v2);
#pragma unroll
            for (int off = 1; off < 16; off <<= 1) mx = fmaxf(mx, __shfl_xor(mx, off, 64));
            float s = expf(v0 - mx) + expf(v1 - mx) + ((l15 < 8) ? expf(v2 - mx) : 0.f);
#pragma unroll
            for (int off = 1; off < 16; off <<= 1) s += __shfl_xor(s, off, 64);
            float lg = mx + logf(s);
            if (grow < N_NODES) {
                out[(size_t)grow * DOUT + l15] = v0 - lg;
                out[(size_t)grow * DOUT + 16 + l15] = v1 - lg;
                if (l15 < 8) out[(size_t)grow * DOUT + 32 + l15] = v2 - lg;
            }
        }
    }
}

// bnfin also RE-ZEROES the stats accumulators after consuming them (saves memsets)
__global__ void k_bnfin(float* __restrict__ sum, float* __restrict__ sumsq,
                        const float* __restrict__ g, const float* __restrict__ be,
                        float* __restrict__ scale, float* __restrict__ shift) {
    int c = threadIdx.x;
    if (c < DIM) {
        float mu = sum[c] * (1.0f / N_NODES);
        float var = sumsq[c] * (1.0f / N_NODES) - mu * mu;
        float sc = g[c] * rsqrtf(var + BN_EPS);
        scale[c] = sc;
        shift[c] = be[c] - mu * sc;
        sum[c] = 0.f;
        sumsq[c] = 0.f;
    }
}

// ---------------- launch ----------------
extern "C" void kernel_launch(void* const* d_in, const int* in_sizes, int n_in,
                              void* d_out, int out_size, void* d_ws, size_t ws_size,
                              hipStream_t stream) {
    const float* x = (const float*)d_in[0];
    const int* ei = (const int*)d_in[1];
    const float* w1 = (const float*)d_in[2];
    const float* r1 = (const float*)d_in[3];
    const float* b1 = (const float*)d_in[4];
    const float* g1 = (const float*)d_in[5];
    const float* be1 = (const float*)d_in[6];
    const float* w2 = (const float*)d_in[7];
    const float* r2 = (const float*)d_in[8];
    const float* b2 = (const float*)d_in[9];
    const float* g2 = (const float*)d_in[10];
    const float* be2 = (const float*)d_in[11];
    const float* w3 = (const float*)d_in[12];
    const float* r3 = (const float*)d_in[13];
    const float* b3 = (const float*)d_in[14];
    float* out = (float*)d_out;

    const size_t NF = (size_t)N_NODES * DIM;  // 12.8M
    ushort* Xb = (ushort*)d_ws;
    ushort* Ab = Xb + NF;
    ushort* Bb = Ab + NF;
    ushort* Wc1 = Bb + NF;             // 128*256
    ushort* Wc2 = Wc1 + 128 * 256;
    ushort* Wc3 = Wc2 + 128 * 256;     // 48*256
    uint* bucketbuf = (uint*)(Wc3 + 48 * 256);   // NB*BCAP = 2.048M uints
    int* gcnt = (int*)(bucketbuf + (size_t)NB * BCAP);  // NB
    int* bbase = gcnt + NB;                       // NB+1
    int* rowstart = bbase + NB + 1;               // N+1
    int* csr = rowstart + (N_NODES + 1);          // E
    float* colsum = (float*)(csr + N_EDGES);      // 128
    float* colsumsq = colsum + 128;
    float* scaleS = colsumsq + 128;
    float* shiftS = scaleS + 128;
    size_t needed = (size_t)((char*)(shiftS + 128) - (char*)d_ws);
    if (ws_size < needed) return;

    const int AGG_BLOCKS = N_NODES / 4;               // 25000
    const int GEMM_BLOCKS = (N_NODES + 127) / 128;    // 782

    // conversions
    k_cvt<<<2048, 256, 0, stream>>>(x, Xb, (int)(NF / 4));
    k_wcat<<<128, 256, 0, stream>>>(w1, r1, Wc1, 128);
    k_wcat<<<128, 256, 0, stream>>>(w2, r2, Wc2, 128);
    k_wcat<<<48, 256, 0, stream>>>(w3, r3, Wc3, DOUT);

    // CSR build (bucketed, 2-pass); zero gcnt + colsum/colsumsq in one memset (adjacent? no)
    hipMemsetAsync(gcnt, 0, sizeof(int) * NB, stream);
    hipMemsetAsync(colsum, 0, sizeof(float) * 256, stream);  // once; bnfin re-zeroes after use
    k_bucket<<<256, 256, 0, stream>>>(ei, bucketbuf, gcnt);
    k_bscan<<<1, 64, 0, stream>>>(gcnt, bbase);
    k_csr_build<<<NB, 256, 0, stream>>>(ei, bucketbuf, gcnt, bbase, rowstart, csr);

    // ---- layer 1 ----  (h1 = gemm output, PRE-BN, in Ab; stats fused)
    k_agg_bf<<<AGG_BLOCKS, 256, 0, stream>>>(Xb, rowstart, csr, Ab, nullptr, nullptr, 0);
    k_gemm_mfma<<<GEMM_BLOCKS, 256, 0, stream>>>(Ab, Xb, Wc1, b1, nullptr, nullptr, 0, Ab,
                                                 colsum, colsumsq, 1);
    k_bnfin<<<1, 128, 0, stream>>>(colsum, colsumsq, g1, be1, scaleS, shiftS);  // BN1 (+re-zero)

    // ---- layer 2 ----  (consumers apply BN1+ReLU on the fly; stats fused)
    k_agg_bf<<<AGG_BLOCKS, 256, 0, stream>>>(Ab, rowstart, csr, Bb, scaleS, shiftS, 1);
    k_gemm_mfma<<<GEMM_BLOCKS, 256, 0, stream>>>(Bb, Ab, Wc2, b2, scaleS, shiftS, 1, Bb,
                                                 colsum, colsumsq, 1);
    k_bnfin<<<1, 128, 0, stream>>>(colsum, colsumsq, g2, be2, scaleS, shiftS);  // BN2 (+re-zero)

    // ---- layer 3 ----  (consumers apply BN2+ReLU; bias + log_softmax fused)
    k_agg_bf<<<AGG_BLOCKS, 256, 0, stream>>>(Bb, rowstart, csr, Ab, scaleS, shiftS, 1);
    k_gemm40_mfma<<<GEMM_BLOCKS, 256, 0, stream>>>(Ab, Bb, Wc3, b3, scaleS, shiftS, out);
}

// Round 11
// 438.997 us; speedup vs baseline: 1.1389x; 1.0318x over previous
//
#include <hip/hip_runtime.h>
#include <cstdint>
#include <cstddef>
#include <math.h>

#define N_NODES 100000
#define N_EDGES 1600000
#define DIM 128
#define DOUT 40
#define BN_EPS 1e-5f

// bucketed CSR build
#define NB 250          // buckets
#define NPB 400         // nodes per bucket (250*400 = 100000 exactly)
#define BCAP 8192       // bucket capacity (mean 6400 -> huge headroom)

typedef __attribute__((ext_vector_type(8))) short bf16x8;
typedef __attribute__((ext_vector_type(4))) float f32x4;

__device__ __forceinline__ float bf2f(uint u16shifted) {
    union { uint i; float f; } c; c.i = u16shifted; return c.f;
}
__device__ __forceinline__ ushort f2bf(float f) {
    union { float f; uint i; } c; c.f = f;
    uint i = c.i;
    uint lsb = (i >> 16) & 1u;
    i += 0x7FFFu + lsb;
    return (ushort)(i >> 16);
}
__device__ __forceinline__ uint bnpack(uint u, float s0, float h0, float s1, float h1) {
    float lo = fmaxf(bf2f(u << 16) * s0 + h0, 0.f);
    float hi = fmaxf(bf2f(u & 0xFFFF0000u) * s1 + h1, 0.f);
    return (uint)f2bf(lo) | ((uint)f2bf(hi) << 16);
}

// ---------------- fused prep: x->bf16 cvt (blocks 0..2047) + 3x wcat ----------------
__device__ __forceinline__ void wcat_body(const float* __restrict__ W,
                                          const float* __restrict__ R,
                                          ushort* __restrict__ out, int NW, int blk) {
    int idx = blk * 256 + threadIdx.x;
    int n = idx >> 8, k = idx & 255;
    float v = 0.f;
    if (n < NW) v = (k < 128) ? W[k * NW + n] : R[(k - 128) * NW + n];
    out[idx] = f2bf(v);
}

__global__ __launch_bounds__(256) void k_prep(const float* __restrict__ x,
                                              ushort* __restrict__ Xb,
                                              const float* __restrict__ w1, const float* __restrict__ r1, ushort* __restrict__ Wc1,
                                              const float* __restrict__ w2, const float* __restrict__ r2, ushort* __restrict__ Wc2,
                                              const float* __restrict__ w3, const float* __restrict__ r3, ushort* __restrict__ Wc3) {
    int b = blockIdx.x;
    if (b < 2048) {
        int n4 = N_NODES * DIM / 4;
        int i = b * 256 + threadIdx.x;
        int stride = 2048 * 256;
        for (; i < n4; i += stride) {
            float4 v = reinterpret_cast<const float4*>(x)[i];
            ushort4 o;
            o.x = f2bf(v.x); o.y = f2bf(v.y); o.z = f2bf(v.z); o.w = f2bf(v.w);
            reinterpret_cast<ushort4*>(Xb)[i] = o;
        }
    } else if (b < 2048 + 128) {
        wcat_body(w1, r1, Wc1, 128, b - 2048);
    } else if (b < 2048 + 256) {
        wcat_body(w2, r2, Wc2, 128, b - 2176);
    } else {
        wcat_body(w3, r3, Wc3, DOUT, b - 2304);
    }
}

// ---------------- CSR pass A: partition edges into dst-buckets ----------------
__global__ __launch_bounds__(256) void k_bucket(const int* __restrict__ ei,
                                                uint* __restrict__ bucketbuf,
                                                int* __restrict__ gcnt) {
    __shared__ int hist[NB];
    __shared__ int base_[NB];
    int tid = threadIdx.x;
    for (int i = tid; i < NB; i += 256) hist[i] = 0;
    __syncthreads();
    const int EPB = N_EDGES / 256;  // 6250
    int e0 = blockIdx.x * EPB, e1 = e0 + EPB;
    for (int e = e0 + tid; e < e1; e += 256) {
        int d = ei[N_EDGES + e];
        atomicAdd(&hist[d / NPB], 1);
    }
    __syncthreads();
    for (int i = tid; i < NB; i += 256) base_[i] = atomicAdd(&gcnt[i], hist[i]);
    __syncthreads();
    for (int i = tid; i < NB; i += 256) hist[i] = 0;
    __syncthreads();
    for (int e = e0 + tid; e < e1; e += 256) {
        int d = ei[N_EDGES + e];
        int s = ei[e];
        int b = d / NPB;
        int pos = base_[b] + atomicAdd(&hist[b], 1);
        if (pos < BCAP)
            bucketbuf[(size_t)b * BCAP + pos] = ((uint)(d - b * NPB) << 17) | (uint)s;
    }
}

__global__ void k_bscan(const int* __restrict__ gcnt, int* __restrict__ bbase) {
    if (threadIdx.x == 0) {
        int run = 0;
        for (int b = 0; b < NB; b++) { bbase[b] = run; run += gcnt[b]; }
        bbase[NB] = run;
    }
}

// ---------------- CSR pass B: per-bucket CSR entirely in LDS, stream out ----------------
__global__ __launch_bounds__(256) void k_csr_build(const int* __restrict__ ei,
                                                   const uint* __restrict__ bucketbuf,
                                                   const int* __restrict__ gcnt,
                                                   const int* __restrict__ bbase,
                                                   int* __restrict__ rowstart,
                                                   int* __restrict__ csr) {
    __shared__ int cnts[NPB + 1];
    __shared__ int lcur[NPB];
    __shared__ int csr_l[BCAP];
    int b = blockIdx.x, tid = threadIdx.x;
    int cnt = gcnt[b];
    int base = bbase[b];
    int lo = b * NPB;
    bool fits = (cnt <= BCAP);
    for (int i = tid; i < NPB; i += 256) cnts[i] = 0;
    __syncthreads();
    if (fits) {
        for (int i = tid; i < cnt; i += 256)
            atomicAdd(&cnts[bucketbuf[(size_t)b * BCAP + i] >> 17], 1);
    } else {
        for (int e = tid; e < N_EDGES; e += 256) {
            int d = ei[N_EDGES + e];
            if (d >= lo && d < lo + NPB) atomicAdd(&cnts[d - lo], 1);
        }
    }
    __syncthreads();
    if (tid == 0) {
        int run = 0;
        for (int i = 0; i < NPB; i++) { int c = cnts[i]; cnts[i] = run; run += c; }
        cnts[NPB] = run;
    }
    __syncthreads();
    for (int i = tid; i < NPB; i += 256) rowstart[lo + i] = base + cnts[i];
    if (b == NB - 1 && tid == 0) rowstart[N_NODES] = base + cnts[NPB];
    for (int i = tid; i < NPB; i += 256) lcur[i] = 0;
    __syncthreads();
    if (fits) {
        for (int i = tid; i < cnt; i += 256) {
            uint p = bucketbuf[(size_t)b * BCAP + i];
            int dl = p >> 17;
            int pos = cnts[dl] + atomicAdd(&lcur[dl], 1);
            csr_l[pos] = (int)(p & 0x1FFFFu);
        }
        __syncthreads();
        for (int i = tid; i < cnt; i += 256) csr[base + i] = csr_l[i];
    } else {
        for (int e = tid; e < N_EDGES; e += 256) {
            int d = ei[N_EDGES + e];
            if (d >= lo && d < lo + NPB) {
                int dl = d - lo;
                int pos = cnts[dl] + atomicAdd(&lcur[dl], 1);
                csr[base + pos] = ei[e];
            }
        }
    }
}

// ---------------- mean aggregation, bf16, 4 edges in flight, BN+ReLU from raw stats -------
__global__ __launch_bounds__(256) void k_agg_bf(const ushort* __restrict__ cur,
                                                const int* __restrict__ rowstart,
                                                const int* __restrict__ csr,
                                                ushort* __restrict__ out,
                                                const float* __restrict__ stats,  // [sum(128), sumsq(128)]
                                                const float* __restrict__ g,
                                                const float* __restrict__ be,
                                                int hasbn) {
    int wid = (blockIdx.x * blockDim.x + threadIdx.x) >> 6;
    int lane = threadIdx.x & 63;
    if (wid >= N_NODES) return;
    int beg = rowstart[wid];
    int end = rowstart[wid + 1];
    int slot = lane >> 4;   // which edge within a group of 4
    int cg = lane & 15;     // column group: cols cg*8 .. cg*8+7
    float scv[8], shv[8];
#pragma unroll
    for (int j = 0; j < 8; j++) { scv[j] = 1.f; shv[j] = 0.f; }
    if (hasbn) {
        int c0 = cg * 8;
#pragma unroll
        for (int j = 0; j < 8; j++) {
            int c = c0 + j;
            float mu = stats[c] * (1.0f / N_NODES);
            float var = stats[128 + c] * (1.0f / N_NODES) - mu * mu;
            float sc = g[c] * rsqrtf(var + BN_EPS);
            scv[j] = sc;
            shv[j] = be[c] - mu * sc;
        }
    }
    const uint4* base = reinterpret_cast<const uint4*>(cur);
    float a0 = 0.f, a1 = 0.f, a2 = 0.f, a3 = 0.f, a4 = 0.f, a5 = 0.f, a6 = 0.f, a7 = 0.f;
#pragma unroll 2
    for (int e = beg + slot; e < end; e += 4) {
        int s = csr[e];
        uint4 u = base[(size_t)s * 16 + cg];
        float v0 = bf2f(u.x << 16), v1 = bf2f(u.x & 0xFFFF0000u);
        float v2 = bf2f(u.y << 16), v3 = bf2f(u.y & 0xFFFF0000u);
        float v4 = bf2f(u.z << 16), v5 = bf2f(u.z & 0xFFFF0000u);
        float v6 = bf2f(u.w << 16), v7 = bf2f(u.w & 0xFFFF0000u);
        if (hasbn) {
            v0 = fmaxf(v0 * scv[0] + shv[0], 0.f); v1 = fmaxf(v1 * scv[1] + shv[1], 0.f);
            v2 = fmaxf(v2 * scv[2] + shv[2], 0.f); v3 = fmaxf(v3 * scv[3] + shv[3], 0.f);
            v4 = fmaxf(v4 * scv[4] + shv[4], 0.f); v5 = fmaxf(v5 * scv[5] + shv[5], 0.f);
            v6 = fmaxf(v6 * scv[6] + shv[6], 0.f); v7 = fmaxf(v7 * scv[7] + shv[7], 0.f);
        }
        a0 += v0; a1 += v1; a2 += v2; a3 += v3;
        a4 += v4; a5 += v5; a6 += v6; a7 += v7;
    }
#pragma unroll
    for (int off = 16; off < 64; off <<= 1) {
        a0 += __shfl_xor(a0, off, 64); a1 += __shfl_xor(a1, off, 64);
        a2 += __shfl_xor(a2, off, 64); a3 += __shfl_xor(a3, off, 64);
        a4 += __shfl_xor(a4, off, 64); a5 += __shfl_xor(a5, off, 64);
        a6 += __shfl_xor(a6, off, 64); a7 += __shfl_xor(a7, off, 64);
    }
    if (slot == 0) {
        int deg = end - beg;
        float inv = 1.0f / (float)(deg > 1 ? deg : 1);
        uint4 o;
        o.x = (uint)f2bf(a0 * inv) | ((uint)f2bf(a1 * inv) << 16);
        o.y = (uint)f2bf(a2 * inv) | ((uint)f2bf(a3 * inv) << 16);
        o.z = (uint)f2bf(a4 * inv) | ((uint)f2bf(a5 * inv) << 16);
        o.w = (uint)f2bf(a6 * inv) | ((uint)f2bf(a7 * inv) << 16);
        reinterpret_cast<uint4*>(out)[(size_t)wid * 16 + cg] = o;
    }
}

// ---------------- MFMA GEMM v2: ONE-SHOT A staging, zero K-loop barriers ----------------
// out[M,128] = mean@W + bnrelu(cur)@R + b, fused col-stats.
// Both A halves staged to LDS once (stride 136 -> bank-uniform b128 reads);
// B fragments register-direct from L2-resident Wcat. 3 barriers total per block.
__global__ __launch_bounds__(256, 2) void k_gemm_mfma(const ushort* __restrict__ Am,
                                                      const ushort* __restrict__ Ac,
                                                      const ushort* __restrict__ Wcat, // [128][256]
                                                      const float* __restrict__ bias,
                                                      const float* __restrict__ stats_in,
                                                      const float* __restrict__ g,
                                                      const float* __restrict__ be,
                                                      int hasbn,
                                                      ushort* __restrict__ out,
                                                      float* __restrict__ stats_out,
                                                      int dostats) {
    __shared__ ushort A2[2][128][136];   // 69.6 KB
    __shared__ float scS[128], shS[128];
    __shared__ float lsum[128], lsumsq[128];
    int tid = threadIdx.x;
    int wid = tid >> 6, lane = tid & 63;
    int wr = wid >> 1, wc = wid & 1;
    int l15 = lane & 15, lhi = lane >> 4;
    int row0 = blockIdx.x * 128;

    if (tid < 128) {
        if (hasbn) {
            float mu = stats_in[tid] * (1.0f / N_NODES);
            float var = stats_in[128 + tid] * (1.0f / N_NODES) - mu * mu;
            float sc = g[tid] * rsqrtf(var + BN_EPS);
            scS[tid] = sc;
            shS[tid] = be[tid] - mu * sc;
        }
        lsum[tid] = 0.f;
        lsumsq[tid] = 0.f;
    }
    __syncthreads();

    // one-shot staging of both A halves (h=0: mean, h=1: self w/ BN+ReLU)
    for (int h = 0; h < 2; ++h) {
        const ushort* Asrc = h ? Ac : Am;
        bool doBN = (h == 1) && hasbn;
#pragma unroll
        for (int i = 0; i < 8; ++i) {
            int idx = i * 256 + tid;
            int row = idx >> 4, q = idx & 15;
            int gr = row0 + row;
            uint4 v = {0, 0, 0, 0};
            if (gr < N_NODES)
                v = *reinterpret_cast<const uint4*>(Asrc + (size_t)gr * 128 + q * 8);
            if (doBN) {
                int cc = q * 8;
                v.x = bnpack(v.x, scS[cc + 0], shS[cc + 0], scS[cc + 1], shS[cc + 1]);
                v.y = bnpack(v.y, scS[cc + 2], shS[cc + 2], scS[cc + 3], shS[cc + 3]);
                v.z = bnpack(v.z, scS[cc + 4], shS[cc + 4], scS[cc + 5], shS[cc + 5]);
                v.w = bnpack(v.w, scS[cc + 6], shS[cc + 6], scS[cc + 7], shS[cc + 7]);
            }
            *reinterpret_cast<uint4*>(&A2[h][row][q * 8]) = v;
        }
    }
    __syncthreads();

    f32x4 acc[4][4];
#pragma unroll
    for (int m = 0; m < 4; m++)
#pragma unroll
        for (int n = 0; n < 4; n++) acc[m][n] = (f32x4){0.f, 0.f, 0.f, 0.f};

#pragma unroll
    for (int ks = 0; ks < 8; ++ks) {
        int kg = ks * 32;
        int half = kg >> 7;
        int ka = (kg & 127) + lhi * 8;
        bf16x8 a[4], b[4];
#pragma unroll
        for (int m = 0; m < 4; m++)
            a[m] = *reinterpret_cast<bf16x8*>(&A2[half][wr * 64 + m * 16 + l15][ka]);
#pragma unroll
        for (int n = 0; n < 4; n++)
            b[n] = *reinterpret_cast<const bf16x8*>(Wcat + (wc * 64 + n * 16 + l15) * 256 + kg + lhi * 8);
#pragma unroll
        for (int m = 0; m < 4; m++)
#pragma unroll
            for (int n = 0; n < 4; n++)
                acc[m][n] = __builtin_amdgcn_mfma_f32_16x16x32_bf16(a[m], b[n], acc[m][n], 0, 0, 0);
    }
    // epilogue: + bias, bf16 store, per-column stats partials
    float ps[4] = {0.f, 0.f, 0.f, 0.f}, ps2[4] = {0.f, 0.f, 0.f, 0.f};
#pragma unroll
    for (int m = 0; m < 4; m++) {
        int rbase = row0 + wr * 64 + m * 16 + lhi * 4;
#pragma unroll
        for (int n = 0; n < 4; n++) {
            int col = wc * 64 + n * 16 + l15;
            float bv = bias[col];
#pragma unroll
            for (int j = 0; j < 4; j++) {
                int gr = rbase + j;
                if (gr < N_NODES) {
                    float v = acc[m][n][j] + bv;
                    out[(size_t)gr * 128 + col] = f2bf(v);
                    ps[n] += v;
                    ps2[n] += v * v;
                }
            }
        }
    }
    if (dostats) {
#pragma unroll
        for (int n = 0; n < 4; n++) {
            ps[n] += __shfl_xor(ps[n], 16, 64);
            ps2[n] += __shfl_xor(ps2[n], 16, 64);
            ps[n] += __shfl_xor(ps[n], 32, 64);
            ps2[n] += __shfl_xor(ps2[n], 32, 64);
        }
        if (lhi == 0) {
#pragma unroll
            for (int n = 0; n < 4; n++) {
                int col = wc * 64 + n * 16 + l15;
                atomicAdd(&lsum[col], ps[n]);
                atomicAdd(&lsumsq[col], ps2[n]);
            }
        }
        __syncthreads();
        if (tid < 128) {
            atomicAdd(&stats_out[tid], lsum[tid]);
            atomicAdd(&stats_out[128 + tid], lsumsq[tid]);
        }
    }
}

// ---------------- layer-3 GEMM v2: one-shot A staging + bias + log_softmax fused ----------
__global__ __launch_bounds__(256, 2) void k_gemm40_mfma(const ushort* __restrict__ Am,
                                                        const ushort* __restrict__ Ac,
                                                        const ushort* __restrict__ Wcat, // [48][256]
                                                        const float* __restrict__ bias,  // [40]
                                                        const float* __restrict__ stats_in,
                                                        const float* __restrict__ g,
                                                        const float* __restrict__ be,
                                                        float* __restrict__ out) {
    __shared__ ushort A2[2][128][136];
    __shared__ float scS[128], shS[128];
    int tid = threadIdx.x;
    int w = tid >> 6, lane = tid & 63;
    int l15 = lane & 15, lhi = lane >> 4;
    int row0 = blockIdx.x * 128;

    if (tid < 128) {
        float mu = stats_in[tid] * (1.0f / N_NODES);
        float var = stats_in[128 + tid] * (1.0f / N_NODES) - mu * mu;
        float sc = g[tid] * rsqrtf(var + BN_EPS);
        scS[tid] = sc;
        shS[tid] = be[tid] - mu * sc;
    }
    __syncthreads();

    for (int h = 0; h < 2; ++h) {
        const ushort* Asrc = h ? Ac : Am;
#pragma unroll
        for (int i = 0; i < 8; ++i) {
            int idx = i * 256 + tid;
            int row = idx >> 4, q = idx & 15;
            int gr = row0 + row;
            uint4 v = {0, 0, 0, 0};
            if (gr < N_NODES)
                v = *reinterpret_cast<const uint4*>(Asrc + (size_t)gr * 128 + q * 8);
            if (h == 1) {
                int cc = q * 8;
                v.x = bnpack(v.x, scS[cc + 0], shS[cc + 0], scS[cc + 1], shS[cc + 1]);
                v.y = bnpack(v.y, scS[cc + 2], shS[cc + 2], scS[cc + 3], shS[cc + 3]);
                v.z = bnpack(v.z, scS[cc + 4], shS[cc + 4], scS[cc + 5], shS[cc + 5]);
                v.w = bnpack(v.w, scS[cc + 6], shS[cc + 6], scS[cc + 7], shS[cc + 7]);
            }
            *reinterpret_cast<uint4*>(&A2[h][row][q * 8]) = v;
        }
    }
    __syncthreads();

    f32x4 acc[2][3];
#pragma unroll
    for (int m = 0; m < 2; m++)
#pragma unroll
        for (int n = 0; n < 3; n++) acc[m][n] = (f32x4){0.f, 0.f, 0.f, 0.f};

#pragma unroll
    for (int ks = 0; ks < 8; ++ks) {
        int kg = ks * 32;
        int half = kg >> 7;
        int ka = (kg & 127) + lhi * 8;
        bf16x8 a[2], b[3];
#pragma unroll
        for (int m = 0; m < 2; m++)
            a[m] = *reinterpret_cast<bf16x8*>(&A2[half][w * 32 + m * 16 + l15][ka]);
#pragma unroll
        for (int n = 0; n < 3; n++)
            b[n] = *reinterpret_cast<const bf16x8*>(Wcat + (n * 16 + l15) * 256 + kg + lhi * 8);
#pragma unroll
        for (int m = 0; m < 2; m++)
#pragma unroll
            for (int n = 0; n < 3; n++)
                acc[m][n] = __builtin_amdgcn_mfma_f32_16x16x32_bf16(a[m], b[n], acc[m][n], 0, 0, 0);
    }
    // epilogue: bias + log_softmax per row (row lives in a 16-lane group)
    float b0 = bias[l15];
    float b1 = bias[16 + l15];
    float b2 = (l15 < 8) ? bias[32 + l15] : 0.f;
#pragma unroll
    for (int m = 0; m < 2; m++) {
#pragma unroll
        for (int j = 0; j < 4; j++) {
            int grow = row0 + w * 32 + m * 16 + lhi * 4 + j;
            float v0 = acc[m][0][j] + b0;
            float v1 = acc[m][1][j] + b1;
            float v2 = (l15 < 8) ? (acc[m][2][j] + b2) : -INFINITY;
            float mx = fmaxf(fmaxf(v0, v1), v2);
#pragma unroll
            for (int off = 1; off < 16; off <<= 1) mx = fmaxf(mx, __shfl_xor(mx, off, 64));
            float s = expf(v0 - mx) + expf(v1 - mx) + ((l15 < 8) ? expf(v2 - mx) : 0.f);
#pragma unroll
            for (int off = 1; off < 16; off <<= 1) s += __shfl_xor(s, off, 64);
            float lg = mx + logf(s);
            if (grow < N_NODES) {
                out[(size_t)grow * DOUT + l15] = v0 - lg;
                out[(size_t)grow * DOUT + 16 + l15] = v1 - lg;
                if (l15 < 8) out[(size_t)grow * DOUT + 32 + l15] = v2 - lg;
            }
        }
    }
}

// ---------------- launch ----------------
extern "C" void kernel_launch(void* const* d_in, const int* in_sizes, int n_in,
                              void* d_out, int out_size, void* d_ws, size_t ws_size,
                              hipStream_t stream) {
    const float* x = (const float*)d_in[0];
    const int* ei = (const int*)d_in[1];
    const float* w1 = (const float*)d_in[2];
    const float* r1 = (const float*)d_in[3];
    const float* b1 = (const float*)d_in[4];
    const float* g1 = (const float*)d_in[5];
    const float* be1 = (const float*)d_in[6];
    const float* w2 = (const float*)d_in[7];
    const float* r2 = (const float*)d_in[8];
    const float* b2 = (const float*)d_in[9];
    const float* g2 = (const float*)d_in[10];
    const float* be2 = (const float*)d_in[11];
    const float* w3 = (const float*)d_in[12];
    const float* r3 = (const float*)d_in[13];
    const float* b3 = (const float*)d_in[14];
    float* out = (float*)d_out;

    const size_t NF = (size_t)N_NODES * DIM;  // 12.8M
    ushort* Xb = (ushort*)d_ws;
    ushort* Ab = Xb + NF;
    ushort* Bb = Ab + NF;
    ushort* Wc1 = Bb + NF;             // 128*256
    ushort* Wc2 = Wc1 + 128 * 256;
    ushort* Wc3 = Wc2 + 128 * 256;     // 48*256
    uint* bucketbuf = (uint*)(Wc3 + 48 * 256);   // NB*BCAP
    int* gcnt = (int*)(bucketbuf + (size_t)NB * BCAP);  // NB
    float* statsA = (float*)(gcnt + NB);          // 256 (sum+sumsq)
    float* statsB = statsA + 256;                 // 256
    int* bbase = (int*)(statsB + 256);            // NB+1
    int* rowstart = bbase + NB + 1;               // N+1
    int* csr = rowstart + (N_NODES + 1);          // E
    size_t needed = (size_t)((char*)(csr + N_EDGES) - (char*)d_ws);
    if (ws_size < needed) return;

    const int AGG_BLOCKS = N_NODES / 4;               // 25000
    const int GEMM_BLOCKS = (N_NODES + 127) / 128;    // 782

    // prep (cvt + 3x wcat fused) and zero gcnt+stats in one memset
    k_prep<<<2352, 256, 0, stream>>>(x, Xb, w1, r1, Wc1, w2, r2, Wc2, w3, r3, Wc3);
    hipMemsetAsync(gcnt, 0, (NB + 512) * sizeof(int), stream);

    // CSR build (bucketed, 2-pass)
    k_bucket<<<256, 256, 0, stream>>>(ei, bucketbuf, gcnt);
    k_bscan<<<1, 64, 0, stream>>>(gcnt, bbase);
    k_csr_build<<<NB, 256, 0, stream>>>(ei, bucketbuf, gcnt, bbase, rowstart, csr);

    // ---- layer 1 ----  (h1 PRE-BN in Ab; stats -> statsA)
    k_agg_bf<<<AGG_BLOCKS, 256, 0, stream>>>(Xb, rowstart, csr, Ab, nullptr, nullptr, nullptr, 0);
    k_gemm_mfma<<<GEMM_BLOCKS, 256, 0, stream>>>(Ab, Xb, Wc1, b1, nullptr, nullptr, nullptr, 0,
                                                 Ab, statsA, 1);

    // ---- layer 2 ----  (consumers apply BN1+ReLU from statsA; stats -> statsB)
    k_agg_bf<<<AGG_BLOCKS, 256, 0, stream>>>(Ab, rowstart, csr, Bb, statsA, g1, be1, 1);
    k_gemm_mfma<<<GEMM_BLOCKS, 256, 0, stream>>>(Bb, Ab, Wc2, b2, statsA, g1, be1, 1,
                                                 Bb, statsB, 1);

    // ---- layer 3 ----  (consumers apply BN2+ReLU from statsB; bias + log_softmax fused)
    k_agg_bf<<<AGG_BLOCKS, 256, 0, stream>>>(Bb, rowstart, csr, Ab, statsB, g2, be2, 1);
    k_gemm40_mfma<<<GEMM_BLOCKS, 256, 0, stream>>>(Ab, Bb, Wc3, b3, statsB, g2, be2, out);
}

// Round 12
// 422.510 us; speedup vs baseline: 1.1834x; 1.0390x over previous
//
#include <hip/hip_runtime.h>
#include <cstdint>
#include <cstddef>
#include <math.h>

#define N_NODES 100000
#define N_EDGES 1600000
#define DIM 128
#define DOUT 40
#define BN_EPS 1e-5f

// bucketed CSR build
#define NB 250          // buckets
#define NPB 400         // nodes per bucket (250*400 = 100000 exactly)
#define BCAP 8192       // bucket capacity (mean 6400 -> huge headroom)

typedef __attribute__((ext_vector_type(8))) short bf16x8;
typedef __attribute__((ext_vector_type(4))) float f32x4;

__device__ __forceinline__ float bf2f(uint u16shifted) {
    union { uint i; float f; } c; c.i = u16shifted; return c.f;
}
__device__ __forceinline__ ushort f2bf(float f) {
    union { float f; uint i; } c; c.f = f;
    uint i = c.i;
    uint lsb = (i >> 16) & 1u;
    i += 0x7FFFu + lsb;
    return (ushort)(i >> 16);
}
__device__ __forceinline__ uint bnpack(uint u, float s0, float h0, float s1, float h1) {
    float lo = fmaxf(bf2f(u << 16) * s0 + h0, 0.f);
    float hi = fmaxf(bf2f(u & 0xFFFF0000u) * s1 + h1, 0.f);
    return (uint)f2bf(lo) | ((uint)f2bf(hi) << 16);
}

// Wcat FRAGMENT layout: for col-fragment fc (=col>>4) and K-step ks (=k>>5),
// fragment base = (fc*8+ks)*512 ushorts; within, lane l holds elems l*8..l*8+7
// (col = fc*16 + (l&15), k = ks*32 + (l>>4)*8 + j). B-load = base + lane*8 (1KB coalesced).
__device__ __forceinline__ void wcat_body(const float* __restrict__ W,
                                          const float* __restrict__ R,
                                          ushort* __restrict__ out, int NW, int blk) {
    int idx = blk * 256 + threadIdx.x;      // idx over Ncols*256
    int n = idx >> 8, k = idx & 255;
    float v = 0.f;
    if (n < NW) v = (k < 128) ? W[k * NW + n] : R[(k - 128) * NW + n];
    int fc = n >> 4, l15 = n & 15;
    int ks = k >> 5, lhi = (k & 31) >> 3, j = k & 7;
    out[(fc * 8 + ks) * 512 + (lhi * 16 + l15) * 8 + j] = f2bf(v);
}

// ---------------- fused prep: cvt (0..2047) + wcat x3 (2048..2351) + bucket (2352..2607) ---
__global__ __launch_bounds__(256) void k_prep(const float* __restrict__ x,
                                              ushort* __restrict__ Xb,
                                              const float* __restrict__ w1, const float* __restrict__ r1, ushort* __restrict__ Wc1,
                                              const float* __restrict__ w2, const float* __restrict__ r2, ushort* __restrict__ Wc2,
                                              const float* __restrict__ w3, const float* __restrict__ r3, ushort* __restrict__ Wc3,
                                              const int* __restrict__ ei,
                                              uint* __restrict__ bucketbuf,
                                              int* __restrict__ gcnt) {
    int b = blockIdx.x;
    int tid = threadIdx.x;
    if (b < 2048) {
        int n4 = N_NODES * DIM / 4;
        int i = b * 256 + tid;
        int stride = 2048 * 256;
        for (; i < n4; i += stride) {
            float4 v = reinterpret_cast<const float4*>(x)[i];
            ushort4 o;
            o.x = f2bf(v.x); o.y = f2bf(v.y); o.z = f2bf(v.z); o.w = f2bf(v.w);
            reinterpret_cast<ushort4*>(Xb)[i] = o;
        }
    } else if (b < 2048 + 128) {
        wcat_body(w1, r1, Wc1, 128, b - 2048);
    } else if (b < 2048 + 256) {
        wcat_body(w2, r2, Wc2, 128, b - 2176);
    } else if (b < 2048 + 304) {
        wcat_body(w3, r3, Wc3, DOUT, b - 2304);
    } else {
        // bucket pass: partition edges into dst-buckets
        __shared__ int hist[NB];
        __shared__ int base_[NB];
        int blk = b - 2352;
        for (int i = tid; i < NB; i += 256) hist[i] = 0;
        __syncthreads();
        const int EPB = N_EDGES / 256;  // 6250
        int e0 = blk * EPB, e1 = e0 + EPB;
        for (int e = e0 + tid; e < e1; e += 256) {
            int d = ei[N_EDGES + e];
            atomicAdd(&hist[d / NPB], 1);
        }
        __syncthreads();
        for (int i = tid; i < NB; i += 256) base_[i] = atomicAdd(&gcnt[i], hist[i]);
        __syncthreads();
        for (int i = tid; i < NB; i += 256) hist[i] = 0;
        __syncthreads();
        for (int e = e0 + tid; e < e1; e += 256) {
            int d = ei[N_EDGES + e];
            int s = ei[e];
            int bk = d / NPB;
            int pos = base_[bk] + atomicAdd(&hist[bk], 1);
            if (pos < BCAP)
                bucketbuf[(size_t)bk * BCAP + pos] = ((uint)(d - bk * NPB) << 17) | (uint)s;
        }
    }
}

// ---------------- CSR pass B: per-bucket CSR entirely in LDS (self-computed base) ----------
__global__ __launch_bounds__(256) void k_csr_build(const int* __restrict__ ei,
                                                   const uint* __restrict__ bucketbuf,
                                                   const int* __restrict__ gcnt,
                                                   int* __restrict__ rowstart,
                                                   int* __restrict__ csr) {
    __shared__ int cnts[NPB + 1];
    __shared__ int lcur[NPB];
    __shared__ int csr_l[BCAP];
    __shared__ int baseS;
    int b = blockIdx.x, tid = threadIdx.x;
    int cnt = gcnt[b];
    int lo = b * NPB;
    if (tid == 0) baseS = 0;
    for (int i = tid; i < NPB; i += 256) cnts[i] = 0;
    __syncthreads();
    // prefix over gcnt[0..b-1]
    int part = 0;
    for (int i = tid; i < b; i += 256) part += gcnt[i];
    if (part) atomicAdd(&baseS, part);
    bool fits = (cnt <= BCAP);
    if (fits) {
        for (int i = tid; i < cnt; i += 256)
            atomicAdd(&cnts[bucketbuf[(size_t)b * BCAP + i] >> 17], 1);
    } else {  // overflow fallback (statistically never)
        for (int e = tid; e < N_EDGES; e += 256) {
            int d = ei[N_EDGES + e];
            if (d >= lo && d < lo + NPB) atomicAdd(&cnts[d - lo], 1);
        }
    }
    __syncthreads();
    int base = baseS;
    if (tid == 0) {
        int run = 0;
        for (int i = 0; i < NPB; i++) { int c = cnts[i]; cnts[i] = run; run += c; }
        cnts[NPB] = run;
    }
    __syncthreads();
    for (int i = tid; i < NPB; i += 256) rowstart[lo + i] = base + cnts[i];
    if (b == NB - 1 && tid == 0) rowstart[N_NODES] = N_EDGES;
    for (int i = tid; i < NPB; i += 256) lcur[i] = 0;
    __syncthreads();
    if (fits) {
        for (int i = tid; i < cnt; i += 256) {
            uint p = bucketbuf[(size_t)b * BCAP + i];
            int dl = p >> 17;
            int pos = cnts[dl] + atomicAdd(&lcur[dl], 1);
            csr_l[pos] = (int)(p & 0x1FFFFu);
        }
        __syncthreads();
        for (int i = tid; i < cnt; i += 256) csr[base + i] = csr_l[i];
    } else {
        for (int e = tid; e < N_EDGES; e += 256) {
            int d = ei[N_EDGES + e];
            if (d >= lo && d < lo + NPB) {
                int dl = d - lo;
                int pos = cnts[dl] + atomicAdd(&lcur[dl], 1);
                csr[base + pos] = ei[e];
            }
        }
    }
}

// ---------------- mean aggregation, bf16, 4 edges in flight, BN+ReLU from raw stats -------
__global__ __launch_bounds__(256) void k_agg_bf(const ushort* __restrict__ cur,
                                                const int* __restrict__ rowstart,
                                                const int* __restrict__ csr,
                                                ushort* __restrict__ out,
                                                const float* __restrict__ stats,  // [sum(128), sumsq(128)]
                                                const float* __restrict__ g,
                                                const float* __restrict__ be,
                                                int hasbn) {
    int wid = (blockIdx.x * blockDim.x + threadIdx.x) >> 6;
    int lane = threadIdx.x & 63;
    if (wid >= N_NODES) return;
    int beg = rowstart[wid];
    int end = rowstart[wid + 1];
    int slot = lane >> 4;   // which edge within a group of 4
    int cg = lane & 15;     // column group: cols cg*8 .. cg*8+7
    float scv[8], shv[8];
#pragma unroll
    for (int j = 0; j < 8; j++) { scv[j] = 1.f; shv[j] = 0.f; }
    if (hasbn) {
        int c0 = cg * 8;
#pragma unroll
        for (int j = 0; j < 8; j++) {
            int c = c0 + j;
            float mu = stats[c] * (1.0f / N_NODES);
            float var = stats[128 + c] * (1.0f / N_NODES) - mu * mu;
            float sc = g[c] * rsqrtf(var + BN_EPS);
            scv[j] = sc;
            shv[j] = be[c] - mu * sc;
        }
    }
    const uint4* base = reinterpret_cast<const uint4*>(cur);
    float a0 = 0.f, a1 = 0.f, a2 = 0.f, a3 = 0.f, a4 = 0.f, a5 = 0.f, a6 = 0.f, a7 = 0.f;
#pragma unroll 2
    for (int e = beg + slot; e < end; e += 4) {
        int s = csr[e];
        uint4 u = base[(size_t)s * 16 + cg];
        float v0 = bf2f(u.x << 16), v1 = bf2f(u.x & 0xFFFF0000u);
        float v2 = bf2f(u.y << 16), v3 = bf2f(u.y & 0xFFFF0000u);
        float v4 = bf2f(u.z << 16), v5 = bf2f(u.z & 0xFFFF0000u);
        float v6 = bf2f(u.w << 16), v7 = bf2f(u.w & 0xFFFF0000u);
        if (hasbn) {
            v0 = fmaxf(v0 * scv[0] + shv[0], 0.f); v1 = fmaxf(v1 * scv[1] + shv[1], 0.f);
            v2 = fmaxf(v2 * scv[2] + shv[2], 0.f); v3 = fmaxf(v3 * scv[3] + shv[3], 0.f);
            v4 = fmaxf(v4 * scv[4] + shv[4], 0.f); v5 = fmaxf(v5 * scv[5] + shv[5], 0.f);
            v6 = fmaxf(v6 * scv[6] + shv[6], 0.f); v7 = fmaxf(v7 * scv[7] + shv[7], 0.f);
        }
        a0 += v0; a1 += v1; a2 += v2; a3 += v3;
        a4 += v4; a5 += v5; a6 += v6; a7 += v7;
    }
#pragma unroll
    for (int off = 16; off < 64; off <<= 1) {
        a0 += __shfl_xor(a0, off, 64); a1 += __shfl_xor(a1, off, 64);
        a2 += __shfl_xor(a2, off, 64); a3 += __shfl_xor(a3, off, 64);
        a4 += __shfl_xor(a4, off, 64); a5 += __shfl_xor(a5, off, 64);
        a6 += __shfl_xor(a6, off, 64); a7 += __shfl_xor(a7, off, 64);
    }
    if (slot == 0) {
        int deg = end - beg;
        float inv = 1.0f / (float)(deg > 1 ? deg : 1);
        uint4 o;
        o.x = (uint)f2bf(a0 * inv) | ((uint)f2bf(a1 * inv) << 16);
        o.y = (uint)f2bf(a2 * inv) | ((uint)f2bf(a3 * inv) << 16);
        o.z = (uint)f2bf(a4 * inv) | ((uint)f2bf(a5 * inv) << 16);
        o.w = (uint)f2bf(a6 * inv) | ((uint)f2bf(a7 * inv) << 16);
        reinterpret_cast<uint4*>(out)[(size_t)wid * 16 + cg] = o;
    }
}

// ---------------- MFMA GEMM v2: one-shot A staging, fragment-ordered B ----------------
// out[M,128] = mean@W + bnrelu(cur)@R + b, fused col-stats; 3 barriers per block.
__global__ __launch_bounds__(256, 2) void k_gemm_mfma(const ushort* __restrict__ Am,
                                                      const ushort* __restrict__ Ac,
                                                      const ushort* __restrict__ Wcat, // frag layout
                                                      const float* __restrict__ bias,
                                                      const float* __restrict__ stats_in,
                                                      const float* __restrict__ g,
                                                      const float* __restrict__ be,
                                                      int hasbn,
                                                      ushort* __restrict__ out,
                                                      float* __restrict__ stats_out,
                                                      int dostats) {
    __shared__ ushort A2[2][128][136];   // 69.6 KB
    __shared__ float scS[128], shS[128];
    __shared__ float lsum[128], lsumsq[128];
    int tid = threadIdx.x;
    int wid = tid >> 6, lane = tid & 63;
    int wr = wid >> 1, wc = wid & 1;
    int l15 = lane & 15, lhi = lane >> 4;
    int row0 = blockIdx.x * 128;

    if (tid < 128) {
        if (hasbn) {
            float mu = stats_in[tid] * (1.0f / N_NODES);
            float var = stats_in[128 + tid] * (1.0f / N_NODES) - mu * mu;
            float sc = g[tid] * rsqrtf(var + BN_EPS);
            scS[tid] = sc;
            shS[tid] = be[tid] - mu * sc;
        }
        lsum[tid] = 0.f;
        lsumsq[tid] = 0.f;
    }
    __syncthreads();

    for (int h = 0; h < 2; ++h) {
        const ushort* Asrc = h ? Ac : Am;
        bool doBN = (h == 1) && hasbn;
#pragma unroll
        for (int i = 0; i < 8; ++i) {
            int idx = i * 256 + tid;
            int row = idx >> 4, q = idx & 15;
            int gr = row0 + row;
            uint4 v = {0, 0, 0, 0};
            if (gr < N_NODES)
                v = *reinterpret_cast<const uint4*>(Asrc + (size_t)gr * 128 + q * 8);
            if (doBN) {
                int cc = q * 8;
                v.x = bnpack(v.x, scS[cc + 0], shS[cc + 0], scS[cc + 1], shS[cc + 1]);
                v.y = bnpack(v.y, scS[cc + 2], shS[cc + 2], scS[cc + 3], shS[cc + 3]);
                v.z = bnpack(v.z, scS[cc + 4], shS[cc + 4], scS[cc + 5], shS[cc + 5]);
                v.w = bnpack(v.w, scS[cc + 6], shS[cc + 6], scS[cc + 7], shS[cc + 7]);
            }
            *reinterpret_cast<uint4*>(&A2[h][row][q * 8]) = v;
        }
    }
    __syncthreads();

    f32x4 acc[4][4];
#pragma unroll
    for (int m = 0; m < 4; m++)
#pragma unroll
        for (int n = 0; n < 4; n++) acc[m][n] = (f32x4){0.f, 0.f, 0.f, 0.f};

#pragma unroll
    for (int ks = 0; ks < 8; ++ks) {
        int kg = ks * 32;
        int half = kg >> 7;
        int ka = (kg & 127) + lhi * 8;
        bf16x8 a[4], b[4];
#pragma unroll
        for (int m = 0; m < 4; m++)
            a[m] = *reinterpret_cast<bf16x8*>(&A2[half][wr * 64 + m * 16 + l15][ka]);
#pragma unroll
        for (int n = 0; n < 4; n++)
            b[n] = *reinterpret_cast<const bf16x8*>(Wcat + ((wc * 4 + n) * 8 + ks) * 512 + lane * 8);
#pragma unroll
        for (int m = 0; m < 4; m++)
#pragma unroll
            for (int n = 0; n < 4; n++)
                acc[m][n] = __builtin_amdgcn_mfma_f32_16x16x32_bf16(a[m], b[n], acc[m][n], 0, 0, 0);
    }
    // epilogue: + bias, bf16 store, per-column stats partials
    float ps[4] = {0.f, 0.f, 0.f, 0.f}, ps2[4] = {0.f, 0.f, 0.f, 0.f};
#pragma unroll
    for (int m = 0; m < 4; m++) {
        int rbase = row0 + wr * 64 + m * 16 + lhi * 4;
#pragma unroll
        for (int n = 0; n < 4; n++) {
            int col = wc * 64 + n * 16 + l15;
            float bv = bias[col];
#pragma unroll
            for (int j = 0; j < 4; j++) {
                int gr = rbase + j;
                if (gr < N_NODES) {
                    float v = acc[m][n][j] + bv;
                    out[(size_t)gr * 128 + col] = f2bf(v);
                    ps[n] += v;
                    ps2[n] += v * v;
                }
            }
        }
    }
    if (dostats) {
#pragma unroll
        for (int n = 0; n < 4; n++) {
            ps[n] += __shfl_xor(ps[n], 16, 64);
            ps2[n] += __shfl_xor(ps2[n], 16, 64);
            ps[n] += __shfl_xor(ps[n], 32, 64);
            ps2[n] += __shfl_xor(ps2[n], 32, 64);
        }
        if (lhi == 0) {
#pragma unroll
            for (int n = 0; n < 4; n++) {
                int col = wc * 64 + n * 16 + l15;
                atomicAdd(&lsum[col], ps[n]);
                atomicAdd(&lsumsq[col], ps2[n]);
            }
        }
        __syncthreads();
        if (tid < 128) {
            atomicAdd(&stats_out[tid], lsum[tid]);
            atomicAdd(&stats_out[128 + tid], lsumsq[tid]);
        }
    }
}

// ---------------- layer-3 GEMM v2: one-shot A staging + frag B + bias + log_softmax -------
__global__ __launch_bounds__(256, 2) void k_gemm40_mfma(const ushort* __restrict__ Am,
                                                        const ushort* __restrict__ Ac,
                                                        const ushort* __restrict__ Wcat, // frag layout [3 fc][8 ks][512]
                                                        const float* __restrict__ bias,  // [40]
                                                        const float* __restrict__ stats_in,
                                                        const float* __restrict__ g,
                                                        const float* __restrict__ be,
                                                        float* __restrict__ out) {
    __shared__ ushort A2[2][128][136];
    __shared__ float scS[128], shS[128];
    int tid = threadIdx.x;
    int w = tid >> 6, lane = tid & 63;
    int l15 = lane & 15, lhi = lane >> 4;
    int row0 = blockIdx.x * 128;

    if (tid < 128) {
        float mu = stats_in[tid] * (1.0f / N_NODES);
        float var = stats_in[128 + tid] * (1.0f / N_NODES) - mu * mu;
        float sc = g[tid] * rsqrtf(var + BN_EPS);
        scS[tid] = sc;
        shS[tid] = be[tid] - mu * sc;
    }
    __syncthreads();

    for (int h = 0; h < 2; ++h) {
        const ushort* Asrc = h ? Ac : Am;
#pragma unroll
        for (int i = 0; i < 8; ++i) {
            int idx = i * 256 + tid;
            int row = idx >> 4, q = idx & 15;
            int gr = row0 + row;
            uint4 v = {0, 0, 0, 0};
            if (gr < N_NODES)
                v = *reinterpret_cast<const uint4*>(Asrc + (size_t)gr * 128 + q * 8);
            if (h == 1) {
                int cc = q * 8;
                v.x = bnpack(v.x, scS[cc + 0], shS[cc + 0], scS[cc + 1], shS[cc + 1]);
                v.y = bnpack(v.y, scS[cc + 2], shS[cc + 2], scS[cc + 3], shS[cc + 3]);
                v.z = bnpack(v.z, scS[cc + 4], shS[cc + 4], scS[cc + 5], shS[cc + 5]);
                v.w = bnpack(v.w, scS[cc + 6], shS[cc + 6], scS[cc + 7], shS[cc + 7]);
            }
            *reinterpret_cast<uint4*>(&A2[h][row][q * 8]) = v;
        }
    }
    __syncthreads();

    f32x4 acc[2][3];
#pragma unroll
    for (int m = 0; m < 2; m++)
#pragma unroll
        for (int n = 0; n < 3; n++) acc[m][n] = (f32x4){0.f, 0.f, 0.f, 0.f};

#pragma unroll
    for (int ks = 0; ks < 8; ++ks) {
        int kg = ks * 32;
        int half = kg >> 7;
        int ka = (kg & 127) + lhi * 8;
        bf16x8 a[2], b[3];
#pragma unroll
        for (int m = 0; m < 2; m++)
            a[m] = *reinterpret_cast<bf16x8*>(&A2[half][w * 32 + m * 16 + l15][ka]);
#pragma unroll
        for (int n = 0; n < 3; n++)
            b[n] = *reinterpret_cast<const bf16x8*>(Wcat + (n * 8 + ks) * 512 + lane * 8);
#pragma unroll
        for (int m = 0; m < 2; m++)
#pragma unroll
            for (int n = 0; n < 3; n++)
                acc[m][n] = __builtin_amdgcn_mfma_f32_16x16x32_bf16(a[m], b[n], acc[m][n], 0, 0, 0);
    }
    // epilogue: bias + log_softmax per row (row lives in a 16-lane group)
    float b0 = bias[l15];
    float b1 = bias[16 + l15];
    float b2 = (l15 < 8) ? bias[32 + l15] : 0.f;
#pragma unroll
    for (int m = 0; m < 2; m++) {
#pragma unroll
        for (int j = 0; j < 4; j++) {
            int grow = row0 + w * 32 + m * 16 + lhi * 4 + j;
            float v0 = acc[m][0][j] + b0;
            float v1 = acc[m][1][j] + b1;
            float v2 = (l15 < 8) ? (acc[m][2][j] + b2) : -INFINITY;
            float mx = fmaxf(fmaxf(v0, v1), v2);
#pragma unroll
            for (int off = 1; off < 16; off <<= 1) mx = fmaxf(mx, __shfl_xor(mx, off, 64));
            float s = expf(v0 - mx) + expf(v1 - mx) + ((l15 < 8) ? expf(v2 - mx) : 0.f);
#pragma unroll
            for (int off = 1; off < 16; off <<= 1) s += __shfl_xor(s, off, 64);
            float lg = mx + logf(s);
            if (grow < N_NODES) {
                out[(size_t)grow * DOUT + l15] = v0 - lg;
                out[(size_t)grow * DOUT + 16 + l15] = v1 - lg;
                if (l15 < 8) out[(size_t)grow * DOUT + 32 + l15] = v2 - lg;
            }
        }
    }
}

// ---------------- launch ----------------
extern "C" void kernel_launch(void* const* d_in, const int* in_sizes, int n_in,
                              void* d_out, int out_size, void* d_ws, size_t ws_size,
                              hipStream_t stream) {
    const float* x = (const float*)d_in[0];
    const int* ei = (const int*)d_in[1];
    const float* w1 = (const float*)d_in[2];
    const float* r1 = (const float*)d_in[3];
    const float* b1 = (const float*)d_in[4];
    const float* g1 = (const float*)d_in[5];
    const float* be1 = (const float*)d_in[6];
    const float* w2 = (const float*)d_in[7];
    const float* r2 = (const float*)d_in[8];
    const float* b2 = (const float*)d_in[9];
    const float* g2 = (const float*)d_in[10];
    const float* be2 = (const float*)d_in[11];
    const float* w3 = (const float*)d_in[12];
    const float* r3 = (const float*)d_in[13];
    const float* b3 = (const float*)d_in[14];
    float* out = (float*)d_out;

    const size_t NF = (size_t)N_NODES * DIM;  // 12.8M
    ushort* Xb = (ushort*)d_ws;
    ushort* Ab = Xb + NF;
    ushort* Bb = Ab + NF;
    ushort* Wc1 = Bb + NF;             // 128*256
    ushort* Wc2 = Wc1 + 128 * 256;
    ushort* Wc3 = Wc2 + 128 * 256;     // 48*256
    uint* bucketbuf = (uint*)(Wc3 + 48 * 256);   // NB*BCAP
    int* gcnt = (int*)(bucketbuf + (size_t)NB * BCAP);  // NB
    float* statsA = (float*)(gcnt + NB);          // 256 (sum+sumsq)
    float* statsB = statsA + 256;                 // 256
    int* rowstart = (int*)(statsB + 256);         // N+1
    int* csr = rowstart + (N_NODES + 1);          // E
    size_t needed = (size_t)((char*)(csr + N_EDGES) - (char*)d_ws);
    if (ws_size < needed) return;

    const int AGG_BLOCKS = N_NODES / 4;               // 25000
    const int GEMM_BLOCKS = (N_NODES + 127) / 128;    // 782

    // zero gcnt + stats, then fused prep (cvt + wcat x3 + bucket)
    hipMemsetAsync(gcnt, 0, (NB + 512) * sizeof(int), stream);
    k_prep<<<2608, 256, 0, stream>>>(x, Xb, w1, r1, Wc1, w2, r2, Wc2, w3, r3, Wc3,
                                     ei, bucketbuf, gcnt);
    k_csr_build<<<NB, 256, 0, stream>>>(ei, bucketbuf, gcnt, rowstart, csr);

    // ---- layer 1 ----  (h1 PRE-BN in Ab; stats -> statsA)
    k_agg_bf<<<AGG_BLOCKS, 256, 0, stream>>>(Xb, rowstart, csr, Ab, nullptr, nullptr, nullptr, 0);
    k_gemm_mfma<<<GEMM_BLOCKS, 256, 0, stream>>>(Ab, Xb, Wc1, b1, nullptr, nullptr, nullptr, 0,
                                                 Ab, statsA, 1);

    // ---- layer 2 ----  (consumers apply BN1+ReLU from statsA; stats -> statsB)
    k_agg_bf<<<AGG_BLOCKS, 256, 0, stream>>>(Ab, rowstart, csr, Bb, statsA, g1, be1, 1);
    k_gemm_mfma<<<GEMM_BLOCKS, 256, 0, stream>>>(Bb, Ab, Wc2, b2, statsA, g1, be1, 1,
                                                 Bb, statsB, 1);

    // ---- layer 3 ----  (consumers apply BN2+ReLU from statsB; bias + log_softmax fused)
    k_agg_bf<<<AGG_BLOCKS, 256, 0, stream>>>(Bb, rowstart, csr, Ab, statsB, g2, be2, 1);
    k_gemm40_mfma<<<GEMM_BLOCKS, 256, 0, stream>>>(Ab, Bb, Wc3, b3, statsB, g2, be2, out);
}

// Round 13
// 384.815 us; speedup vs baseline: 1.2993x; 1.0980x over previous
//
#include <hip/hip_runtime.h>
#include <cstdint>
#include <cstddef>
#include <math.h>

#define N_NODES 100000
#define N_EDGES 1600000
#define DIM 128
#define DOUT 40
#define BN_EPS 1e-5f

// bucketed CSR build
#define NB 250          // buckets
#define NPB 400         // nodes per bucket (250*400 = 100000 exactly)
#define BCAP 8192       // bucket capacity (mean 6400 -> huge headroom)

typedef __attribute__((ext_vector_type(8))) short bf16x8;
typedef __attribute__((ext_vector_type(4))) float f32x4;

__device__ __forceinline__ float bf2f(uint u16shifted) {
    union { uint i; float f; } c; c.i = u16shifted; return c.f;
}
__device__ __forceinline__ ushort f2bf(float f) {
    union { float f; uint i; } c; c.f = f;
    uint i = c.i;
    uint lsb = (i >> 16) & 1u;
    i += 0x7FFFu + lsb;
    return (ushort)(i >> 16);
}
__device__ __forceinline__ uint bnpack(uint u, float s0, float h0, float s1, float h1) {
    float lo = fmaxf(bf2f(u << 16) * s0 + h0, 0.f);
    float hi = fmaxf(bf2f(u & 0xFFFF0000u) * s1 + h1, 0.f);
    return (uint)f2bf(lo) | ((uint)f2bf(hi) << 16);
}

// Wcat FRAGMENT layout: for col-fragment fc (=col>>4) and K-step ks (=k>>5),
// fragment base = (fc*8+ks)*512 ushorts; within, lane l holds elems l*8..l*8+7
__device__ __forceinline__ void wcat_body(const float* __restrict__ W,
                                          const float* __restrict__ R,
                                          ushort* __restrict__ out, int NW, int blk) {
    int idx = blk * 256 + threadIdx.x;      // idx over Ncols*256
    int n = idx >> 8, k = idx & 255;
    float v = 0.f;
    if (n < NW) v = (k < 128) ? W[k * NW + n] : R[(k - 128) * NW + n];
    int fc = n >> 4, l15 = n & 15;
    int ks = k >> 5, lhi = (k & 31) >> 3, j = k & 7;
    out[(fc * 8 + ks) * 512 + (lhi * 16 + l15) * 8 + j] = f2bf(v);
}

// ---------------- fused prep: cvt (0..2047) + wcat x3 (2048..2351) + bucket (2352..2607) ---
__global__ __launch_bounds__(256) void k_prep(const float* __restrict__ x,
                                              ushort* __restrict__ Xb,
                                              const float* __restrict__ w1, const float* __restrict__ r1, ushort* __restrict__ Wc1,
                                              const float* __restrict__ w2, const float* __restrict__ r2, ushort* __restrict__ Wc2,
                                              const float* __restrict__ w3, const float* __restrict__ r3, ushort* __restrict__ Wc3,
                                              const int* __restrict__ ei,
                                              uint* __restrict__ bucketbuf,
                                              int* __restrict__ gcnt) {
    int b = blockIdx.x;
    int tid = threadIdx.x;
    if (b < 2048) {
        int n4 = N_NODES * DIM / 4;
        int i = b * 256 + tid;
        int stride = 2048 * 256;
        for (; i < n4; i += stride) {
            float4 v = reinterpret_cast<const float4*>(x)[i];
            ushort4 o;
            o.x = f2bf(v.x); o.y = f2bf(v.y); o.z = f2bf(v.z); o.w = f2bf(v.w);
            reinterpret_cast<ushort4*>(Xb)[i] = o;
        }
    } else if (b < 2048 + 128) {
        wcat_body(w1, r1, Wc1, 128, b - 2048);
    } else if (b < 2048 + 256) {
        wcat_body(w2, r2, Wc2, 128, b - 2176);
    } else if (b < 2048 + 304) {
        wcat_body(w3, r3, Wc3, DOUT, b - 2304);
    } else {
        // bucket pass: partition edges into dst-buckets
        __shared__ int hist[NB];
        __shared__ int base_[NB];
        int blk = b - 2352;
        for (int i = tid; i < NB; i += 256) hist[i] = 0;
        __syncthreads();
        const int EPB = N_EDGES / 256;  // 6250
        int e0 = blk * EPB, e1 = e0 + EPB;
        for (int e = e0 + tid; e < e1; e += 256) {
            int d = ei[N_EDGES + e];
            atomicAdd(&hist[d / NPB], 1);
        }
        __syncthreads();
        for (int i = tid; i < NB; i += 256) base_[i] = atomicAdd(&gcnt[i], hist[i]);
        __syncthreads();
        for (int i = tid; i < NB; i += 256) hist[i] = 0;
        __syncthreads();
        for (int e = e0 + tid; e < e1; e += 256) {
            int d = ei[N_EDGES + e];
            int s = ei[e];
            int bk = d / NPB;
            int pos = base_[bk] + atomicAdd(&hist[bk], 1);
            if (pos < BCAP)
                bucketbuf[(size_t)bk * BCAP + pos] = ((uint)(d - bk * NPB) << 17) | (uint)s;
        }
    }
}

// ---------------- CSR pass B: per-bucket CSR entirely in LDS (self-computed base) ----------
__global__ __launch_bounds__(256) void k_csr_build(const int* __restrict__ ei,
                                                   const uint* __restrict__ bucketbuf,
                                                   const int* __restrict__ gcnt,
                                                   int* __restrict__ rowstart,
                                                   int* __restrict__ csr) {
    __shared__ int cnts[NPB + 1];
    __shared__ int lcur[NPB];
    __shared__ int csr_l[BCAP];
    __shared__ int baseS;
    int b = blockIdx.x, tid = threadIdx.x;
    int cnt = gcnt[b];
    int lo = b * NPB;
    if (tid == 0) baseS = 0;
    for (int i = tid; i < NPB; i += 256) cnts[i] = 0;
    __syncthreads();
    int part = 0;
    for (int i = tid; i < b; i += 256) part += gcnt[i];
    if (part) atomicAdd(&baseS, part);
    bool fits = (cnt <= BCAP);
    if (fits) {
        for (int i = tid; i < cnt; i += 256)
            atomicAdd(&cnts[bucketbuf[(size_t)b * BCAP + i] >> 17], 1);
    } else {  // overflow fallback (statistically never)
        for (int e = tid; e < N_EDGES; e += 256) {
            int d = ei[N_EDGES + e];
            if (d >= lo && d < lo + NPB) atomicAdd(&cnts[d - lo], 1);
        }
    }
    __syncthreads();
    int base = baseS;
    if (tid == 0) {
        int run = 0;
        for (int i = 0; i < NPB; i++) { int c = cnts[i]; cnts[i] = run; run += c; }
        cnts[NPB] = run;
    }
    __syncthreads();
    for (int i = tid; i < NPB; i += 256) rowstart[lo + i] = base + cnts[i];
    if (b == NB - 1 && tid == 0) rowstart[N_NODES] = N_EDGES;
    for (int i = tid; i < NPB; i += 256) lcur[i] = 0;
    __syncthreads();
    if (fits) {
        for (int i = tid; i < cnt; i += 256) {
            uint p = bucketbuf[(size_t)b * BCAP + i];
            int dl = p >> 17;
            int pos = cnts[dl] + atomicAdd(&lcur[dl], 1);
            csr_l[pos] = (int)(p & 0x1FFFFu);
        }
        __syncthreads();
        for (int i = tid; i < cnt; i += 256) csr[base + i] = csr_l[i];
    } else {
        for (int e = tid; e < N_EDGES; e += 256) {
            int d = ei[N_EDGES + e];
            if (d >= lo && d < lo + NPB) {
                int dl = d - lo;
                int pos = cnts[dl] + atomicAdd(&lcur[dl], 1);
                csr[base + pos] = ei[e];
            }
        }
    }
}

// ---------------- BN+ReLU materialization, in-place, vectorized ----------------
__global__ __launch_bounds__(256) void k_bnrelu(ushort* __restrict__ H,
                                                const float* __restrict__ stats,
                                                const float* __restrict__ g,
                                                const float* __restrict__ be) {
    __shared__ float scS[128], shS[128];
    int tid = threadIdx.x;
    if (tid < 128) {
        float mu = stats[tid] * (1.0f / N_NODES);
        float var = stats[128 + tid] * (1.0f / N_NODES) - mu * mu;
        float sc = g[tid] * rsqrtf(var + BN_EPS);
        scS[tid] = sc;
        shS[tid] = be[tid] - mu * sc;
    }
    __syncthreads();
    uint4* H4 = reinterpret_cast<uint4*>(H);
    const int total = N_NODES * 16;   // uint4 per row = 16
    for (int i = blockIdx.x * 256 + tid; i < total; i += gridDim.x * 256) {
        uint4 u = H4[i];
        int c0 = (i & 15) * 8;
        u.x = bnpack(u.x, scS[c0 + 0], shS[c0 + 0], scS[c0 + 1], shS[c0 + 1]);
        u.y = bnpack(u.y, scS[c0 + 2], shS[c0 + 2], scS[c0 + 3], shS[c0 + 3]);
        u.z = bnpack(u.z, scS[c0 + 4], shS[c0 + 4], scS[c0 + 5], shS[c0 + 5]);
        u.w = bnpack(u.w, scS[c0 + 6], shS[c0 + 6], scS[c0 + 7], shS[c0 + 7]);
        H4[i] = u;
    }
}

// ---------------- mean aggregation, bf16, 4 edges in flight (no BN — pure unpack+add) ------
__global__ __launch_bounds__(256) void k_agg_bf(const ushort* __restrict__ cur,
                                                const int* __restrict__ rowstart,
                                                const int* __restrict__ csr,
                                                ushort* __restrict__ out) {
    int wid = (blockIdx.x * blockDim.x + threadIdx.x) >> 6;
    int lane = threadIdx.x & 63;
    if (wid >= N_NODES) return;
    int beg = rowstart[wid];
    int end = rowstart[wid + 1];
    int slot = lane >> 4;   // which edge within a group of 4
    int cg = lane & 15;     // column group: cols cg*8 .. cg*8+7
    const uint4* base = reinterpret_cast<const uint4*>(cur);
    float a0 = 0.f, a1 = 0.f, a2 = 0.f, a3 = 0.f, a4 = 0.f, a5 = 0.f, a6 = 0.f, a7 = 0.f;
#pragma unroll 2
    for (int e = beg + slot; e < end; e += 4) {
        int s = csr[e];
        uint4 u = base[(size_t)s * 16 + cg];
        a0 += bf2f(u.x << 16); a1 += bf2f(u.x & 0xFFFF0000u);
        a2 += bf2f(u.y << 16); a3 += bf2f(u.y & 0xFFFF0000u);
        a4 += bf2f(u.z << 16); a5 += bf2f(u.z & 0xFFFF0000u);
        a6 += bf2f(u.w << 16); a7 += bf2f(u.w & 0xFFFF0000u);
    }
#pragma unroll
    for (int off = 16; off < 64; off <<= 1) {
        a0 += __shfl_xor(a0, off, 64); a1 += __shfl_xor(a1, off, 64);
        a2 += __shfl_xor(a2, off, 64); a3 += __shfl_xor(a3, off, 64);
        a4 += __shfl_xor(a4, off, 64); a5 += __shfl_xor(a5, off, 64);
        a6 += __shfl_xor(a6, off, 64); a7 += __shfl_xor(a7, off, 64);
    }
    if (slot == 0) {
        int deg = end - beg;
        float inv = 1.0f / (float)(deg > 1 ? deg : 1);
        uint4 o;
        o.x = (uint)f2bf(a0 * inv) | ((uint)f2bf(a1 * inv) << 16);
        o.y = (uint)f2bf(a2 * inv) | ((uint)f2bf(a3 * inv) << 16);
        o.z = (uint)f2bf(a4 * inv) | ((uint)f2bf(a5 * inv) << 16);
        o.w = (uint)f2bf(a6 * inv) | ((uint)f2bf(a7 * inv) << 16);
        reinterpret_cast<uint4*>(out)[(size_t)wid * 16 + cg] = o;
    }
}

// ---------------- MFMA GEMM v3: one-shot A staging (no BN), fragment-ordered B -------------
// out[M,128] = mean@W + cur@R + b, fused col-stats; 3 barriers per block.
__global__ __launch_bounds__(256, 2) void k_gemm_mfma(const ushort* __restrict__ Am,
                                                      const ushort* __restrict__ Ac,
                                                      const ushort* __restrict__ Wcat, // frag layout
                                                      const float* __restrict__ bias,
                                                      ushort* __restrict__ out,
                                                      float* __restrict__ stats_out,
                                                      int dostats) {
    __shared__ ushort A2[2][128][136];   // 69.6 KB
    __shared__ float lsum[128], lsumsq[128];
    int tid = threadIdx.x;
    int wid = tid >> 6, lane = tid & 63;
    int wr = wid >> 1, wc = wid & 1;
    int l15 = lane & 15, lhi = lane >> 4;
    int row0 = blockIdx.x * 128;

    if (tid < 128) { lsum[tid] = 0.f; lsumsq[tid] = 0.f; }

    for (int h = 0; h < 2; ++h) {
        const ushort* Asrc = h ? Ac : Am;
#pragma unroll
        for (int i = 0; i < 8; ++i) {
            int idx = i * 256 + tid;
            int row = idx >> 4, q = idx & 15;
            int gr = row0 + row;
            uint4 v = {0, 0, 0, 0};
            if (gr < N_NODES)
                v = *reinterpret_cast<const uint4*>(Asrc + (size_t)gr * 128 + q * 8);
            *reinterpret_cast<uint4*>(&A2[h][row][q * 8]) = v;
        }
    }
    __syncthreads();

    f32x4 acc[4][4];
#pragma unroll
    for (int m = 0; m < 4; m++)
#pragma unroll
        for (int n = 0; n < 4; n++) acc[m][n] = (f32x4){0.f, 0.f, 0.f, 0.f};

#pragma unroll
    for (int ks = 0; ks < 8; ++ks) {
        int kg = ks * 32;
        int half = kg >> 7;
        int ka = (kg & 127) + lhi * 8;
        bf16x8 a[4], b[4];
#pragma unroll
        for (int m = 0; m < 4; m++)
            a[m] = *reinterpret_cast<bf16x8*>(&A2[half][wr * 64 + m * 16 + l15][ka]);
#pragma unroll
        for (int n = 0; n < 4; n++)
            b[n] = *reinterpret_cast<const bf16x8*>(Wcat + ((wc * 4 + n) * 8 + ks) * 512 + lane * 8);
#pragma unroll
        for (int m = 0; m < 4; m++)
#pragma unroll
            for (int n = 0; n < 4; n++)
                acc[m][n] = __builtin_amdgcn_mfma_f32_16x16x32_bf16(a[m], b[n], acc[m][n], 0, 0, 0);
    }
    // epilogue: + bias, bf16 store, per-column stats partials
    float ps[4] = {0.f, 0.f, 0.f, 0.f}, ps2[4] = {0.f, 0.f, 0.f, 0.f};
#pragma unroll
    for (int m = 0; m < 4; m++) {
        int rbase = row0 + wr * 64 + m * 16 + lhi * 4;
#pragma unroll
        for (int n = 0; n < 4; n++) {
            int col = wc * 64 + n * 16 + l15;
            float bv = bias[col];
#pragma unroll
            for (int j = 0; j < 4; j++) {
                int gr = rbase + j;
                if (gr < N_NODES) {
                    float v = acc[m][n][j] + bv;
                    out[(size_t)gr * 128 + col] = f2bf(v);
                    ps[n] += v;
                    ps2[n] += v * v;
                }
            }
        }
    }
    if (dostats) {
#pragma unroll
        for (int n = 0; n < 4; n++) {
            ps[n] += __shfl_xor(ps[n], 16, 64);
            ps2[n] += __shfl_xor(ps2[n], 16, 64);
            ps[n] += __shfl_xor(ps[n], 32, 64);
            ps2[n] += __shfl_xor(ps2[n], 32, 64);
        }
        if (lhi == 0) {
#pragma unroll
            for (int n = 0; n < 4; n++) {
                int col = wc * 64 + n * 16 + l15;
                atomicAdd(&lsum[col], ps[n]);
                atomicAdd(&lsumsq[col], ps2[n]);
            }
        }
        __syncthreads();
        if (tid < 128) {
            atomicAdd(&stats_out[tid], lsum[tid]);
            atomicAdd(&stats_out[128 + tid], lsumsq[tid]);
        }
    }
}

// ---------------- layer-3 GEMM v3: one-shot A staging + frag B + bias + log_softmax -------
__global__ __launch_bounds__(256, 2) void k_gemm40_mfma(const ushort* __restrict__ Am,
                                                        const ushort* __restrict__ Ac,
                                                        const ushort* __restrict__ Wcat, // frag layout [3 fc][8 ks][512]
                                                        const float* __restrict__ bias,  // [40]
                                                        float* __restrict__ out) {
    __shared__ ushort A2[2][128][136];
    int tid = threadIdx.x;
    int w = tid >> 6, lane = tid & 63;
    int l15 = lane & 15, lhi = lane >> 4;
    int row0 = blockIdx.x * 128;

    for (int h = 0; h < 2; ++h) {
        const ushort* Asrc = h ? Ac : Am;
#pragma unroll
        for (int i = 0; i < 8; ++i) {
            int idx = i * 256 + tid;
            int row = idx >> 4, q = idx & 15;
            int gr = row0 + row;
            uint4 v = {0, 0, 0, 0};
            if (gr < N_NODES)
                v = *reinterpret_cast<const uint4*>(Asrc + (size_t)gr * 128 + q * 8);
            *reinterpret_cast<uint4*>(&A2[h][row][q * 8]) = v;
        }
    }
    __syncthreads();

    f32x4 acc[2][3];
#pragma unroll
    for (int m = 0; m < 2; m++)
#pragma unroll
        for (int n = 0; n < 3; n++) acc[m][n] = (f32x4){0.f, 0.f, 0.f, 0.f};

#pragma unroll
    for (int ks = 0; ks < 8; ++ks) {
        int kg = ks * 32;
        int half = kg >> 7;
        int ka = (kg & 127) + lhi * 8;
        bf16x8 a[2], b[3];
#pragma unroll
        for (int m = 0; m < 2; m++)
            a[m] = *reinterpret_cast<bf16x8*>(&A2[half][w * 32 + m * 16 + l15][ka]);
#pragma unroll
        for (int n = 0; n < 3; n++)
            b[n] = *reinterpret_cast<const bf16x8*>(Wcat + (n * 8 + ks) * 512 + lane * 8);
#pragma unroll
        for (int m = 0; m < 2; m++)
#pragma unroll
            for (int n = 0; n < 3; n++)
                acc[m][n] = __builtin_amdgcn_mfma_f32_16x16x32_bf16(a[m], b[n], acc[m][n], 0, 0, 0);
    }
    // epilogue: bias + log_softmax per row (row lives in a 16-lane group)
    float b0 = bias[l15];
    float b1 = bias[16 + l15];
    float b2 = (l15 < 8) ? bias[32 + l15] : 0.f;
#pragma unroll
    for (int m = 0; m < 2; m++) {
#pragma unroll
        for (int j = 0; j < 4; j++) {
            int grow = row0 + w * 32 + m * 16 + lhi * 4 + j;
            float v0 = acc[m][0][j] + b0;
            float v1 = acc[m][1][j] + b1;
            float v2 = (l15 < 8) ? (acc[m][2][j] + b2) : -INFINITY;
            float mx = fmaxf(fmaxf(v0, v1), v2);
#pragma unroll
            for (int off = 1; off < 16; off <<= 1) mx = fmaxf(mx, __shfl_xor(mx, off, 64));
            float s = expf(v0 - mx) + expf(v1 - mx) + ((l15 < 8) ? expf(v2 - mx) : 0.f);
#pragma unroll
            for (int off = 1; off < 16; off <<= 1) s += __shfl_xor(s, off, 64);
            float lg = mx + logf(s);
            if (grow < N_NODES) {
                out[(size_t)grow * DOUT + l15] = v0 - lg;
                out[(size_t)grow * DOUT + 16 + l15] = v1 - lg;
                if (l15 < 8) out[(size_t)grow * DOUT + 32 + l15] = v2 - lg;
            }
        }
    }
}

// ---------------- launch ----------------
extern "C" void kernel_launch(void* const* d_in, const int* in_sizes, int n_in,
                              void* d_out, int out_size, void* d_ws, size_t ws_size,
                              hipStream_t stream) {
    const float* x = (const float*)d_in[0];
    const int* ei = (const int*)d_in[1];
    const float* w1 = (const float*)d_in[2];
    const float* r1 = (const float*)d_in[3];
    const float* b1 = (const float*)d_in[4];
    const float* g1 = (const float*)d_in[5];
    const float* be1 = (const float*)d_in[6];
    const float* w2 = (const float*)d_in[7];
    const float* r2 = (const float*)d_in[8];
    const float* b2 = (const float*)d_in[9];
    const float* g2 = (const float*)d_in[10];
    const float* be2 = (const float*)d_in[11];
    const float* w3 = (const float*)d_in[12];
    const float* r3 = (const float*)d_in[13];
    const float* b3 = (const float*)d_in[14];
    float* out = (float*)d_out;

    const size_t NF = (size_t)N_NODES * DIM;  // 12.8M
    ushort* Xb = (ushort*)d_ws;
    ushort* Ab = Xb + NF;
    ushort* Bb = Ab + NF;
    ushort* Wc1 = Bb + NF;             // 128*256
    ushort* Wc2 = Wc1 + 128 * 256;
    ushort* Wc3 = Wc2 + 128 * 256;     // 48*256
    uint* bucketbuf = (uint*)(Wc3 + 48 * 256);   // NB*BCAP
    int* gcnt = (int*)(bucketbuf + (size_t)NB * BCAP);  // NB
    float* statsA = (float*)(gcnt + NB);          // 256 (sum+sumsq)
    float* statsB = statsA + 256;                 // 256
    int* rowstart = (int*)(statsB + 256);         // N+1
    int* csr = rowstart + (N_NODES + 1);          // E
    size_t needed = (size_t)((char*)(csr + N_EDGES) - (char*)d_ws);
    if (ws_size < needed) return;

    const int AGG_BLOCKS = N_NODES / 4;               // 25000
    const int GEMM_BLOCKS = (N_NODES + 127) / 128;    // 782

    // zero gcnt + stats, then fused prep (cvt + wcat x3 + bucket)
    hipMemsetAsync(gcnt, 0, (NB + 512) * sizeof(int), stream);
    k_prep<<<2608, 256, 0, stream>>>(x, Xb, w1, r1, Wc1, w2, r2, Wc2, w3, r3, Wc3,
                                     ei, bucketbuf, gcnt);
    k_csr_build<<<NB, 256, 0, stream>>>(ei, bucketbuf, gcnt, rowstart, csr);

    // ---- layer 1 ----
    k_agg_bf<<<AGG_BLOCKS, 256, 0, stream>>>(Xb, rowstart, csr, Ab);
    k_gemm_mfma<<<GEMM_BLOCKS, 256, 0, stream>>>(Ab, Xb, Wc1, b1, Ab, statsA, 1);
    k_bnrelu<<<2048, 256, 0, stream>>>(Ab, statsA, g1, be1);   // Ab := bnrelu(h1)

    // ---- layer 2 ----
    k_agg_bf<<<AGG_BLOCKS, 256, 0, stream>>>(Ab, rowstart, csr, Bb);
    k_gemm_mfma<<<GEMM_BLOCKS, 256, 0, stream>>>(Bb, Ab, Wc2, b2, Bb, statsB, 1);
    k_bnrelu<<<2048, 256, 0, stream>>>(Bb, statsB, g2, be2);   // Bb := bnrelu(h2)

    // ---- layer 3 ----
    k_agg_bf<<<AGG_BLOCKS, 256, 0, stream>>>(Bb, rowstart, csr, Ab);
    k_gemm40_mfma<<<GEMM_BLOCKS, 256, 0, stream>>>(Ab, Bb, Wc3, b3, out);
}

// Round 14
// 376.674 us; speedup vs baseline: 1.3274x; 1.0216x over previous
//
#include <hip/hip_runtime.h>
#include <cstdint>
#include <cstddef>
#include <math.h>

#define N_NODES 100000
#define N_EDGES 1600000
#define DIM 128
#define DOUT 40
#define BN_EPS 1e-5f

// bucketed CSR build
#define NB 500          // buckets
#define NPB 200         // nodes per bucket (500*200 = 100000 exactly)
#define BCAP 4096       // bucket capacity (mean 3200 -> ~16 sigma headroom)
#define BKT_BLOCKS 800
#define EPB (N_EDGES / BKT_BLOCKS)   // 2000

typedef __attribute__((ext_vector_type(8))) short bf16x8;
typedef __attribute__((ext_vector_type(4))) float f32x4;

__device__ __forceinline__ float bf2f(uint u16shifted) {
    union { uint i; float f; } c; c.i = u16shifted; return c.f;
}
__device__ __forceinline__ ushort f2bf(float f) {
    union { float f; uint i; } c; c.f = f;
    uint i = c.i;
    uint lsb = (i >> 16) & 1u;
    i += 0x7FFFu + lsb;
    return (ushort)(i >> 16);
}
__device__ __forceinline__ uint bnpack(uint u, float s0, float h0, float s1, float h1) {
    float lo = fmaxf(bf2f(u << 16) * s0 + h0, 0.f);
    float hi = fmaxf(bf2f(u & 0xFFFF0000u) * s1 + h1, 0.f);
    return (uint)f2bf(lo) | ((uint)f2bf(hi) << 16);
}

// Wcat FRAGMENT layout: for col-fragment fc (=col>>4) and K-step ks (=k>>5),
// fragment base = (fc*8+ks)*512 ushorts; within, lane l holds elems l*8..l*8+7
__device__ __forceinline__ void wcat_body(const float* __restrict__ W,
                                          const float* __restrict__ R,
                                          ushort* __restrict__ out, int NW, int blk) {
    int idx = blk * 256 + threadIdx.x;      // idx over Ncols*256
    int n = idx >> 8, k = idx & 255;
    float v = 0.f;
    if (n < NW) v = (k < 128) ? W[k * NW + n] : R[(k - 128) * NW + n];
    int fc = n >> 4, l15 = n & 15;
    int ks = k >> 5, lhi = (k & 31) >> 3, j = k & 7;
    out[(fc * 8 + ks) * 512 + (lhi * 16 + l15) * 8 + j] = f2bf(v);
}

// ---------------- fused prep: bucket (0..799) + wcat x3 (800..1103) + cvt (1104..3151) -----
__global__ __launch_bounds__(256) void k_prep(const float* __restrict__ x,
                                              ushort* __restrict__ Xb,
                                              const float* __restrict__ w1, const float* __restrict__ r1, ushort* __restrict__ Wc1,
                                              const float* __restrict__ w2, const float* __restrict__ r2, ushort* __restrict__ Wc2,
                                              const float* __restrict__ w3, const float* __restrict__ r3, ushort* __restrict__ Wc3,
                                              const int* __restrict__ ei,
                                              uint* __restrict__ bucketbuf,
                                              int* __restrict__ gcnt) {
    int b = blockIdx.x;
    int tid = threadIdx.x;
    if (b < BKT_BLOCKS) {
        // bucket pass: partition edges into dst-buckets (launched first = long pole)
        __shared__ int hist[NB];
        __shared__ int base_[NB];
        for (int i = tid; i < NB; i += 256) hist[i] = 0;
        __syncthreads();
        int e0 = b * EPB, e1 = e0 + EPB;
        for (int e = e0 + tid; e < e1; e += 256) {
            int d = ei[N_EDGES + e];
            atomicAdd(&hist[d / NPB], 1);
        }
        __syncthreads();
        for (int i = tid; i < NB; i += 256) base_[i] = atomicAdd(&gcnt[i], hist[i]);
        __syncthreads();
        for (int i = tid; i < NB; i += 256) hist[i] = 0;
        __syncthreads();
        for (int e = e0 + tid; e < e1; e += 256) {
            int d = ei[N_EDGES + e];
            int s = ei[e];
            int bk = d / NPB;
            int pos = base_[bk] + atomicAdd(&hist[bk], 1);
            if (pos < BCAP)
                bucketbuf[(size_t)bk * BCAP + pos] = ((uint)(d - bk * NPB) << 17) | (uint)s;
        }
    } else if (b < BKT_BLOCKS + 128) {
        wcat_body(w1, r1, Wc1, 128, b - BKT_BLOCKS);
    } else if (b < BKT_BLOCKS + 256) {
        wcat_body(w2, r2, Wc2, 128, b - (BKT_BLOCKS + 128));
    } else if (b < BKT_BLOCKS + 304) {
        wcat_body(w3, r3, Wc3, DOUT, b - (BKT_BLOCKS + 256));
    } else {
        int n4 = N_NODES * DIM / 4;
        int i = (b - (BKT_BLOCKS + 304)) * 256 + tid;
        int stride = 2048 * 256;
        for (; i < n4; i += stride) {
            float4 v = reinterpret_cast<const float4*>(x)[i];
            ushort4 o;
            o.x = f2bf(v.x); o.y = f2bf(v.y); o.z = f2bf(v.z); o.w = f2bf(v.w);
            reinterpret_cast<ushort4*>(Xb)[i] = o;
        }
    }
}

// ---------------- CSR pass B: per-bucket CSR entirely in LDS (self-computed base) ----------
__global__ __launch_bounds__(256) void k_csr_build(const int* __restrict__ ei,
                                                   const uint* __restrict__ bucketbuf,
                                                   const int* __restrict__ gcnt,
                                                   int* __restrict__ rowstart,
                                                   int* __restrict__ csr) {
    __shared__ int cnts[NPB + 1];
    __shared__ int lcur[NPB];
    __shared__ int csr_l[BCAP];
    __shared__ int baseS;
    int b = blockIdx.x, tid = threadIdx.x;
    int cnt = gcnt[b];
    int lo = b * NPB;
    if (tid == 0) baseS = 0;
    for (int i = tid; i < NPB; i += 256) cnts[i] = 0;
    __syncthreads();
    int part = 0;
    for (int i = tid; i < b; i += 256) part += gcnt[i];
    if (part) atomicAdd(&baseS, part);
    bool fits = (cnt <= BCAP);
    if (fits) {
        for (int i = tid; i < cnt; i += 256)
            atomicAdd(&cnts[bucketbuf[(size_t)b * BCAP + i] >> 17], 1);
    } else {  // overflow fallback (statistically never)
        for (int e = tid; e < N_EDGES; e += 256) {
            int d = ei[N_EDGES + e];
            if (d >= lo && d < lo + NPB) atomicAdd(&cnts[d - lo], 1);
        }
    }
    __syncthreads();
    int base = baseS;
    if (tid == 0) {
        int run = 0;
        for (int i = 0; i < NPB; i++) { int c = cnts[i]; cnts[i] = run; run += c; }
        cnts[NPB] = run;
    }
    __syncthreads();
    for (int i = tid; i < NPB; i += 256) rowstart[lo + i] = base + cnts[i];
    if (b == NB - 1 && tid == 0) rowstart[N_NODES] = N_EDGES;
    for (int i = tid; i < NPB; i += 256) lcur[i] = 0;
    __syncthreads();
    if (fits) {
        for (int i = tid; i < cnt; i += 256) {
            uint p = bucketbuf[(size_t)b * BCAP + i];
            int dl = p >> 17;
            int pos = cnts[dl] + atomicAdd(&lcur[dl], 1);
            csr_l[pos] = (int)(p & 0x1FFFFu);
        }
        __syncthreads();
        for (int i = tid; i < cnt; i += 256) csr[base + i] = csr_l[i];
    } else {
        for (int e = tid; e < N_EDGES; e += 256) {
            int d = ei[N_EDGES + e];
            if (d >= lo && d < lo + NPB) {
                int dl = d - lo;
                int pos = cnts[dl] + atomicAdd(&lcur[dl], 1);
                csr[base + pos] = ei[e];
            }
        }
    }
}

// ---------------- BN+ReLU materialization, in-place, vectorized ----------------
__global__ __launch_bounds__(256) void k_bnrelu(ushort* __restrict__ H,
                                                const float* __restrict__ stats,
                                                const float* __restrict__ g,
                                                const float* __restrict__ be) {
    __shared__ float scS[128], shS[128];
    int tid = threadIdx.x;
    if (tid < 128) {
        float mu = stats[tid] * (1.0f / N_NODES);
        float var = stats[128 + tid] * (1.0f / N_NODES) - mu * mu;
        float sc = g[tid] * rsqrtf(var + BN_EPS);
        scS[tid] = sc;
        shS[tid] = be[tid] - mu * sc;
    }
    __syncthreads();
    uint4* H4 = reinterpret_cast<uint4*>(H);
    const int total = N_NODES * 16;   // uint4 per row = 16
    for (int i = blockIdx.x * 256 + tid; i < total; i += gridDim.x * 256) {
        uint4 u = H4[i];
        int c0 = (i & 15) * 8;
        u.x = bnpack(u.x, scS[c0 + 0], shS[c0 + 0], scS[c0 + 1], shS[c0 + 1]);
        u.y = bnpack(u.y, scS[c0 + 2], shS[c0 + 2], scS[c0 + 3], shS[c0 + 3]);
        u.z = bnpack(u.z, scS[c0 + 4], shS[c0 + 4], scS[c0 + 5], shS[c0 + 5]);
        u.w = bnpack(u.w, scS[c0 + 6], shS[c0 + 6], scS[c0 + 7], shS[c0 + 7]);
        H4[i] = u;
    }
}

// ---------------- mean aggregation, bf16, 4 edges in flight (pure unpack+add) ------
__global__ __launch_bounds__(256) void k_agg_bf(const ushort* __restrict__ cur,
                                                const int* __restrict__ rowstart,
                                                const int* __restrict__ csr,
                                                ushort* __restrict__ out) {
    int wid = (blockIdx.x * blockDim.x + threadIdx.x) >> 6;
    int lane = threadIdx.x & 63;
    if (wid >= N_NODES) return;
    int beg = rowstart[wid];
    int end = rowstart[wid + 1];
    int slot = lane >> 4;   // which edge within a group of 4
    int cg = lane & 15;     // column group: cols cg*8 .. cg*8+7
    const uint4* base = reinterpret_cast<const uint4*>(cur);
    float a0 = 0.f, a1 = 0.f, a2 = 0.f, a3 = 0.f, a4 = 0.f, a5 = 0.f, a6 = 0.f, a7 = 0.f;
#pragma unroll 2
    for (int e = beg + slot; e < end; e += 4) {
        int s = csr[e];
        uint4 u = base[(size_t)s * 16 + cg];
        a0 += bf2f(u.x << 16); a1 += bf2f(u.x & 0xFFFF0000u);
        a2 += bf2f(u.y << 16); a3 += bf2f(u.y & 0xFFFF0000u);
        a4 += bf2f(u.z << 16); a5 += bf2f(u.z & 0xFFFF0000u);
        a6 += bf2f(u.w << 16); a7 += bf2f(u.w & 0xFFFF0000u);
    }
#pragma unroll
    for (int off = 16; off < 64; off <<= 1) {
        a0 += __shfl_xor(a0, off, 64); a1 += __shfl_xor(a1, off, 64);
        a2 += __shfl_xor(a2, off, 64); a3 += __shfl_xor(a3, off, 64);
        a4 += __shfl_xor(a4, off, 64); a5 += __shfl_xor(a5, off, 64);
        a6 += __shfl_xor(a6, off, 64); a7 += __shfl_xor(a7, off, 64);
    }
    if (slot == 0) {
        int deg = end - beg;
        float inv = 1.0f / (float)(deg > 1 ? deg : 1);
        uint4 o;
        o.x = (uint)f2bf(a0 * inv) | ((uint)f2bf(a1 * inv) << 16);
        o.y = (uint)f2bf(a2 * inv) | ((uint)f2bf(a3 * inv) << 16);
        o.z = (uint)f2bf(a4 * inv) | ((uint)f2bf(a5 * inv) << 16);
        o.w = (uint)f2bf(a6 * inv) | ((uint)f2bf(a7 * inv) << 16);
        reinterpret_cast<uint4*>(out)[(size_t)wid * 16 + cg] = o;
    }
}

// ---------------- MFMA GEMM v3: one-shot A staging, fragment-ordered B -------------
__global__ __launch_bounds__(256, 2) void k_gemm_mfma(const ushort* __restrict__ Am,
                                                      const ushort* __restrict__ Ac,
                                                      const ushort* __restrict__ Wcat, // frag layout
                                                      const float* __restrict__ bias,
                                                      ushort* __restrict__ out,
                                                      float* __restrict__ stats_out,
                                                      int dostats) {
    __shared__ ushort A2[2][128][136];   // 69.6 KB
    __shared__ float lsum[128], lsumsq[128];
    int tid = threadIdx.x;
    int wid = tid >> 6, lane = tid & 63;
    int wr = wid >> 1, wc = wid & 1;
    int l15 = lane & 15, lhi = lane >> 4;
    int row0 = blockIdx.x * 128;

    if (tid < 128) { lsum[tid] = 0.f; lsumsq[tid] = 0.f; }

    for (int h = 0; h < 2; ++h) {
        const ushort* Asrc = h ? Ac : Am;
#pragma unroll
        for (int i = 0; i < 8; ++i) {
            int idx = i * 256 + tid;
            int row = idx >> 4, q = idx & 15;
            int gr = row0 + row;
            uint4 v = {0, 0, 0, 0};
            if (gr < N_NODES)
                v = *reinterpret_cast<const uint4*>(Asrc + (size_t)gr * 128 + q * 8);
            *reinterpret_cast<uint4*>(&A2[h][row][q * 8]) = v;
        }
    }
    __syncthreads();

    f32x4 acc[4][4];
#pragma unroll
    for (int m = 0; m < 4; m++)
#pragma unroll
        for (int n = 0; n < 4; n++) acc[m][n] = (f32x4){0.f, 0.f, 0.f, 0.f};

#pragma unroll
    for (int ks = 0; ks < 8; ++ks) {
        int kg = ks * 32;
        int half = kg >> 7;
        int ka = (kg & 127) + lhi * 8;
        bf16x8 a[4], b[4];
#pragma unroll
        for (int m = 0; m < 4; m++)
            a[m] = *reinterpret_cast<bf16x8*>(&A2[half][wr * 64 + m * 16 + l15][ka]);
#pragma unroll
        for (int n = 0; n < 4; n++)
            b[n] = *reinterpret_cast<const bf16x8*>(Wcat + ((wc * 4 + n) * 8 + ks) * 512 + lane * 8);
#pragma unroll
        for (int m = 0; m < 4; m++)
#pragma unroll
            for (int n = 0; n < 4; n++)
                acc[m][n] = __builtin_amdgcn_mfma_f32_16x16x32_bf16(a[m], b[n], acc[m][n], 0, 0, 0);
    }
    float ps[4] = {0.f, 0.f, 0.f, 0.f}, ps2[4] = {0.f, 0.f, 0.f, 0.f};
#pragma unroll
    for (int m = 0; m < 4; m++) {
        int rbase = row0 + wr * 64 + m * 16 + lhi * 4;
#pragma unroll
        for (int n = 0; n < 4; n++) {
            int col = wc * 64 + n * 16 + l15;
            float bv = bias[col];
#pragma unroll
            for (int j = 0; j < 4; j++) {
                int gr = rbase + j;
                if (gr < N_NODES) {
                    float v = acc[m][n][j] + bv;
                    out[(size_t)gr * 128 + col] = f2bf(v);
                    ps[n] += v;
                    ps2[n] += v * v;
                }
            }
        }
    }
    if (dostats) {
#pragma unroll
        for (int n = 0; n < 4; n++) {
            ps[n] += __shfl_xor(ps[n], 16, 64);
            ps2[n] += __shfl_xor(ps2[n], 16, 64);
            ps[n] += __shfl_xor(ps[n], 32, 64);
            ps2[n] += __shfl_xor(ps2[n], 32, 64);
        }
        if (lhi == 0) {
#pragma unroll
            for (int n = 0; n < 4; n++) {
                int col = wc * 64 + n * 16 + l15;
                atomicAdd(&lsum[col], ps[n]);
                atomicAdd(&lsumsq[col], ps2[n]);
            }
        }
        __syncthreads();
        if (tid < 128) {
            atomicAdd(&stats_out[tid], lsum[tid]);
            atomicAdd(&stats_out[128 + tid], lsumsq[tid]);
        }
    }
}

// ---------------- layer-3 GEMM v3: one-shot A staging + frag B + bias + log_softmax -------
__global__ __launch_bounds__(256, 2) void k_gemm40_mfma(const ushort* __restrict__ Am,
                                                        const ushort* __restrict__ Ac,
                                                        const ushort* __restrict__ Wcat, // frag layout [3 fc][8 ks][512]
                                                        const float* __restrict__ bias,  // [40]
                                                        float* __restrict__ out) {
    __shared__ ushort A2[2][128][136];
    int tid = threadIdx.x;
    int w = tid >> 6, lane = tid & 63;
    int l15 = lane & 15, lhi = lane >> 4;
    int row0 = blockIdx.x * 128;

    for (int h = 0; h < 2; ++h) {
        const ushort* Asrc = h ? Ac : Am;
#pragma unroll
        for (int i = 0; i < 8; ++i) {
            int idx = i * 256 + tid;
            int row = idx >> 4, q = idx & 15;
            int gr = row0 + row;
            uint4 v = {0, 0, 0, 0};
            if (gr < N_NODES)
                v = *reinterpret_cast<const uint4*>(Asrc + (size_t)gr * 128 + q * 8);
            *reinterpret_cast<uint4*>(&A2[h][row][q * 8]) = v;
        }
    }
    __syncthreads();

    f32x4 acc[2][3];
#pragma unroll
    for (int m = 0; m < 2; m++)
#pragma unroll
        for (int n = 0; n < 3; n++) acc[m][n] = (f32x4){0.f, 0.f, 0.f, 0.f};

#pragma unroll
    for (int ks = 0; ks < 8; ++ks) {
        int kg = ks * 32;
        int half = kg >> 7;
        int ka = (kg & 127) + lhi * 8;
        bf16x8 a[2], b[3];
#pragma unroll
        for (int m = 0; m < 2; m++)
            a[m] = *reinterpret_cast<bf16x8*>(&A2[half][w * 32 + m * 16 + l15][ka]);
#pragma unroll
        for (int n = 0; n < 3; n++)
            b[n] = *reinterpret_cast<const bf16x8*>(Wcat + (n * 8 + ks) * 512 + lane * 8);
#pragma unroll
        for (int m = 0; m < 2; m++)
#pragma unroll
            for (int n = 0; n < 3; n++)
                acc[m][n] = __builtin_amdgcn_mfma_f32_16x16x32_bf16(a[m], b[n], acc[m][n], 0, 0, 0);
    }
    float b0 = bias[l15];
    float b1 = bias[16 + l15];
    float b2 = (l15 < 8) ? bias[32 + l15] : 0.f;
#pragma unroll
    for (int m = 0; m < 2; m++) {
#pragma unroll
        for (int j = 0; j < 4; j++) {
            int grow = row0 + w * 32 + m * 16 + lhi * 4 + j;
            float v0 = acc[m][0][j] + b0;
            float v1 = acc[m][1][j] + b1;
            float v2 = (l15 < 8) ? (acc[m][2][j] + b2) : -INFINITY;
            float mx = fmaxf(fmaxf(v0, v1), v2);
#pragma unroll
            for (int off = 1; off < 16; off <<= 1) mx = fmaxf(mx, __shfl_xor(mx, off, 64));
            float s = expf(v0 - mx) + expf(v1 - mx) + ((l15 < 8) ? expf(v2 - mx) : 0.f);
#pragma unroll
            for (int off = 1; off < 16; off <<= 1) s += __shfl_xor(s, off, 64);
            float lg = mx + logf(s);
            if (grow < N_NODES) {
                out[(size_t)grow * DOUT + l15] = v0 - lg;
                out[(size_t)grow * DOUT + 16 + l15] = v1 - lg;
                if (l15 < 8) out[(size_t)grow * DOUT + 32 + l15] = v2 - lg;
            }
        }
    }
}

// ---------------- launch ----------------
extern "C" void kernel_launch(void* const* d_in, const int* in_sizes, int n_in,
                              void* d_out, int out_size, void* d_ws, size_t ws_size,
                              hipStream_t stream) {
    const float* x = (const float*)d_in[0];
    const int* ei = (const int*)d_in[1];
    const float* w1 = (const float*)d_in[2];
    const float* r1 = (const float*)d_in[3];
    const float* b1 = (const float*)d_in[4];
    const float* g1 = (const float*)d_in[5];
    const float* be1 = (const float*)d_in[6];
    const float* w2 = (const float*)d_in[7];
    const float* r2 = (const float*)d_in[8];
    const float* b2 = (const float*)d_in[9];
    const float* g2 = (const float*)d_in[10];
    const float* be2 = (const float*)d_in[11];
    const float* w3 = (const float*)d_in[12];
    const float* r3 = (const float*)d_in[13];
    const float* b3 = (const float*)d_in[14];
    float* out = (float*)d_out;

    const size_t NF = (size_t)N_NODES * DIM;  // 12.8M
    ushort* Xb = (ushort*)d_ws;
    ushort* Ab = Xb + NF;
    ushort* Bb = Ab + NF;
    ushort* Wc1 = Bb + NF;             // 128*256
    ushort* Wc2 = Wc1 + 128 * 256;
    ushort* Wc3 = Wc2 + 128 * 256;     // 48*256
    uint* bucketbuf = (uint*)(Wc3 + 48 * 256);   // NB*BCAP = 2.048M uints
    int* gcnt = (int*)(bucketbuf + (size_t)NB * BCAP);  // NB
    float* statsA = (float*)(gcnt + NB);          // 256 (sum+sumsq)
    float* statsB = statsA + 256;                 // 256
    int* rowstart = (int*)(statsB + 256);         // N+1
    int* csr = rowstart + (N_NODES + 1);          // E
    size_t needed = (size_t)((char*)(csr + N_EDGES) - (char*)d_ws);
    if (ws_size < needed) return;

    const int AGG_BLOCKS = N_NODES / 4;               // 25000
    const int GEMM_BLOCKS = (N_NODES + 127) / 128;    // 782
    const int PREP_BLOCKS = BKT_BLOCKS + 304 + 2048;  // 3152

    // zero gcnt + stats, then fused prep (bucket first + wcat x3 + cvt)
    hipMemsetAsync(gcnt, 0, (NB + 512) * sizeof(int), stream);
    k_prep<<<PREP_BLOCKS, 256, 0, stream>>>(x, Xb, w1, r1, Wc1, w2, r2, Wc2, w3, r3, Wc3,
                                            ei, bucketbuf, gcnt);
    k_csr_build<<<NB, 256, 0, stream>>>(ei, bucketbuf, gcnt, rowstart, csr);

    // ---- layer 1 ----
    k_agg_bf<<<AGG_BLOCKS, 256, 0, stream>>>(Xb, rowstart, csr, Ab);
    k_gemm_mfma<<<GEMM_BLOCKS, 256, 0, stream>>>(Ab, Xb, Wc1, b1, Ab, statsA, 1);
    k_bnrelu<<<2048, 256, 0, stream>>>(Ab, statsA, g1, be1);   // Ab := bnrelu(h1)

    // ---- layer 2 ----
    k_agg_bf<<<AGG_BLOCKS, 256, 0, stream>>>(Ab, rowstart, csr, Bb);
    k_gemm_mfma<<<GEMM_BLOCKS, 256, 0, stream>>>(Bb, Ab, Wc2, b2, Bb, statsB, 1);
    k_bnrelu<<<2048, 256, 0, stream>>>(Bb, statsB, g2, be2);   // Bb := bnrelu(h2)

    // ---- layer 3 ----
    k_agg_bf<<<AGG_BLOCKS, 256, 0, stream>>>(Bb, rowstart, csr, Ab);
    k_gemm40_mfma<<<GEMM_BLOCKS, 256, 0, stream>>>(Ab, Bb, Wc3, b3, out);
}

// Round 15
// 369.591 us; speedup vs baseline: 1.3528x; 1.0192x over previous
//
#include <hip/hip_runtime.h>
#include <cstdint>
#include <cstddef>
#include <math.h>

#define N_NODES 100000
#define N_EDGES 1600000
#define DIM 128
#define DOUT 40
#define BN_EPS 1e-5f

// bucketed CSR build
#define NB 500          // buckets
#define NPB 200         // nodes per bucket (500*200 = 100000 exactly)
#define BCAP 4096       // bucket capacity (mean 3200 -> ~16 sigma headroom)
#define BKT_BLOCKS 200
#define EPB (N_EDGES / BKT_BLOCKS)   // 8000

typedef __attribute__((ext_vector_type(8))) short bf16x8;
typedef __attribute__((ext_vector_type(4))) float f32x4;

__device__ __forceinline__ float bf2f(uint u16shifted) {
    union { uint i; float f; } c; c.i = u16shifted; return c.f;
}
__device__ __forceinline__ ushort f2bf(float f) {
    union { float f; uint i; } c; c.f = f;
    uint i = c.i;
    uint lsb = (i >> 16) & 1u;
    i += 0x7FFFu + lsb;
    return (ushort)(i >> 16);
}
__device__ __forceinline__ uint bnpack(uint u, float s0, float h0, float s1, float h1) {
    float lo = fmaxf(bf2f(u << 16) * s0 + h0, 0.f);
    float hi = fmaxf(bf2f(u & 0xFFFF0000u) * s1 + h1, 0.f);
    return (uint)f2bf(lo) | ((uint)f2bf(hi) << 16);
}

// Wcat FRAGMENT layout: for col-fragment fc (=col>>4) and K-step ks (=k>>5),
// fragment base = (fc*8+ks)*512 ushorts; within, lane l holds elems l*8..l*8+7
__device__ __forceinline__ void wcat_body(const float* __restrict__ W,
                                          const float* __restrict__ R,
                                          ushort* __restrict__ out, int NW, int blk) {
    int idx = blk * 256 + threadIdx.x;      // idx over Ncols*256
    int n = idx >> 8, k = idx & 255;
    float v = 0.f;
    if (n < NW) v = (k < 128) ? W[k * NW + n] : R[(k - 128) * NW + n];
    int fc = n >> 4, l15 = n & 15;
    int ks = k >> 5, lhi = (k & 31) >> 3, j = k & 7;
    out[(fc * 8 + ks) * 512 + (lhi * 16 + l15) * 8 + j] = f2bf(v);
}

// ---------------- fused prep: bucket (0..199) + cvt (200..2247) + wcat x3 (2248..2551) -----
__global__ __launch_bounds__(256) void k_prep(const float* __restrict__ x,
                                              ushort* __restrict__ Xb,
                                              const float* __restrict__ w1, const float* __restrict__ r1, ushort* __restrict__ Wc1,
                                              const float* __restrict__ w2, const float* __restrict__ r2, ushort* __restrict__ Wc2,
                                              const float* __restrict__ w3, const float* __restrict__ r3, ushort* __restrict__ Wc3,
                                              const int* __restrict__ ei,
                                              uint* __restrict__ bucketbuf,
                                              int* __restrict__ gcnt) {
    int b = blockIdx.x;
    int tid = threadIdx.x;
    if (b < BKT_BLOCKS) {
        // bucket pass: partition edges into dst-buckets (long runs -> write-combined)
        __shared__ int hist[NB];
        __shared__ int base_[NB];
        for (int i = tid; i < NB; i += 256) hist[i] = 0;
        __syncthreads();
        int e0 = b * EPB, e1 = e0 + EPB;
        for (int e = e0 + tid; e < e1; e += 256) {
            int d = ei[N_EDGES + e];
            atomicAdd(&hist[d / NPB], 1);
        }
        __syncthreads();
        for (int i = tid; i < NB; i += 256) base_[i] = atomicAdd(&gcnt[i], hist[i]);
        __syncthreads();
        for (int i = tid; i < NB; i += 256) hist[i] = 0;
        __syncthreads();
        for (int e = e0 + tid; e < e1; e += 256) {
            int d = ei[N_EDGES + e];
            int s = ei[e];
            int bk = d / NPB;
            int pos = base_[bk] + atomicAdd(&hist[bk], 1);
            if (pos < BCAP)
                bucketbuf[(size_t)bk * BCAP + pos] = ((uint)(d - bk * NPB) << 17) | (uint)s;
        }
    } else if (b < BKT_BLOCKS + 2048) {
        int n4 = N_NODES * DIM / 4;
        int i = (b - BKT_BLOCKS) * 256 + tid;
        int stride = 2048 * 256;
        for (; i < n4; i += stride) {
            float4 v = reinterpret_cast<const float4*>(x)[i];
            ushort4 o;
            o.x = f2bf(v.x); o.y = f2bf(v.y); o.z = f2bf(v.z); o.w = f2bf(v.w);
            reinterpret_cast<ushort4*>(Xb)[i] = o;
        }
    } else if (b < BKT_BLOCKS + 2048 + 128) {
        wcat_body(w1, r1, Wc1, 128, b - (BKT_BLOCKS + 2048));
    } else if (b < BKT_BLOCKS + 2048 + 256) {
        wcat_body(w2, r2, Wc2, 128, b - (BKT_BLOCKS + 2048 + 128));
    } else {
        wcat_body(w3, r3, Wc3, DOUT, b - (BKT_BLOCKS + 2048 + 256));
    }
}

// ---------------- CSR pass B: per-bucket CSR entirely in LDS (self-computed base) ----------
__global__ __launch_bounds__(256) void k_csr_build(const int* __restrict__ ei,
                                                   const uint* __restrict__ bucketbuf,
                                                   const int* __restrict__ gcnt,
                                                   int* __restrict__ rowstart,
                                                   int* __restrict__ csr) {
    __shared__ int cnts[NPB + 1];
    __shared__ int lcur[NPB];
    __shared__ int csr_l[BCAP];
    __shared__ int baseS;
    int b = blockIdx.x, tid = threadIdx.x;
    int cnt = gcnt[b];
    int lo = b * NPB;
    if (tid == 0) baseS = 0;
    for (int i = tid; i < NPB; i += 256) cnts[i] = 0;
    __syncthreads();
    int part = 0;
    for (int i = tid; i < b; i += 256) part += gcnt[i];
    if (part) atomicAdd(&baseS, part);
    bool fits = (cnt <= BCAP);
    if (fits) {
        for (int i = tid; i < cnt; i += 256)
            atomicAdd(&cnts[bucketbuf[(size_t)b * BCAP + i] >> 17], 1);
    } else {  // overflow fallback (statistically never)
        for (int e = tid; e < N_EDGES; e += 256) {
            int d = ei[N_EDGES + e];
            if (d >= lo && d < lo + NPB) atomicAdd(&cnts[d - lo], 1);
        }
    }
    __syncthreads();
    int base = baseS;
    if (tid == 0) {
        int run = 0;
        for (int i = 0; i < NPB; i++) { int c = cnts[i]; cnts[i] = run; run += c; }
        cnts[NPB] = run;
    }
    __syncthreads();
    for (int i = tid; i < NPB; i += 256) rowstart[lo + i] = base + cnts[i];
    if (b == NB - 1 && tid == 0) rowstart[N_NODES] = N_EDGES;
    for (int i = tid; i < NPB; i += 256) lcur[i] = 0;
    __syncthreads();
    if (fits) {
        for (int i = tid; i < cnt; i += 256) {
            uint p = bucketbuf[(size_t)b * BCAP + i];
            int dl = p >> 17;
            int pos = cnts[dl] + atomicAdd(&lcur[dl], 1);
            csr_l[pos] = (int)(p & 0x1FFFFu);
        }
        __syncthreads();
        for (int i = tid; i < cnt; i += 256) csr[base + i] = csr_l[i];
    } else {
        for (int e = tid; e < N_EDGES; e += 256) {
            int d = ei[N_EDGES + e];
            if (d >= lo && d < lo + NPB) {
                int dl = d - lo;
                int pos = cnts[dl] + atomicAdd(&lcur[dl], 1);
                csr[base + pos] = ei[e];
            }
        }
    }
}

// ---------------- BN+ReLU materialization, in-place, vectorized ----------------
__global__ __launch_bounds__(256) void k_bnrelu(ushort* __restrict__ H,
                                                const float* __restrict__ stats,
                                                const float* __restrict__ g,
                                                const float* __restrict__ be) {
    __shared__ float scS[128], shS[128];
    int tid = threadIdx.x;
    if (tid < 128) {
        float mu = stats[tid] * (1.0f / N_NODES);
        float var = stats[128 + tid] * (1.0f / N_NODES) - mu * mu;
        float sc = g[tid] * rsqrtf(var + BN_EPS);
        scS[tid] = sc;
        shS[tid] = be[tid] - mu * sc;
    }
    __syncthreads();
    uint4* H4 = reinterpret_cast<uint4*>(H);
    const int total = N_NODES * 16;   // uint4 per row = 16
    for (int i = blockIdx.x * 256 + tid; i < total; i += gridDim.x * 256) {
        uint4 u = H4[i];
        int c0 = (i & 15) * 8;
        u.x = bnpack(u.x, scS[c0 + 0], shS[c0 + 0], scS[c0 + 1], shS[c0 + 1]);
        u.y = bnpack(u.y, scS[c0 + 2], shS[c0 + 2], scS[c0 + 3], shS[c0 + 3]);
        u.z = bnpack(u.z, scS[c0 + 4], shS[c0 + 4], scS[c0 + 5], shS[c0 + 5]);
        u.w = bnpack(u.w, scS[c0 + 6], shS[c0 + 6], scS[c0 + 7], shS[c0 + 7]);
        H4[i] = u;
    }
}

// ---------------- mean aggregation, bf16, 4 edges in flight (pure unpack+add) ------
__global__ __launch_bounds__(256) void k_agg_bf(const ushort* __restrict__ cur,
                                                const int* __restrict__ rowstart,
                                                const int* __restrict__ csr,
                                                ushort* __restrict__ out) {
    int wid = (blockIdx.x * blockDim.x + threadIdx.x) >> 6;
    int lane = threadIdx.x & 63;
    if (wid >= N_NODES) return;
    int beg = rowstart[wid];
    int end = rowstart[wid + 1];
    int slot = lane >> 4;   // which edge within a group of 4
    int cg = lane & 15;     // column group: cols cg*8 .. cg*8+7
    const uint4* base = reinterpret_cast<const uint4*>(cur);
    float a0 = 0.f, a1 = 0.f, a2 = 0.f, a3 = 0.f, a4 = 0.f, a5 = 0.f, a6 = 0.f, a7 = 0.f;
#pragma unroll 2
    for (int e = beg + slot; e < end; e += 4) {
        int s = csr[e];
        uint4 u = base[(size_t)s * 16 + cg];
        a0 += bf2f(u.x << 16); a1 += bf2f(u.x & 0xFFFF0000u);
        a2 += bf2f(u.y << 16); a3 += bf2f(u.y & 0xFFFF0000u);
        a4 += bf2f(u.z << 16); a5 += bf2f(u.z & 0xFFFF0000u);
        a6 += bf2f(u.w << 16); a7 += bf2f(u.w & 0xFFFF0000u);
    }
#pragma unroll
    for (int off = 16; off < 64; off <<= 1) {
        a0 += __shfl_xor(a0, off, 64); a1 += __shfl_xor(a1, off, 64);
        a2 += __shfl_xor(a2, off, 64); a3 += __shfl_xor(a3, off, 64);
        a4 += __shfl_xor(a4, off, 64); a5 += __shfl_xor(a5, off, 64);
        a6 += __shfl_xor(a6, off, 64); a7 += __shfl_xor(a7, off, 64);
    }
    if (slot == 0) {
        int deg = end - beg;
        float inv = 1.0f / (float)(deg > 1 ? deg : 1);
        uint4 o;
        o.x = (uint)f2bf(a0 * inv) | ((uint)f2bf(a1 * inv) << 16);
        o.y = (uint)f2bf(a2 * inv) | ((uint)f2bf(a3 * inv) << 16);
        o.z = (uint)f2bf(a4 * inv) | ((uint)f2bf(a5 * inv) << 16);
        o.w = (uint)f2bf(a6 * inv) | ((uint)f2bf(a7 * inv) << 16);
        reinterpret_cast<uint4*>(out)[(size_t)wid * 16 + cg] = o;
    }
}

// ---------------- MFMA GEMM v4: pipelined staging (mean LDS -> self regs in flight) -------
// out[M,128] = mean@W + cur@R + b, fused col-stats.
__global__ __launch_bounds__(256, 2) void k_gemm_mfma(const ushort* __restrict__ Am,
                                                      const ushort* __restrict__ Ac,
                                                      const ushort* __restrict__ Wcat, // frag layout
                                                      const float* __restrict__ bias,
                                                      ushort* __restrict__ out,
                                                      float* __restrict__ stats_out,
                                                      int dostats) {
    __shared__ ushort A2[2][128][136];   // 69.6 KB
    __shared__ float lsum[128], lsumsq[128];
    int tid = threadIdx.x;
    int wid = tid >> 6, lane = tid & 63;
    int wr = wid >> 1, wc = wid & 1;
    int l15 = lane & 15, lhi = lane >> 4;
    int row0 = blockIdx.x * 128;

    if (tid < 128) { lsum[tid] = 0.f; lsumsq[tid] = 0.f; }

    // stage mean half into LDS[0]
#pragma unroll
    for (int i = 0; i < 8; ++i) {
        int idx = i * 256 + tid;
        int row = idx >> 4, q = idx & 15;
        int gr = row0 + row;
        uint4 v = {0, 0, 0, 0};
        if (gr < N_NODES)
            v = *reinterpret_cast<const uint4*>(Am + (size_t)gr * 128 + q * 8);
        *reinterpret_cast<uint4*>(&A2[0][row][q * 8]) = v;
    }
    // issue self-half loads into registers (in flight across the first MFMA phase)
    uint4 sreg[8];
#pragma unroll
    for (int i = 0; i < 8; ++i) {
        int idx = i * 256 + tid;
        int row = idx >> 4, q = idx & 15;
        int gr = row0 + row;
        uint4 v = {0, 0, 0, 0};
        if (gr < N_NODES)
            v = *reinterpret_cast<const uint4*>(Ac + (size_t)gr * 128 + q * 8);
        sreg[i] = v;
    }
    __syncthreads();

    f32x4 acc[4][4];
#pragma unroll
    for (int m = 0; m < 4; m++)
#pragma unroll
        for (int n = 0; n < 4; n++) acc[m][n] = (f32x4){0.f, 0.f, 0.f, 0.f};

    // ks 0..3 on mean half (self loads still in flight)
#pragma unroll
    for (int ks = 0; ks < 4; ++ks) {
        int ka = ks * 32 + lhi * 8;
        bf16x8 a[4], b[4];
#pragma unroll
        for (int m = 0; m < 4; m++)
            a[m] = *reinterpret_cast<bf16x8*>(&A2[0][wr * 64 + m * 16 + l15][ka]);
#pragma unroll
        for (int n = 0; n < 4; n++)
            b[n] = *reinterpret_cast<const bf16x8*>(Wcat + ((wc * 4 + n) * 8 + ks) * 512 + lane * 8);
#pragma unroll
        for (int m = 0; m < 4; m++)
#pragma unroll
            for (int n = 0; n < 4; n++)
                acc[m][n] = __builtin_amdgcn_mfma_f32_16x16x32_bf16(a[m], b[n], acc[m][n], 0, 0, 0);
    }
    // write self half to LDS[1]
#pragma unroll
    for (int i = 0; i < 8; ++i) {
        int idx = i * 256 + tid;
        int row = idx >> 4, q = idx & 15;
        *reinterpret_cast<uint4*>(&A2[1][row][q * 8]) = sreg[i];
    }
    __syncthreads();
    // ks 4..7 on self half
#pragma unroll
    for (int ks = 4; ks < 8; ++ks) {
        int ka = (ks - 4) * 32 + lhi * 8;
        bf16x8 a[4], b[4];
#pragma unroll
        for (int m = 0; m < 4; m++)
            a[m] = *reinterpret_cast<bf16x8*>(&A2[1][wr * 64 + m * 16 + l15][ka]);
#pragma unroll
        for (int n = 0; n < 4; n++)
            b[n] = *reinterpret_cast<const bf16x8*>(Wcat + ((wc * 4 + n) * 8 + ks) * 512 + lane * 8);
#pragma unroll
        for (int m = 0; m < 4; m++)
#pragma unroll
            for (int n = 0; n < 4; n++)
                acc[m][n] = __builtin_amdgcn_mfma_f32_16x16x32_bf16(a[m], b[n], acc[m][n], 0, 0, 0);
    }
    // epilogue: + bias, bf16 store, per-column stats partials
    float ps[4] = {0.f, 0.f, 0.f, 0.f}, ps2[4] = {0.f, 0.f, 0.f, 0.f};
#pragma unroll
    for (int m = 0; m < 4; m++) {
        int rbase = row0 + wr * 64 + m * 16 + lhi * 4;
#pragma unroll
        for (int n = 0; n < 4; n++) {
            int col = wc * 64 + n * 16 + l15;
            float bv = bias[col];
#pragma unroll
            for (int j = 0; j < 4; j++) {
                int gr = rbase + j;
                if (gr < N_NODES) {
                    float v = acc[m][n][j] + bv;
                    out[(size_t)gr * 128 + col] = f2bf(v);
                    ps[n] += v;
                    ps2[n] += v * v;
                }
            }
        }
    }
    if (dostats) {
#pragma unroll
        for (int n = 0; n < 4; n++) {
            ps[n] += __shfl_xor(ps[n], 16, 64);
            ps2[n] += __shfl_xor(ps2[n], 16, 64);
            ps[n] += __shfl_xor(ps[n], 32, 64);
            ps2[n] += __shfl_xor(ps2[n], 32, 64);
        }
        if (lhi == 0) {
#pragma unroll
            for (int n = 0; n < 4; n++) {
                int col = wc * 64 + n * 16 + l15;
                atomicAdd(&lsum[col], ps[n]);
                atomicAdd(&lsumsq[col], ps2[n]);
            }
        }
        __syncthreads();
        if (tid < 128) {
            atomicAdd(&stats_out[tid], lsum[tid]);
            atomicAdd(&stats_out[128 + tid], lsumsq[tid]);
        }
    }
}

// ---------------- layer-3 GEMM v4: pipelined staging + frag B + bias + log_softmax --------
__global__ __launch_bounds__(256, 2) void k_gemm40_mfma(const ushort* __restrict__ Am,
                                                        const ushort* __restrict__ Ac,
                                                        const ushort* __restrict__ Wcat, // frag layout [3 fc][8 ks][512]
                                                        const float* __restrict__ bias,  // [40]
                                                        float* __restrict__ out) {
    __shared__ ushort A2[2][128][136];
    int tid = threadIdx.x;
    int w = tid >> 6, lane = tid & 63;
    int l15 = lane & 15, lhi = lane >> 4;
    int row0 = blockIdx.x * 128;

    // stage mean half
#pragma unroll
    for (int i = 0; i < 8; ++i) {
        int idx = i * 256 + tid;
        int row = idx >> 4, q = idx & 15;
        int gr = row0 + row;
        uint4 v = {0, 0, 0, 0};
        if (gr < N_NODES)
            v = *reinterpret_cast<const uint4*>(Am + (size_t)gr * 128 + q * 8);
        *reinterpret_cast<uint4*>(&A2[0][row][q * 8]) = v;
    }
    uint4 sreg[8];
#pragma unroll
    for (int i = 0; i < 8; ++i) {
        int idx = i * 256 + tid;
        int row = idx >> 4, q = idx & 15;
        int gr = row0 + row;
        uint4 v = {0, 0, 0, 0};
        if (gr < N_NODES)
            v = *reinterpret_cast<const uint4*>(Ac + (size_t)gr * 128 + q * 8);
        sreg[i] = v;
    }
    __syncthreads();

    f32x4 acc[2][3];
#pragma unroll
    for (int m = 0; m < 2; m++)
#pragma unroll
        for (int n = 0; n < 3; n++) acc[m][n] = (f32x4){0.f, 0.f, 0.f, 0.f};

#pragma unroll
    for (int ks = 0; ks < 4; ++ks) {
        int ka = ks * 32 + lhi * 8;
        bf16x8 a[2], b[3];
#pragma unroll
        for (int m = 0; m < 2; m++)
            a[m] = *reinterpret_cast<bf16x8*>(&A2[0][w * 32 + m * 16 + l15][ka]);
#pragma unroll
        for (int n = 0; n < 3; n++)
            b[n] = *reinterpret_cast<const bf16x8*>(Wcat + (n * 8 + ks) * 512 + lane * 8);
#pragma unroll
        for (int m = 0; m < 2; m++)
#pragma unroll
            for (int n = 0; n < 3; n++)
                acc[m][n] = __builtin_amdgcn_mfma_f32_16x16x32_bf16(a[m], b[n], acc[m][n], 0, 0, 0);
    }
#pragma unroll
    for (int i = 0; i < 8; ++i) {
        int idx = i * 256 + tid;
        int row = idx >> 4, q = idx & 15;
        *reinterpret_cast<uint4*>(&A2[1][row][q * 8]) = sreg[i];
    }
    __syncthreads();
#pragma unroll
    for (int ks = 4; ks < 8; ++ks) {
        int ka = (ks - 4) * 32 + lhi * 8;
        bf16x8 a[2], b[3];
#pragma unroll
        for (int m = 0; m < 2; m++)
            a[m] = *reinterpret_cast<bf16x8*>(&A2[1][w * 32 + m * 16 + l15][ka]);
#pragma unroll
        for (int n = 0; n < 3; n++)
            b[n] = *reinterpret_cast<const bf16x8*>(Wcat + (n * 8 + ks) * 512 + lane * 8);
#pragma unroll
        for (int m = 0; m < 2; m++)
#pragma unroll
            for (int n = 0; n < 3; n++)
                acc[m][n] = __builtin_amdgcn_mfma_f32_16x16x32_bf16(a[m], b[n], acc[m][n], 0, 0, 0);
    }
    // epilogue: bias + log_softmax per row (row lives in a 16-lane group)
    float b0 = bias[l15];
    float b1 = bias[16 + l15];
    float b2 = (l15 < 8) ? bias[32 + l15] : 0.f;
#pragma unroll
    for (int m = 0; m < 2; m++) {
#pragma unroll
        for (int j = 0; j < 4; j++) {
            int grow = row0 + w * 32 + m * 16 + lhi * 4 + j;
            float v0 = acc[m][0][j] + b0;
            float v1 = acc[m][1][j] + b1;
            float v2 = (l15 < 8) ? (acc[m][2][j] + b2) : -INFINITY;
            float mx = fmaxf(fmaxf(v0, v1), v2);
#pragma unroll
            for (int off = 1; off < 16; off <<= 1) mx = fmaxf(mx, __shfl_xor(mx, off, 64));
            float s = expf(v0 - mx) + expf(v1 - mx) + ((l15 < 8) ? expf(v2 - mx) : 0.f);
#pragma unroll
            for (int off = 1; off < 16; off <<= 1) s += __shfl_xor(s, off, 64);
            float lg = mx + logf(s);
            if (grow < N_NODES) {
                out[(size_t)grow * DOUT + l15] = v0 - lg;
                out[(size_t)grow * DOUT + 16 + l15] = v1 - lg;
                if (l15 < 8) out[(size_t)grow * DOUT + 32 + l15] = v2 - lg;
            }
        }
    }
}

// ---------------- launch ----------------
extern "C" void kernel_launch(void* const* d_in, const int* in_sizes, int n_in,
                              void* d_out, int out_size, void* d_ws, size_t ws_size,
                              hipStream_t stream) {
    const float* x = (const float*)d_in[0];
    const int* ei = (const int*)d_in[1];
    const float* w1 = (const float*)d_in[2];
    const float* r1 = (const float*)d_in[3];
    const float* b1 = (const float*)d_in[4];
    const float* g1 = (const float*)d_in[5];
    const float* be1 = (const float*)d_in[6];
    const float* w2 = (const float*)d_in[7];
    const float* r2 = (const float*)d_in[8];
    const float* b2 = (const float*)d_in[9];
    const float* g2 = (const float*)d_in[10];
    const float* be2 = (const float*)d_in[11];
    const float* w3 = (const float*)d_in[12];
    const float* r3 = (const float*)d_in[13];
    const float* b3 = (const float*)d_in[14];
    float* out = (float*)d_out;

    const size_t NF = (size_t)N_NODES * DIM;  // 12.8M
    ushort* Xb = (ushort*)d_ws;
    ushort* Ab = Xb + NF;
    ushort* Bb = Ab + NF;
    ushort* Wc1 = Bb + NF;             // 128*256
    ushort* Wc2 = Wc1 + 128 * 256;
    ushort* Wc3 = Wc2 + 128 * 256;     // 48*256
    uint* bucketbuf = (uint*)(Wc3 + 48 * 256);   // NB*BCAP = 2.048M uints
    int* gcnt = (int*)(bucketbuf + (size_t)NB * BCAP);  // NB
    float* statsA = (float*)(gcnt + NB);          // 256 (sum+sumsq)
    float* statsB = statsA + 256;                 // 256
    int* rowstart = (int*)(statsB + 256);         // N+1
    int* csr = rowstart + (N_NODES + 1);          // E
    size_t needed = (size_t)((char*)(csr + N_EDGES) - (char*)d_ws);
    if (ws_size < needed) return;

    const int AGG_BLOCKS = N_NODES / 4;               // 25000
    const int GEMM_BLOCKS = (N_NODES + 127) / 128;    // 782
    const int PREP_BLOCKS = BKT_BLOCKS + 2048 + 304;  // 2552

    // zero gcnt + stats, then fused prep (bucket first + cvt + wcat x3)
    hipMemsetAsync(gcnt, 0, (NB + 512) * sizeof(int), stream);
    k_prep<<<PREP_BLOCKS, 256, 0, stream>>>(x, Xb, w1, r1, Wc1, w2, r2, Wc2, w3, r3, Wc3,
                                            ei, bucketbuf, gcnt);
    k_csr_build<<<NB, 256, 0, stream>>>(ei, bucketbuf, gcnt, rowstart, csr);

    // ---- layer 1 ----
    k_agg_bf<<<AGG_BLOCKS, 256, 0, stream>>>(Xb, rowstart, csr, Ab);
    k_gemm_mfma<<<GEMM_BLOCKS, 256, 0, stream>>>(Ab, Xb, Wc1, b1, Ab, statsA, 1);
    k_bnrelu<<<2048, 256, 0, stream>>>(Ab, statsA, g1, be1);   // Ab := bnrelu(h1)

    // ---- layer 2 ----
    k_agg_bf<<<AGG_BLOCKS, 256, 0, stream>>>(Ab, rowstart, csr, Bb);
    k_gemm_mfma<<<GEMM_BLOCKS, 256, 0, stream>>>(Bb, Ab, Wc2, b2, Bb, statsB, 1);
    k_bnrelu<<<2048, 256, 0, stream>>>(Bb, statsB, g2, be2);   // Bb := bnrelu(h2)

    // ---- layer 3 ----
    k_agg_bf<<<AGG_BLOCKS, 256, 0, stream>>>(Bb, rowstart, csr, Ab);
    k_gemm40_mfma<<<GEMM_BLOCKS, 256, 0, stream>>>(Ab, Bb, Wc3, b3, out);
}

// Round 16
// 355.668 us; speedup vs baseline: 1.4058x; 1.0391x over previous
//
#include <hip/hip_runtime.h>
#include <cstdint>
#include <cstddef>
#include <math.h>

#define N_NODES 100000
#define N_EDGES 1600000
#define DIM 128
#define DOUT 40
#define BN_EPS 1e-5f

// bucketed CSR build
#define NB 500          // buckets
#define NPB 200         // nodes per bucket (500*200 = 100000 exactly)
#define BCAP 4096       // bucket capacity (mean 3200 -> ~16 sigma headroom)
#define BKT_BLOCKS 200
#define EPB (N_EDGES / BKT_BLOCKS)   // 8000

typedef __attribute__((ext_vector_type(8))) short bf16x8;
typedef __attribute__((ext_vector_type(4))) float f32x4;

__device__ __forceinline__ float bf2f(uint u16shifted) {
    union { uint i; float f; } c; c.i = u16shifted; return c.f;
}
__device__ __forceinline__ ushort f2bf(float f) {
    union { float f; uint i; } c; c.f = f;
    uint i = c.i;
    uint lsb = (i >> 16) & 1u;
    i += 0x7FFFu + lsb;
    return (ushort)(i >> 16);
}
__device__ __forceinline__ uint bnpack(uint u, float s0, float h0, float s1, float h1) {
    float lo = fmaxf(bf2f(u << 16) * s0 + h0, 0.f);
    float hi = fmaxf(bf2f(u & 0xFFFF0000u) * s1 + h1, 0.f);
    return (uint)f2bf(lo) | ((uint)f2bf(hi) << 16);
}

// Wcat FRAGMENT layout: for col-fragment fc (=col>>4) and K-step ks (=k>>5),
// fragment base = (fc*8+ks)*512 ushorts; within, lane l holds elems l*8..l*8+7
__device__ __forceinline__ void wcat_body(const float* __restrict__ W,
                                          const float* __restrict__ R,
                                          ushort* __restrict__ out, int NW, int blk) {
    int idx = blk * 256 + threadIdx.x;      // idx over Ncols*256
    int n = idx >> 8, k = idx & 255;
    float v = 0.f;
    if (n < NW) v = (k < 128) ? W[k * NW + n] : R[(k - 128) * NW + n];
    int fc = n >> 4, l15 = n & 15;
    int ks = k >> 5, lhi = (k & 31) >> 3, j = k & 7;
    out[(fc * 8 + ks) * 512 + (lhi * 16 + l15) * 8 + j] = f2bf(v);
}

// ---------------- fused prep: bucket (0..199, int4-vectorized) + cvt + wcat x3 -------------
__global__ __launch_bounds__(256) void k_prep(const float* __restrict__ x,
                                              ushort* __restrict__ Xb,
                                              const float* __restrict__ w1, const float* __restrict__ r1, ushort* __restrict__ Wc1,
                                              const float* __restrict__ w2, const float* __restrict__ r2, ushort* __restrict__ Wc2,
                                              const float* __restrict__ w3, const float* __restrict__ r3, ushort* __restrict__ Wc3,
                                              const int* __restrict__ ei,
                                              uint* __restrict__ bucketbuf,
                                              int* __restrict__ gcnt) {
    int b = blockIdx.x;
    int tid = threadIdx.x;
    if (b < BKT_BLOCKS) {
        // bucket pass: partition edges into dst-buckets; int4 loads = 4 edges/thread/iter
        __shared__ int hist[NB];
        __shared__ int base_[NB];
        for (int i = tid; i < NB; i += 256) hist[i] = 0;
        __syncthreads();
        int e0 = b * EPB, e1 = e0 + EPB;
        for (int e = e0 + tid * 4; e < e1; e += 1024) {
            int4 d4 = *reinterpret_cast<const int4*>(ei + N_EDGES + e);
            atomicAdd(&hist[d4.x / NPB], 1);
            atomicAdd(&hist[d4.y / NPB], 1);
            atomicAdd(&hist[d4.z / NPB], 1);
            atomicAdd(&hist[d4.w / NPB], 1);
        }
        __syncthreads();
        for (int i = tid; i < NB; i += 256) base_[i] = atomicAdd(&gcnt[i], hist[i]);
        __syncthreads();
        for (int i = tid; i < NB; i += 256) hist[i] = 0;
        __syncthreads();
        for (int e = e0 + tid * 4; e < e1; e += 1024) {
            int4 d4 = *reinterpret_cast<const int4*>(ei + N_EDGES + e);
            int4 s4 = *reinterpret_cast<const int4*>(ei + e);
            int bk0 = d4.x / NPB, bk1 = d4.y / NPB, bk2 = d4.z / NPB, bk3 = d4.w / NPB;
            int p0 = base_[bk0] + atomicAdd(&hist[bk0], 1);
            int p1 = base_[bk1] + atomicAdd(&hist[bk1], 1);
            int p2 = base_[bk2] + atomicAdd(&hist[bk2], 1);
            int p3 = base_[bk3] + atomicAdd(&hist[bk3], 1);
            if (p0 < BCAP) bucketbuf[(size_t)bk0 * BCAP + p0] = ((uint)(d4.x - bk0 * NPB) << 17) | (uint)s4.x;
            if (p1 < BCAP) bucketbuf[(size_t)bk1 * BCAP + p1] = ((uint)(d4.y - bk1 * NPB) << 17) | (uint)s4.y;
            if (p2 < BCAP) bucketbuf[(size_t)bk2 * BCAP + p2] = ((uint)(d4.z - bk2 * NPB) << 17) | (uint)s4.z;
            if (p3 < BCAP) bucketbuf[(size_t)bk3 * BCAP + p3] = ((uint)(d4.w - bk3 * NPB) << 17) | (uint)s4.w;
        }
    } else if (b < BKT_BLOCKS + 2048) {
        int n4 = N_NODES * DIM / 4;
        int i = (b - BKT_BLOCKS) * 256 + tid;
        int stride = 2048 * 256;
        for (; i < n4; i += stride) {
            float4 v = reinterpret_cast<const float4*>(x)[i];
            ushort4 o;
            o.x = f2bf(v.x); o.y = f2bf(v.y); o.z = f2bf(v.z); o.w = f2bf(v.w);
            reinterpret_cast<ushort4*>(Xb)[i] = o;
        }
    } else if (b < BKT_BLOCKS + 2048 + 128) {
        wcat_body(w1, r1, Wc1, 128, b - (BKT_BLOCKS + 2048));
    } else if (b < BKT_BLOCKS + 2048 + 256) {
        wcat_body(w2, r2, Wc2, 128, b - (BKT_BLOCKS + 2048 + 128));
    } else {
        wcat_body(w3, r3, Wc3, DOUT, b - (BKT_BLOCKS + 2048 + 256));
    }
}

// ---------------- CSR pass B: per-bucket CSR entirely in LDS (self-computed base) ----------
__global__ __launch_bounds__(256) void k_csr_build(const int* __restrict__ ei,
                                                   const uint* __restrict__ bucketbuf,
                                                   const int* __restrict__ gcnt,
                                                   int* __restrict__ rowstart,
                                                   int* __restrict__ csr) {
    __shared__ int cnts[NPB + 1];
    __shared__ int lcur[NPB];
    __shared__ int csr_l[BCAP];
    __shared__ int baseS;
    int b = blockIdx.x, tid = threadIdx.x;
    int cnt = gcnt[b];
    int lo = b * NPB;
    if (tid == 0) baseS = 0;
    for (int i = tid; i < NPB; i += 256) cnts[i] = 0;
    __syncthreads();
    int part = 0;
    for (int i = tid; i < b; i += 256) part += gcnt[i];
    if (part) atomicAdd(&baseS, part);
    bool fits = (cnt <= BCAP);
    if (fits) {
        for (int i = tid; i < cnt; i += 256)
            atomicAdd(&cnts[bucketbuf[(size_t)b * BCAP + i] >> 17], 1);
    } else {  // overflow fallback (statistically never)
        for (int e = tid; e < N_EDGES; e += 256) {
            int d = ei[N_EDGES + e];
            if (d >= lo && d < lo + NPB) atomicAdd(&cnts[d - lo], 1);
        }
    }
    __syncthreads();
    int base = baseS;
    if (tid == 0) {
        int run = 0;
        for (int i = 0; i < NPB; i++) { int c = cnts[i]; cnts[i] = run; run += c; }
        cnts[NPB] = run;
    }
    __syncthreads();
    for (int i = tid; i < NPB; i += 256) rowstart[lo + i] = base + cnts[i];
    if (b == NB - 1 && tid == 0) rowstart[N_NODES] = N_EDGES;
    for (int i = tid; i < NPB; i += 256) lcur[i] = 0;
    __syncthreads();
    if (fits) {
        for (int i = tid; i < cnt; i += 256) {
            uint p = bucketbuf[(size_t)b * BCAP + i];
            int dl = p >> 17;
            int pos = cnts[dl] + atomicAdd(&lcur[dl], 1);
            csr_l[pos] = (int)(p & 0x1FFFFu);
        }
        __syncthreads();
        for (int i = tid; i < cnt; i += 256) csr[base + i] = csr_l[i];
    } else {
        for (int e = tid; e < N_EDGES; e += 256) {
            int d = ei[N_EDGES + e];
            if (d >= lo && d < lo + NPB) {
                int dl = d - lo;
                int pos = cnts[dl] + atomicAdd(&lcur[dl], 1);
                csr[base + pos] = ei[e];
            }
        }
    }
}

// ---------------- BN+ReLU materialization, in-place, vectorized ----------------
__global__ __launch_bounds__(256) void k_bnrelu(ushort* __restrict__ H,
                                                const float* __restrict__ stats,
                                                const float* __restrict__ g,
                                                const float* __restrict__ be) {
    __shared__ float scS[128], shS[128];
    int tid = threadIdx.x;
    if (tid < 128) {
        float mu = stats[tid] * (1.0f / N_NODES);
        float var = stats[128 + tid] * (1.0f / N_NODES) - mu * mu;
        float sc = g[tid] * rsqrtf(var + BN_EPS);
        scS[tid] = sc;
        shS[tid] = be[tid] - mu * sc;
    }
    __syncthreads();
    uint4* H4 = reinterpret_cast<uint4*>(H);
    const int total = N_NODES * 16;   // uint4 per row = 16
    for (int i = blockIdx.x * 256 + tid; i < total; i += gridDim.x * 256) {
        uint4 u = H4[i];
        int c0 = (i & 15) * 8;
        u.x = bnpack(u.x, scS[c0 + 0], shS[c0 + 0], scS[c0 + 1], shS[c0 + 1]);
        u.y = bnpack(u.y, scS[c0 + 2], shS[c0 + 2], scS[c0 + 3], shS[c0 + 3]);
        u.z = bnpack(u.z, scS[c0 + 4], shS[c0 + 4], scS[c0 + 5], shS[c0 + 5]);
        u.w = bnpack(u.w, scS[c0 + 6], shS[c0 + 6], scS[c0 + 7], shS[c0 + 7]);
        H4[i] = u;
    }
}

// ---------------- mean aggregation, bf16, 4 edges in flight (pure unpack+add) ------
__global__ __launch_bounds__(256) void k_agg_bf(const ushort* __restrict__ cur,
                                                const int* __restrict__ rowstart,
                                                const int* __restrict__ csr,
                                                ushort* __restrict__ out) {
    int wid = (blockIdx.x * blockDim.x + threadIdx.x) >> 6;
    int lane = threadIdx.x & 63;
    if (wid >= N_NODES) return;
    int beg = rowstart[wid];
    int end = rowstart[wid + 1];
    int slot = lane >> 4;   // which edge within a group of 4
    int cg = lane & 15;     // column group: cols cg*8 .. cg*8+7
    const uint4* base = reinterpret_cast<const uint4*>(cur);
    float a0 = 0.f, a1 = 0.f, a2 = 0.f, a3 = 0.f, a4 = 0.f, a5 = 0.f, a6 = 0.f, a7 = 0.f;
#pragma unroll 2
    for (int e = beg + slot; e < end; e += 4) {
        int s = csr[e];
        uint4 u = base[(size_t)s * 16 + cg];
        a0 += bf2f(u.x << 16); a1 += bf2f(u.x & 0xFFFF0000u);
        a2 += bf2f(u.y << 16); a3 += bf2f(u.y & 0xFFFF0000u);
        a4 += bf2f(u.z << 16); a5 += bf2f(u.z & 0xFFFF0000u);
        a6 += bf2f(u.w << 16); a7 += bf2f(u.w & 0xFFFF0000u);
    }
#pragma unroll
    for (int off = 16; off < 64; off <<= 1) {
        a0 += __shfl_xor(a0, off, 64); a1 += __shfl_xor(a1, off, 64);
        a2 += __shfl_xor(a2, off, 64); a3 += __shfl_xor(a3, off, 64);
        a4 += __shfl_xor(a4, off, 64); a5 += __shfl_xor(a5, off, 64);
        a6 += __shfl_xor(a6, off, 64); a7 += __shfl_xor(a7, off, 64);
    }
    if (slot == 0) {
        int deg = end - beg;
        float inv = 1.0f / (float)(deg > 1 ? deg : 1);
        uint4 o;
        o.x = (uint)f2bf(a0 * inv) | ((uint)f2bf(a1 * inv) << 16);
        o.y = (uint)f2bf(a2 * inv) | ((uint)f2bf(a3 * inv) << 16);
        o.z = (uint)f2bf(a4 * inv) | ((uint)f2bf(a5 * inv) << 16);
        o.w = (uint)f2bf(a6 * inv) | ((uint)f2bf(a7 * inv) << 16);
        reinterpret_cast<uint4*>(out)[(size_t)wid * 16 + cg] = o;
    }
}

// ---------------- MFMA GEMM v4: pipelined staging (mean LDS -> self regs in flight) -------
// out[M,128] = mean@W + cur@R + b, fused col-stats.
__global__ __launch_bounds__(256, 2) void k_gemm_mfma(const ushort* __restrict__ Am,
                                                      const ushort* __restrict__ Ac,
                                                      const ushort* __restrict__ Wcat, // frag layout
                                                      const float* __restrict__ bias,
                                                      ushort* __restrict__ out,
                                                      float* __restrict__ stats_out,
                                                      int dostats) {
    __shared__ ushort A2[2][128][136];   // 69.6 KB
    __shared__ float lsum[128], lsumsq[128];
    int tid = threadIdx.x;
    int wid = tid >> 6, lane = tid & 63;
    int wr = wid >> 1, wc = wid & 1;
    int l15 = lane & 15, lhi = lane >> 4;
    int row0 = blockIdx.x * 128;

    if (tid < 128) { lsum[tid] = 0.f; lsumsq[tid] = 0.f; }

    // stage mean half into LDS[0]
#pragma unroll
    for (int i = 0; i < 8; ++i) {
        int idx = i * 256 + tid;
        int row = idx >> 4, q = idx & 15;
        int gr = row0 + row;
        uint4 v = {0, 0, 0, 0};
        if (gr < N_NODES)
            v = *reinterpret_cast<const uint4*>(Am + (size_t)gr * 128 + q * 8);
        *reinterpret_cast<uint4*>(&A2[0][row][q * 8]) = v;
    }
    // issue self-half loads into registers (in flight across the first MFMA phase)
    uint4 sreg[8];
#pragma unroll
    for (int i = 0; i < 8; ++i) {
        int idx = i * 256 + tid;
        int row = idx >> 4, q = idx & 15;
        int gr = row0 + row;
        uint4 v = {0, 0, 0, 0};
        if (gr < N_NODES)
            v = *reinterpret_cast<const uint4*>(Ac + (size_t)gr * 128 + q * 8);
        sreg[i] = v;
    }
    __syncthreads();

    f32x4 acc[4][4];
#pragma unroll
    for (int m = 0; m < 4; m++)
#pragma unroll
        for (int n = 0; n < 4; n++) acc[m][n] = (f32x4){0.f, 0.f, 0.f, 0.f};

    // ks 0..3 on mean half (self loads still in flight)
#pragma unroll
    for (int ks = 0; ks < 4; ++ks) {
        int ka = ks * 32 + lhi * 8;
        bf16x8 a[4], b[4];
#pragma unroll
        for (int m = 0; m < 4; m++)
            a[m] = *reinterpret_cast<bf16x8*>(&A2[0][wr * 64 + m * 16 + l15][ka]);
#pragma unroll
        for (int n = 0; n < 4; n++)
            b[n] = *reinterpret_cast<const bf16x8*>(Wcat + ((wc * 4 + n) * 8 + ks) * 512 + lane * 8);
#pragma unroll
        for (int m = 0; m < 4; m++)
#pragma unroll
            for (int n = 0; n < 4; n++)
                acc[m][n] = __builtin_amdgcn_mfma_f32_16x16x32_bf16(a[m], b[n], acc[m][n], 0, 0, 0);
    }
    // write self half to LDS[1]
#pragma unroll
    for (int i = 0; i < 8; ++i) {
        int idx = i * 256 + tid;
        int row = idx >> 4, q = idx & 15;
        *reinterpret_cast<uint4*>(&A2[1][row][q * 8]) = sreg[i];
    }
    __syncthreads();
    // ks 4..7 on self half
#pragma unroll
    for (int ks = 4; ks < 8; ++ks) {
        int ka = (ks - 4) * 32 + lhi * 8;
        bf16x8 a[4], b[4];
#pragma unroll
        for (int m = 0; m < 4; m++)
            a[m] = *reinterpret_cast<bf16x8*>(&A2[1][wr * 64 + m * 16 + l15][ka]);
#pragma unroll
        for (int n = 0; n < 4; n++)
            b[n] = *reinterpret_cast<const bf16x8*>(Wcat + ((wc * 4 + n) * 8 + ks) * 512 + lane * 8);
#pragma unroll
        for (int m = 0; m < 4; m++)
#pragma unroll
            for (int n = 0; n < 4; n++)
                acc[m][n] = __builtin_amdgcn_mfma_f32_16x16x32_bf16(a[m], b[n], acc[m][n], 0, 0, 0);
    }
    // epilogue: + bias, bf16 store, per-column stats partials
    float ps[4] = {0.f, 0.f, 0.f, 0.f}, ps2[4] = {0.f, 0.f, 0.f, 0.f};
#pragma unroll
    for (int m = 0; m < 4; m++) {
        int rbase = row0 + wr * 64 + m * 16 + lhi * 4;
#pragma unroll
        for (int n = 0; n < 4; n++) {
            int col = wc * 64 + n * 16 + l15;
            float bv = bias[col];
#pragma unroll
            for (int j = 0; j < 4; j++) {
                int gr = rbase + j;
                if (gr < N_NODES) {
                    float v = acc[m][n][j] + bv;
                    out[(size_t)gr * 128 + col] = f2bf(v);
                    ps[n] += v;
                    ps2[n] += v * v;
                }
            }
        }
    }
    if (dostats) {
#pragma unroll
        for (int n = 0; n < 4; n++) {
            ps[n] += __shfl_xor(ps[n], 16, 64);
            ps2[n] += __shfl_xor(ps2[n], 16, 64);
            ps[n] += __shfl_xor(ps[n], 32, 64);
            ps2[n] += __shfl_xor(ps2[n], 32, 64);
        }
        if (lhi == 0) {
#pragma unroll
            for (int n = 0; n < 4; n++) {
                int col = wc * 64 + n * 16 + l15;
                atomicAdd(&lsum[col], ps[n]);
                atomicAdd(&lsumsq[col], ps2[n]);
            }
        }
        __syncthreads();
        if (tid < 128) {
            atomicAdd(&stats_out[tid], lsum[tid]);
            atomicAdd(&stats_out[128 + tid], lsumsq[tid]);
        }
    }
}

// ---------------- layer-3 GEMM v4: pipelined staging + frag B + bias + log_softmax --------
__global__ __launch_bounds__(256, 2) void k_gemm40_mfma(const ushort* __restrict__ Am,
                                                        const ushort* __restrict__ Ac,
                                                        const ushort* __restrict__ Wcat, // frag layout [3 fc][8 ks][512]
                                                        const float* __restrict__ bias,  // [40]
                                                        float* __restrict__ out) {
    __shared__ ushort A2[2][128][136];
    int tid = threadIdx.x;
    int w = tid >> 6, lane = tid & 63;
    int l15 = lane & 15, lhi = lane >> 4;
    int row0 = blockIdx.x * 128;

    // stage mean half
#pragma unroll
    for (int i = 0; i < 8; ++i) {
        int idx = i * 256 + tid;
        int row = idx >> 4, q = idx & 15;
        int gr = row0 + row;
        uint4 v = {0, 0, 0, 0};
        if (gr < N_NODES)
            v = *reinterpret_cast<const uint4*>(Am + (size_t)gr * 128 + q * 8);
        *reinterpret_cast<uint4*>(&A2[0][row][q * 8]) = v;
    }
    uint4 sreg[8];
#pragma unroll
    for (int i = 0; i < 8; ++i) {
        int idx = i * 256 + tid;
        int row = idx >> 4, q = idx & 15;
        int gr = row0 + row;
        uint4 v = {0, 0, 0, 0};
        if (gr < N_NODES)
            v = *reinterpret_cast<const uint4*>(Ac + (size_t)gr * 128 + q * 8);
        sreg[i] = v;
    }
    __syncthreads();

    f32x4 acc[2][3];
#pragma unroll
    for (int m = 0; m < 2; m++)
#pragma unroll
        for (int n = 0; n < 3; n++) acc[m][n] = (f32x4){0.f, 0.f, 0.f, 0.f};

#pragma unroll
    for (int ks = 0; ks < 4; ++ks) {
        int ka = ks * 32 + lhi * 8;
        bf16x8 a[2], b[3];
#pragma unroll
        for (int m = 0; m < 2; m++)
            a[m] = *reinterpret_cast<bf16x8*>(&A2[0][w * 32 + m * 16 + l15][ka]);
#pragma unroll
        for (int n = 0; n < 3; n++)
            b[n] = *reinterpret_cast<const bf16x8*>(Wcat + (n * 8 + ks) * 512 + lane * 8);
#pragma unroll
        for (int m = 0; m < 2; m++)
#pragma unroll
            for (int n = 0; n < 3; n++)
                acc[m][n] = __builtin_amdgcn_mfma_f32_16x16x32_bf16(a[m], b[n], acc[m][n], 0, 0, 0);
    }
#pragma unroll
    for (int i = 0; i < 8; ++i) {
        int idx = i * 256 + tid;
        int row = idx >> 4, q = idx & 15;
        *reinterpret_cast<uint4*>(&A2[1][row][q * 8]) = sreg[i];
    }
    __syncthreads();
#pragma unroll
    for (int ks = 4; ks < 8; ++ks) {
        int ka = (ks - 4) * 32 + lhi * 8;
        bf16x8 a[2], b[3];
#pragma unroll
        for (int m = 0; m < 2; m++)
            a[m] = *reinterpret_cast<bf16x8*>(&A2[1][w * 32 + m * 16 + l15][ka]);
#pragma unroll
        for (int n = 0; n < 3; n++)
            b[n] = *reinterpret_cast<const bf16x8*>(Wcat + (n * 8 + ks) * 512 + lane * 8);
#pragma unroll
        for (int m = 0; m < 2; m++)
#pragma unroll
            for (int n = 0; n < 3; n++)
                acc[m][n] = __builtin_amdgcn_mfma_f32_16x16x32_bf16(a[m], b[n], acc[m][n], 0, 0, 0);
    }
    // epilogue: bias + log_softmax per row (row lives in a 16-lane group)
    float b0 = bias[l15];
    float b1 = bias[16 + l15];
    float b2 = (l15 < 8) ? bias[32 + l15] : 0.f;
#pragma unroll
    for (int m = 0; m < 2; m++) {
#pragma unroll
        for (int j = 0; j < 4; j++) {
            int grow = row0 + w * 32 + m * 16 + lhi * 4 + j;
            float v0 = acc[m][0][j] + b0;
            float v1 = acc[m][1][j] + b1;
            float v2 = (l15 < 8) ? (acc[m][2][j] + b2) : -INFINITY;
            float mx = fmaxf(fmaxf(v0, v1), v2);
#pragma unroll
            for (int off = 1; off < 16; off <<= 1) mx = fmaxf(mx, __shfl_xor(mx, off, 64));
            float s = expf(v0 - mx) + expf(v1 - mx) + ((l15 < 8) ? expf(v2 - mx) : 0.f);
#pragma unroll
            for (int off = 1; off < 16; off <<= 1) s += __shfl_xor(s, off, 64);
            float lg = mx + logf(s);
            if (grow < N_NODES) {
                out[(size_t)grow * DOUT + l15] = v0 - lg;
                out[(size_t)grow * DOUT + 16 + l15] = v1 - lg;
                if (l15 < 8) out[(size_t)grow * DOUT + 32 + l15] = v2 - lg;
            }
        }
    }
}

// ---------------- launch ----------------
extern "C" void kernel_launch(void* const* d_in, const int* in_sizes, int n_in,
                              void* d_out, int out_size, void* d_ws, size_t ws_size,
                              hipStream_t stream) {
    const float* x = (const float*)d_in[0];
    const int* ei = (const int*)d_in[1];
    const float* w1 = (const float*)d_in[2];
    const float* r1 = (const float*)d_in[3];
    const float* b1 = (const float*)d_in[4];
    const float* g1 = (const float*)d_in[5];
    const float* be1 = (const float*)d_in[6];
    const float* w2 = (const float*)d_in[7];
    const float* r2 = (const float*)d_in[8];
    const float* b2 = (const float*)d_in[9];
    const float* g2 = (const float*)d_in[10];
    const float* be2 = (const float*)d_in[11];
    const float* w3 = (const float*)d_in[12];
    const float* r3 = (const float*)d_in[13];
    const float* b3 = (const float*)d_in[14];
    float* out = (float*)d_out;

    const size_t NF = (size_t)N_NODES * DIM;  // 12.8M
    ushort* Xb = (ushort*)d_ws;
    ushort* Ab = Xb + NF;
    ushort* Bb = Ab + NF;
    ushort* Wc1 = Bb + NF;             // 128*256
    ushort* Wc2 = Wc1 + 128 * 256;
    ushort* Wc3 = Wc2 + 128 * 256;     // 48*256
    uint* bucketbuf = (uint*)(Wc3 + 48 * 256);   // NB*BCAP = 2.048M uints
    int* gcnt = (int*)(bucketbuf + (size_t)NB * BCAP);  // NB
    float* statsA = (float*)(gcnt + NB);          // 256 (sum+sumsq)
    float* statsB = statsA + 256;                 // 256
    int* rowstart = (int*)(statsB + 256);         // N+1
    int* csr = rowstart + (N_NODES + 1);          // E
    size_t needed = (size_t)((char*)(csr + N_EDGES) - (char*)d_ws);
    if (ws_size < needed) return;

    const int AGG_BLOCKS = N_NODES / 4;               // 25000
    const int GEMM_BLOCKS = (N_NODES + 127) / 128;    // 782
    const int PREP_BLOCKS = BKT_BLOCKS + 2048 + 304;  // 2552

    // zero gcnt + stats, then fused prep (bucket first + cvt + wcat x3)
    hipMemsetAsync(gcnt, 0, (NB + 512) * sizeof(int), stream);
    k_prep<<<PREP_BLOCKS, 256, 0, stream>>>(x, Xb, w1, r1, Wc1, w2, r2, Wc2, w3, r3, Wc3,
                                            ei, bucketbuf, gcnt);
    k_csr_build<<<NB, 256, 0, stream>>>(ei, bucketbuf, gcnt, rowstart, csr);

    // ---- layer 1 ----
    k_agg_bf<<<AGG_BLOCKS, 256, 0, stream>>>(Xb, rowstart, csr, Ab);
    k_gemm_mfma<<<GEMM_BLOCKS, 256, 0, stream>>>(Ab, Xb, Wc1, b1, Ab, statsA, 1);
    k_bnrelu<<<2048, 256, 0, stream>>>(Ab, statsA, g1, be1);   // Ab := bnrelu(h1)

    // ---- layer 2 ----
    k_agg_bf<<<AGG_BLOCKS, 256, 0, stream>>>(Ab, rowstart, csr, Bb);
    k_gemm_mfma<<<GEMM_BLOCKS, 256, 0, stream>>>(Bb, Ab, Wc2, b2, Bb, statsB, 1);
    k_bnrelu<<<2048, 256, 0, stream>>>(Bb, statsB, g2, be2);   // Bb := bnrelu(h2)

    // ---- layer 3 ----
    k_agg_bf<<<AGG_BLOCKS, 256, 0, stream>>>(Bb, rowstart, csr, Ab);
    k_gemm40_mfma<<<GEMM_BLOCKS, 256, 0, stream>>>(Ab, Bb, Wc3, b3, out);
}